// Round 8
// baseline (824.313 us; speedup 1.0000x reference)
//
#include <hip/hip_runtime.h>
#include <hip/hip_bf16.h>

#define NN 100000
#define NE 1600000
#define NT (NN + NE)
#define LCAP 1024

typedef unsigned int u32;

static __device__ __forceinline__ int clampN(int s) {
    return ((unsigned)s < (unsigned)NN) ? s : 0;
}
static __device__ __forceinline__ bool bad(float a, float r, float atol, float rtol) {
    return fabsf(a - r) > atol + rtol * fabsf(r);
}

// edge index loaders: is32==1 -> packed int32 [2][NE]; is32==0 -> int64 pairs
static __device__ __forceinline__ int ld_src(const int* ei, int is32, int e) {
    return is32 ? ei[e] : ei[2 * e];
}
static __device__ __forceinline__ int ld_dst(const int* ei, int is32, int e) {
    return is32 ? ei[NE + e] : ei[2 * NE + 2 * e];
}

// ---------------- diagnostics infra ----------------
// diag bits: 0 CSR, 1 mm1, 2 agg1, 3 alpha2, 4 gat2, 5 h4, 6 final

__global__ void k_diag0(int* __restrict__ diag, int* __restrict__ lcnt,
                        int* __restrict__ flag) {
    if (threadIdx.x == 0) { diag[0] = 0; lcnt[0] = 0; flag[0] = 0; }
}

__global__ void k_detect(const int* __restrict__ ei, int* __restrict__ flag) {
    int nz = 0;
    for (int i = threadIdx.x; i < 4096; i += 256) nz |= ei[2 * i + 1];
    if (nz) atomicOr(flag, 1);
}

// collect all raw edges with dst==0 (incl self-loop), bypassing CSR
__global__ void k_collect(const int* __restrict__ ei, const int* __restrict__ flag,
                          int* __restrict__ list, int* __restrict__ lcnt) {
    int e = blockIdx.x * 256 + threadIdx.x;
    if (e >= NT) return;
    int is32 = flag[0];
    int d = (e < NE) ? ld_dst(ei, is32, e) : (e - NE);
    if (d == 0) {
        int s = (e < NE) ? clampN(ld_src(ei, is32, e)) : (e - NE);
        int idx = atomicAdd(lcnt, 1);
        if (idx < LCAP) list[idx] = s;
    }
}

// ---------------- CSR construction ----------------

__global__ void k_deg_init(int* __restrict__ cursor) {
    int i = blockIdx.x * 256 + threadIdx.x;
    if (i < NN) cursor[i] = 1;
}

__global__ void k_count(const int* __restrict__ ei, const int* __restrict__ flag,
                        int* __restrict__ cursor) {
    int e = blockIdx.x * 256 + threadIdx.x;
    if (e >= NE) return;
    int d = ld_dst(ei, flag[0], e);
    if ((unsigned)d < (unsigned)NN) atomicAdd(&cursor[d], 1);
}

__global__ void k_scan1(const int* __restrict__ deg, int* __restrict__ rowptr,
                        int* __restrict__ part) {
    __shared__ int sm[256];
    int i = blockIdx.x * 256 + threadIdx.x;
    int v = (i < NN) ? deg[i] : 0;
    sm[threadIdx.x] = v;
    __syncthreads();
    for (int off = 1; off < 256; off <<= 1) {
        int t = (threadIdx.x >= off) ? sm[threadIdx.x - off] : 0;
        __syncthreads();
        sm[threadIdx.x] += t;
        __syncthreads();
    }
    if (i < NN) rowptr[i] = sm[threadIdx.x] - v;
    if (threadIdx.x == 255) part[blockIdx.x] = sm[255];
}

__global__ void k_scan2(int* __restrict__ part, int nb) {
    __shared__ int sm[512];
    int t = threadIdx.x;
    int v = (t < nb) ? part[t] : 0;
    sm[t] = v;
    __syncthreads();
    for (int off = 1; off < 512; off <<= 1) {
        int u = (t >= off) ? sm[t - off] : 0;
        __syncthreads();
        sm[t] += u;
        __syncthreads();
    }
    if (t < nb) part[t] = sm[t] - v;
}

__global__ void k_scan3(int* __restrict__ rowptr, const int* __restrict__ part,
                        const int* __restrict__ deg) {
    int i = blockIdx.x * 256 + threadIdx.x;
    if (i < NN) {
        int r = rowptr[i] + part[blockIdx.x];
        rowptr[i] = r;
        if (i == NN - 1) rowptr[NN] = r + deg[i];
    }
}

__global__ void k_prep(const int* __restrict__ rowptr, int* __restrict__ cursor,
                       float* __restrict__ dinv) {
    int i = blockIdx.x * 256 + threadIdx.x;
    if (i < NN) {
        int b = rowptr[i];
        int d = rowptr[i + 1] - b;
        cursor[i] = b;
        dinv[i] = rsqrtf((float)(d > 0 ? d : 1));
    }
}

__global__ void k_fill(const int* __restrict__ ei, const int* __restrict__ flag,
                       int* __restrict__ cursor, int* __restrict__ col) {
    int e = blockIdx.x * 256 + threadIdx.x;
    if (e < NE) {
        int is32 = flag[0];
        int d = ld_dst(ei, is32, e);
        if ((unsigned)d < (unsigned)NN) {
            int s = clampN(ld_src(ei, is32, e));
            int p = atomicAdd(&cursor[d], 1);
            if ((unsigned)p < (unsigned)NT) col[p] = s;
        }
    } else if (e < NT) {
        int i = e - NE;
        int p = atomicAdd(&cursor[i], 1);
        if ((unsigned)p < (unsigned)NT) col[p] = i;
    }
}

__global__ void k_csrchk(const int* __restrict__ rowptr, const int* __restrict__ cursor,
                         int* __restrict__ diag) {
    int i = blockIdx.x * 256 + threadIdx.x;
    if (i < NN && cursor[i] != rowptr[i + 1]) atomicOr(diag, 1 << 0);
    if (i == 0 && rowptr[NN] != NT) atomicOr(diag, 1 << 0);
}

// ---------------- dense layers (all fp32) ----------------

__global__ void k_mm1(const float* __restrict__ x, const float* __restrict__ W1,
                      float* __restrict__ H) {
    int idx = blockIdx.x * 256 + threadIdx.x;
    int n = idx >> 5, c = idx & 31;
    float acc = 0.f;
    #pragma unroll
    for (int k = 0; k < 7; k++) acc += x[n * 7 + k] * W1[k * 32 + c];
    H[idx] = acc;
}

__global__ void k_mm2(const float* __restrict__ O, const float* __restrict__ W2,
                      const float* __restrict__ avs, const float* __restrict__ avd,
                      float* __restrict__ H, float* __restrict__ as_,
                      float* __restrict__ ad_) {
    int gid = blockIdx.x * 256 + threadIdx.x;
    int n = gid >> 6, c = gid & 63;
    const float* row = O + (size_t)n * 32;
    float acc = 0.f;
    #pragma unroll
    for (int k = 0; k < 32; k++) acc += row[k] * W2[k * 64 + c];
    H[(size_t)n * 64 + c] = acc;
    float vs = acc * avs[c];
    float vd = acc * avd[c];
    #pragma unroll
    for (int off = 32; off > 0; off >>= 1) {
        vs += __shfl_down(vs, off, 64);
        vd += __shfl_down(vd, off, 64);
    }
    if (c == 0) { as_[n] = vs; ad_[n] = vd; }
}

// ---------------- aggregation ----------------

__global__ void __launch_bounds__(256) k_gcn_agg1(const float* __restrict__ H,
                                                  const int* __restrict__ rowptr,
                                                  const int* __restrict__ col,
                                                  const float* __restrict__ dinv,
                                                  const float* __restrict__ bias,
                                                  float* __restrict__ O) {
    int gid = blockIdx.x * 256 + threadIdx.x;
    int n = gid >> 4;
    int lane = gid & 15;
    int beg = rowptr[n], end = rowptr[n + 1];
    float dn = dinv[n];
    float ax = 0.f, ay = 0.f;
    for (int e = beg; e < end; e++) {
        int s = clampN(col[e]);
        float w = dinv[s] * dn;
        float2 f = *(const float2*)(H + (size_t)s * 32 + 2 * lane);
        ax += w * f.x;
        ay += w * f.y;
    }
    float2 o;
    o.x = fmaxf(ax + bias[2 * lane], 0.f);
    o.y = fmaxf(ay + bias[2 * lane + 1], 0.f);
    *(float2*)(O + (size_t)n * 32 + 2 * lane) = o;
}

__global__ void __launch_bounds__(256) k_gat_agg2(const float* __restrict__ H,
                                                  const float* __restrict__ as_,
                                                  const float* __restrict__ ad_,
                                                  const int* __restrict__ rowptr,
                                                  const int* __restrict__ col,
                                                  const float* __restrict__ bias,
                                                  float* __restrict__ O) {
    int gid = blockIdx.x * 256 + threadIdx.x;
    int n = gid >> 5;
    int lane = gid & 31;
    int beg = rowptr[n], end = rowptr[n + 1];
    float adn = ad_[n];
    float m = -1e30f, denom = 0.f, ax = 0.f, ay = 0.f;
    for (int e = beg; e < end; e++) {
        int s = clampN(col[e]);
        float ee = as_[s] + adn;
        ee = (ee > 0.f) ? ee : 0.2f * ee;
        float mn = fmaxf(m, ee);
        float sc = __expf(m - mn);
        float p = __expf(ee - mn);
        denom = denom * sc + p;
        float2 f = *(const float2*)(H + (size_t)s * 64 + 2 * lane);
        ax = ax * sc + p * f.x;
        ay = ay * sc + p * f.y;
        m = mn;
    }
    float inv = 1.0f / (denom + 1e-16f);
    float2 o;
    o.x = fmaxf(ax * inv + bias[2 * lane], 0.f);
    o.y = fmaxf(ay * inv + bias[2 * lane + 1], 0.f);
    *(float2*)(O + (size_t)n * 64 + 2 * lane) = o;
}

__global__ void __launch_bounds__(256) k_fused34(const float* __restrict__ O,
                                                 const float* __restrict__ W3,
                                                 const float* __restrict__ b3,
                                                 const float* __restrict__ W4,
                                                 const float* __restrict__ av4s,
                                                 const float* __restrict__ av4d,
                                                 const int* __restrict__ rowptr,
                                                 const int* __restrict__ col,
                                                 const float* __restrict__ dinv,
                                                 float* __restrict__ h4,
                                                 float* __restrict__ as_,
                                                 float* __restrict__ ad_) {
    __shared__ float sW3[64 * 128];
    __shared__ float sW4[128 * 2];
    __shared__ float sb3[128];
    for (int i = threadIdx.x; i < 64 * 128; i += 256) sW3[i] = W3[i];
    if (threadIdx.x < 128) {
        sW4[2 * threadIdx.x] = W4[2 * threadIdx.x];
        sW4[2 * threadIdx.x + 1] = W4[2 * threadIdx.x + 1];
        sb3[threadIdx.x] = b3[threadIdx.x];
    }
    __syncthreads();

    int wid = threadIdx.x >> 6;
    int lane = threadIdx.x & 63;
    int half = lane >> 5;
    int lw = lane & 31;
    int n = blockIdx.x * 8 + wid * 2 + half;

    int beg = rowptr[n], end = rowptr[n + 1];
    float dn = dinv[n];
    float ax = 0.f, ay = 0.f;   // channels 2*lw, 2*lw+1
    for (int e = beg; e < end; e++) {
        int s = clampN(col[e]);
        float w = dinv[s] * dn;
        float2 f = *(const float2*)(O + (size_t)s * 64 + 2 * lw);
        ax += w * f.x;
        ay += w * f.y;
    }

    float a0 = 0.f, a1 = 0.f, a2 = 0.f, a3 = 0.f;
    #pragma unroll
    for (int k = 0; k < 64; k++) {
        int srcl = half * 32 + (k >> 1);
        float tk = (k & 1) ? __shfl(ay, srcl, 64) : __shfl(ax, srcl, 64);
        const float* wrow = &sW3[k * 128 + lw];
        a0 += tk * wrow[0];
        a1 += tk * wrow[32];
        a2 += tk * wrow[64];
        a3 += tk * wrow[96];
    }
    a0 = fmaxf(a0 + sb3[lw], 0.f);
    a1 = fmaxf(a1 + sb3[lw + 32], 0.f);
    a2 = fmaxf(a2 + sb3[lw + 64], 0.f);
    a3 = fmaxf(a3 + sb3[lw + 96], 0.f);

    float p0 = a0 * sW4[2 * lw] + a1 * sW4[2 * (lw + 32)] +
               a2 * sW4[2 * (lw + 64)] + a3 * sW4[2 * (lw + 96)];
    float p1 = a0 * sW4[2 * lw + 1] + a1 * sW4[2 * (lw + 32) + 1] +
               a2 * sW4[2 * (lw + 64) + 1] + a3 * sW4[2 * (lw + 96) + 1];
    #pragma unroll
    for (int off = 16; off > 0; off >>= 1) {
        p0 += __shfl_down(p0, off, 32);
        p1 += __shfl_down(p1, off, 32);
    }
    if (lw == 0) {
        h4[n * 2 + 0] = p0;
        h4[n * 2 + 1] = p1;
        as_[n] = p0 * av4s[0] + p1 * av4s[1];
        ad_[n] = p0 * av4d[0] + p1 * av4d[1];
    }
}

__global__ void k_final(const float* __restrict__ h4, const float* __restrict__ as_,
                        const float* __restrict__ ad_, const int* __restrict__ rowptr,
                        const int* __restrict__ col, const float* __restrict__ b,
                        float* __restrict__ out) {
    int n = blockIdx.x * 256 + threadIdx.x;
    if (n >= NN) return;
    int beg = rowptr[n], end = rowptr[n + 1];
    float adn = ad_[n];
    float m = -1e30f, denom = 0.f, a0 = 0.f, a1 = 0.f;
    for (int e = beg; e < end; e++) {
        int s = clampN(col[e]);
        float ee = as_[s] + adn;
        ee = (ee > 0.f) ? ee : 0.2f * ee;
        float mn = fmaxf(m, ee);
        float sc = __expf(m - mn);
        float p = __expf(ee - mn);
        denom = denom * sc + p;
        a0 = a0 * sc + p * h4[s * 2 + 0];
        a1 = a1 * sc + p * h4[s * 2 + 1];
        m = mn;
    }
    float inv = 1.0f / (denom + 1e-16f);
    float v0 = a0 * inv + b[0];
    float v1 = a1 * inv + b[1];
    float mx = fmaxf(v0, v1);
    float lse = mx + logf(__expf(v0 - mx) + __expf(v1 - mx));
    out[n * 2 + 0] = v0 - lse;
    out[n * 2 + 1] = v1 - lse;
}

// ---------------- brute-force node-0 cross-checks ----------------

__global__ void k_cmp1(const float* __restrict__ x, const float* __restrict__ W1,
                       const float* __restrict__ b1, const float* __restrict__ h1,
                       const float* __restrict__ O1, const float* __restrict__ dinv,
                       const int* __restrict__ rowptr, const int* __restrict__ list,
                       const int* __restrict__ lcnt, int* __restrict__ diag) {
    int c = threadIdx.x;  // 32 threads
    float r = 0.f;
    for (int k = 0; k < 7; k++) r += x[k] * W1[k * 32 + c];
    if (bad(h1[c], r, 1e-4f, 1e-4f)) atomicOr(diag, 1 << 1);
    int n = min(lcnt[0], LCAP);
    float acc = 0.f;
    for (int j = 0; j < n; j++) {
        int s = list[j];
        acc += dinv[s] * dinv[0] * h1[s * 32 + c];
    }
    float ref = fmaxf(acc + b1[c], 0.f);
    if (bad(O1[c], ref, 1e-3f, 1e-3f)) atomicOr(diag, 1 << 2);
    if (c == 0 && lcnt[0] != rowptr[1] - rowptr[0]) atomicOr(diag, 1 << 2);
}

__global__ void k_cmp2(const float* __restrict__ h2, const float* __restrict__ O2,
                       const float* __restrict__ as_, const float* __restrict__ ad_,
                       const float* __restrict__ avs, const float* __restrict__ avd,
                       const float* __restrict__ b2, const int* __restrict__ list,
                       const int* __restrict__ lcnt, int* __restrict__ diag) {
    __shared__ float smd[2];
    int c = threadIdx.x;  // 64 threads
    int n = min(lcnt[0], LCAP);
    if (c == 0) {
        float asr = 0.f, adr = 0.f;
        for (int k = 0; k < 64; k++) {
            asr += h2[k] * avs[k];
            adr += h2[k] * avd[k];
        }
        if (bad(as_[0], asr, 1e-4f, 1e-3f) || bad(ad_[0], adr, 1e-4f, 1e-3f))
            atomicOr(diag, 1 << 3);
        float m = -1e30f;
        for (int j = 0; j < n; j++) {
            float e = as_[list[j]] + ad_[0];
            e = (e > 0.f) ? e : 0.2f * e;
            m = fmaxf(m, e);
        }
        float den = 0.f;
        for (int j = 0; j < n; j++) {
            float e = as_[list[j]] + ad_[0];
            e = (e > 0.f) ? e : 0.2f * e;
            den += __expf(e - m);
        }
        smd[0] = m; smd[1] = den;
    }
    __syncthreads();
    float m = smd[0], den = smd[1];
    float acc = 0.f;
    for (int j = 0; j < n; j++) {
        int s = list[j];
        float e = as_[s] + ad_[0];
        e = (e > 0.f) ? e : 0.2f * e;
        acc += __expf(e - m) * h2[(size_t)s * 64 + c];
    }
    float ref = fmaxf(acc / (den + 1e-16f) + b2[c], 0.f);
    if (bad(O2[c], ref, 1e-3f, 1e-3f)) atomicOr(diag, 1 << 4);
}

__global__ void k_cmp3(const float* __restrict__ O2, const float* __restrict__ W3,
                       const float* __restrict__ b3, const float* __restrict__ W4,
                       const float* __restrict__ av4s, const float* __restrict__ av4d,
                       const float* __restrict__ b4, const float* __restrict__ dinv,
                       const float* __restrict__ h4, const float* __restrict__ as_,
                       const float* __restrict__ ad_, const float* __restrict__ out,
                       const int* __restrict__ list, const int* __restrict__ lcnt,
                       int* __restrict__ diag) {
    if (threadIdx.x != 0) return;
    int n = min(lcnt[0], LCAP);
    float t[64];
    for (int k = 0; k < 64; k++) t[k] = 0.f;
    for (int j = 0; j < n; j++) {
        int s = list[j];
        float w = dinv[s] * dinv[0];
        for (int k = 0; k < 64; k++) t[k] += w * O2[(size_t)s * 64 + k];
    }
    float p0 = 0.f, p1 = 0.f;
    for (int c = 0; c < 128; c++) {
        float h3 = 0.f;
        for (int k = 0; k < 64; k++) h3 += t[k] * W3[k * 128 + c];
        h3 = fmaxf(h3 + b3[c], 0.f);
        p0 += h3 * W4[2 * c];
        p1 += h3 * W4[2 * c + 1];
    }
    if (bad(h4[0], p0, 1e-3f, 1e-3f) || bad(h4[1], p1, 1e-3f, 1e-3f))
        atomicOr(diag, 1 << 5);
    float m = -1e30f;
    for (int j = 0; j < n; j++) {
        float e = as_[list[j]] + ad_[0];
        e = (e > 0.f) ? e : 0.2f * e;
        m = fmaxf(m, e);
    }
    float den = 0.f, a0 = 0.f, a1 = 0.f;
    for (int j = 0; j < n; j++) {
        int s = list[j];
        float e = as_[s] + ad_[0];
        e = (e > 0.f) ? e : 0.2f * e;
        float p = __expf(e - m);
        den += p;
        a0 += p * h4[s * 2 + 0];
        a1 += p * h4[s * 2 + 1];
    }
    float v0 = a0 / (den + 1e-16f) + b4[0];
    float v1 = a1 / (den + 1e-16f) + b4[1];
    float mx = fmaxf(v0, v1);
    float lse = mx + logf(__expf(v0 - mx) + __expf(v1 - mx));
    if (bad(out[0], v0 - lse, 1e-3f, 1e-3f) || bad(out[1], v1 - lse, 1e-3f, 1e-3f))
        atomicOr(diag, 1 << 6);
}

__global__ void k_override(float* __restrict__ out, const int* __restrict__ diag) {
    int i = blockIdx.x * 256 + threadIdx.x;
    if (i >= NN * 2) return;
    int d = diag[0];
    if (d) out[i] = 4096.f + 512.f * (float)__ffs(d);
}

__global__ void k_sentinel(float* __restrict__ out, float v) {
    int i = blockIdx.x * 256 + threadIdx.x;
    if (i < NN * 2) out[i] = v;
}

// ---------------- launch ----------------

extern "C" void kernel_launch(void* const* d_in, const int* in_sizes, int n_in,
                              void* d_out, int out_size, void* d_ws, size_t ws_size,
                              hipStream_t stream) {
    const float* x    = (const float*)d_in[0];
    const int* ei     = (const int*)d_in[1];
    const float* W1   = (const float*)d_in[2];
    const float* b1   = (const float*)d_in[3];
    const float* W2   = (const float*)d_in[4];
    const float* av2s = (const float*)d_in[5];
    const float* av2d = (const float*)d_in[6];
    const float* b2   = (const float*)d_in[7];
    const float* W3   = (const float*)d_in[8];
    const float* b3   = (const float*)d_in[9];
    const float* W4   = (const float*)d_in[10];
    const float* av4s = (const float*)d_in[11];
    const float* av4d = (const float*)d_in[12];
    const float* b4   = (const float*)d_in[13];
    float* out = (float*)d_out;

    char* base = (char*)d_ws;
    size_t off = 0;
    auto alloc = [&](size_t bytes) {
        char* q = base + off;
        off += (bytes + 255) & ~(size_t)255;
        return q;
    };
    float* bufA  = (float*)alloc((size_t)NN * 64 * 4);   // 25.6 MB (h1/h2)
    float* bufB  = (float*)alloc((size_t)NN * 64 * 4);   // 25.6 MB (O1/O2)
    int* col     = (int*)alloc((size_t)NT * 4);          // 6.8 MB
    int* rowptr  = (int*)alloc((size_t)(NN + 1) * 4);
    int* cursor  = (int*)alloc((size_t)NN * 4);
    float* dinv  = (float*)alloc((size_t)NN * 4);
    float* as_   = (float*)alloc((size_t)NN * 4);
    float* ad_   = (float*)alloc((size_t)NN * 4);
    float* h4    = (float*)alloc((size_t)NN * 2 * 4);
    int* part    = (int*)alloc(512 * 4);
    int* flag    = (int*)alloc(256);
    int* diag    = (int*)alloc(256);
    int* lcnt    = (int*)alloc(256);
    int* list    = (int*)alloc(LCAP * 4);

    float code = 0.f;
    if (off > ws_size)            code = 1000.f + (float)(ws_size >> 20);
    else if (n_in != 14)          code = 2000.f + 10.f * (float)n_in;
    else if (in_sizes[0] != NN*7) code = 3000.f;
    else if (in_sizes[1] != 2*NE) code = 3200.f;
    else if (out_size != NN*2)    code = 3400.f;
    if (code != 0.f) {
        k_sentinel<<<(NN * 2 + 255) / 256, 256, 0, stream>>>(out, code);
        return;
    }

    const int NB = (NN + 255) / 256;

    k_diag0<<<1, 64, 0, stream>>>(diag, lcnt, flag);
    k_detect<<<1, 256, 0, stream>>>(ei, flag);
    k_deg_init<<<NB, 256, 0, stream>>>(cursor);
    k_count<<<(NE + 255) / 256, 256, 0, stream>>>(ei, flag, cursor);
    k_scan1<<<NB, 256, 0, stream>>>(cursor, rowptr, part);
    k_scan2<<<1, 512, 0, stream>>>(part, NB);
    k_scan3<<<NB, 256, 0, stream>>>(rowptr, part, cursor);
    k_prep<<<NB, 256, 0, stream>>>(rowptr, cursor, dinv);
    k_fill<<<(NT + 255) / 256, 256, 0, stream>>>(ei, flag, cursor, col);
    k_csrchk<<<NB, 256, 0, stream>>>(rowptr, cursor, diag);
    k_collect<<<(NT + 255) / 256, 256, 0, stream>>>(ei, flag, list, lcnt);

    k_mm1<<<NN * 32 / 256, 256, 0, stream>>>(x, W1, bufA);
    k_gcn_agg1<<<NN * 16 / 256, 256, 0, stream>>>(bufA, rowptr, col, dinv, b1, bufB);
    k_cmp1<<<1, 32, 0, stream>>>(x, W1, b1, bufA, bufB, dinv, rowptr, list, lcnt, diag);

    k_mm2<<<NN * 64 / 256, 256, 0, stream>>>(bufB, W2, av2s, av2d, bufA, as_, ad_);
    k_gat_agg2<<<NN * 32 / 256, 256, 0, stream>>>(bufA, as_, ad_, rowptr, col, b2, bufB);
    k_cmp2<<<1, 64, 0, stream>>>(bufA, bufB, as_, ad_, av2s, av2d, b2, list, lcnt, diag);

    k_fused34<<<NN / 8, 256, 0, stream>>>(bufB, W3, b3, W4, av4s, av4d, rowptr, col,
                                          dinv, h4, as_, ad_);
    k_final<<<NB, 256, 0, stream>>>(h4, as_, ad_, rowptr, col, b4, out);
    k_cmp3<<<1, 64, 0, stream>>>(bufB, W3, b3, W4, av4s, av4d, b4, dinv, h4, as_, ad_,
                                 out, list, lcnt, diag);

    k_override<<<(NN * 2 + 255) / 256, 256, 0, stream>>>(out, diag);
}

// Round 9
// 663.712 us; speedup vs baseline: 1.2420x; 1.2420x over previous
//
#include <hip/hip_runtime.h>

#define NN 100000
#define NE 1600000
#define NT (NN + NE)

static __device__ __forceinline__ int clampN(int s) {
    return ((unsigned)s < (unsigned)NN) ? s : 0;
}

// edge index loaders: is32==1 -> packed int32 [2][NE]; is32==0 -> int64 pairs
static __device__ __forceinline__ int ld_src(const int* ei, int is32, int e) {
    return is32 ? ei[e] : ei[2 * e];
}
static __device__ __forceinline__ int ld_dst(const int* ei, int is32, int e) {
    return is32 ? ei[NE + e] : ei[2 * NE + 2 * e];
}

__global__ void k_flag0(int* flag) {
    if (threadIdx.x == 0 && blockIdx.x == 0) flag[0] = 0;
}

__global__ void k_detect(const int* __restrict__ ei, int* __restrict__ flag) {
    int nz = 0;
    for (int i = threadIdx.x; i < 4096; i += 256) nz |= ei[2 * i + 1];
    if (nz) atomicOr(flag, 1);
}

// ---------------- CSR construction ----------------

__global__ void k_deg_init(int* __restrict__ cursor) {
    int i = blockIdx.x * 256 + threadIdx.x;
    if (i < NN) cursor[i] = 1;  // self-loop
}

__global__ void k_count(const int* __restrict__ ei, const int* __restrict__ flag,
                        int* __restrict__ cursor) {
    int e = blockIdx.x * 256 + threadIdx.x;
    if (e >= NE) return;
    int d = ld_dst(ei, flag[0], e);
    if ((unsigned)d < (unsigned)NN) atomicAdd(&cursor[d], 1);
}

__global__ void k_scan1(const int* __restrict__ deg, int* __restrict__ rowptr,
                        int* __restrict__ part) {
    __shared__ int sm[256];
    int i = blockIdx.x * 256 + threadIdx.x;
    int v = (i < NN) ? deg[i] : 0;
    sm[threadIdx.x] = v;
    __syncthreads();
    for (int off = 1; off < 256; off <<= 1) {
        int t = (threadIdx.x >= off) ? sm[threadIdx.x - off] : 0;
        __syncthreads();
        sm[threadIdx.x] += t;
        __syncthreads();
    }
    if (i < NN) rowptr[i] = sm[threadIdx.x] - v;
    if (threadIdx.x == 255) part[blockIdx.x] = sm[255];
}

__global__ void k_scan2(int* __restrict__ part, int nb) {
    __shared__ int sm[512];
    int t = threadIdx.x;
    int v = (t < nb) ? part[t] : 0;
    sm[t] = v;
    __syncthreads();
    for (int off = 1; off < 512; off <<= 1) {
        int u = (t >= off) ? sm[t - off] : 0;
        __syncthreads();
        sm[t] += u;
        __syncthreads();
    }
    if (t < nb) part[t] = sm[t] - v;
}

__global__ void k_scan3(int* __restrict__ rowptr, const int* __restrict__ part,
                        const int* __restrict__ deg) {
    int i = blockIdx.x * 256 + threadIdx.x;
    if (i < NN) {
        int r = rowptr[i] + part[blockIdx.x];
        rowptr[i] = r;
        if (i == NN - 1) rowptr[NN] = r + deg[i];
    }
}

__global__ void k_prep(const int* __restrict__ rowptr, int* __restrict__ cursor,
                       float* __restrict__ dinv) {
    int i = blockIdx.x * 256 + threadIdx.x;
    if (i < NN) {
        int b = rowptr[i];
        int d = rowptr[i + 1] - b;
        cursor[i] = b;
        dinv[i] = rsqrtf((float)(d > 0 ? d : 1));
    }
}

__global__ void k_fill(const int* __restrict__ ei, const int* __restrict__ flag,
                       int* __restrict__ cursor, int* __restrict__ col) {
    int e = blockIdx.x * 256 + threadIdx.x;
    if (e < NE) {
        int is32 = flag[0];
        int d = ld_dst(ei, is32, e);
        if ((unsigned)d < (unsigned)NN) {
            int s = clampN(ld_src(ei, is32, e));
            int p = atomicAdd(&cursor[d], 1);
            if ((unsigned)p < (unsigned)NT) col[p] = s;
        }
    } else if (e < NT) {
        int i = e - NE;
        int p = atomicAdd(&cursor[i], 1);
        if ((unsigned)p < (unsigned)NT) col[p] = i;
    }
}

// ---------------- small precompute ----------------

// pad x (7ch) into 8-float rows
__global__ void k_padx(const float* __restrict__ x, float* __restrict__ xp) {
    int idx = blockIdx.x * 256 + threadIdx.x;  // NN*8 exact
    int n = idx >> 3, c = idx & 7;
    xp[idx] = (c < 7) ? x[n * 7 + c] : 0.f;
}

// va2 = W2 @ a_src2, vd2 = W2 @ a_dst2  (32-vectors)
__global__ void k_vecs(const float* __restrict__ W2, const float* __restrict__ a2s,
                       const float* __restrict__ a2d, float* __restrict__ va2,
                       float* __restrict__ vd2) {
    int t = threadIdx.x;  // 64
    if (t < 32) {
        float a = 0.f;
        for (int c = 0; c < 64; c++) a += W2[t * 64 + c] * a2s[c];
        va2[t] = a;
    } else {
        int k = t - 32;
        float a = 0.f;
        for (int c = 0; c < 64; c++) a += W2[k * 64 + c] * a2d[c];
        vd2[k] = a;
    }
}

// ---------------- aggregations ----------------

// GCN-1 aggregate over padded x: 8 ch, 8 lanes/node (32 B rows)
__global__ void __launch_bounds__(256) k_agg1(const float* __restrict__ xp,
                                              const int* __restrict__ rowptr,
                                              const int* __restrict__ col,
                                              const float* __restrict__ dinv,
                                              float* __restrict__ T1) {
    int gid = blockIdx.x * 256 + threadIdx.x;  // NN*8 exact
    int n = gid >> 3;
    int lane = gid & 7;
    int beg = rowptr[n], end = rowptr[n + 1];
    float dn = dinv[n];
    float acc = 0.f;
    #pragma unroll 4
    for (int e = beg; e < end; e++) {
        int s = clampN(col[e]);
        acc += dinv[s] * dn * xp[s * 8 + lane];
    }
    T1[n * 8 + lane] = acc;
}

// O1 = ReLU(T1 @ W1 + b1)  (7->32)  + alpha2 dots via half-wave reduction
__global__ void k_mm1a(const float* __restrict__ T1, const float* __restrict__ W1,
                       const float* __restrict__ b1, const float* __restrict__ va2,
                       const float* __restrict__ vd2, float* __restrict__ O1,
                       float* __restrict__ as_, float* __restrict__ ad_) {
    int idx = blockIdx.x * 256 + threadIdx.x;  // NN*32 exact
    int n = idx >> 5, c = idx & 31;
    const float* t1 = T1 + (size_t)n * 8;
    float acc = 0.f;
    #pragma unroll
    for (int k = 0; k < 7; k++) acc += t1[k] * W1[k * 32 + c];
    float o = fmaxf(acc + b1[c], 0.f);
    O1[(size_t)n * 32 + c] = o;
    float vs = o * va2[c];
    float vd = o * vd2[c];
    #pragma unroll
    for (int off = 16; off > 0; off >>= 1) {
        vs += __shfl_down(vs, off, 32);
        vd += __shfl_down(vd, off, 32);
    }
    if (c == 0) { as_[n] = vs; ad_[n] = vd; }
}

// GAT-2 aggregate over O1: 32 ch, 32 lanes/node (128 B rows), online softmax
__global__ void __launch_bounds__(256) k_agg2(const float* __restrict__ O1,
                                              const float* __restrict__ as_,
                                              const float* __restrict__ ad_,
                                              const int* __restrict__ rowptr,
                                              const int* __restrict__ col,
                                              float* __restrict__ T2) {
    int gid = blockIdx.x * 256 + threadIdx.x;  // NN*32 exact
    int n = gid >> 5;
    int lane = gid & 31;
    int beg = rowptr[n], end = rowptr[n + 1];
    float adn = ad_[n];
    float m = -1e30f, denom = 0.f, acc = 0.f;
    for (int e = beg; e < end; e++) {
        int s = clampN(col[e]);
        float ee = as_[s] + adn;
        ee = (ee > 0.f) ? ee : 0.2f * ee;        // leaky relu
        float mn = fmaxf(m, ee);
        float sc = __expf(m - mn);
        float p = __expf(ee - mn);
        denom = denom * sc + p;
        acc = acc * sc + p * O1[(size_t)s * 32 + lane];
        m = mn;
    }
    T2[(size_t)n * 32 + lane] = acc / (denom + 1e-16f);
}

// O2 = ReLU(T2 @ W2 + b2)  (32->64)
__global__ void k_mm2(const float* __restrict__ T2, const float* __restrict__ W2,
                      const float* __restrict__ b2, float* __restrict__ O2) {
    int gid = blockIdx.x * 256 + threadIdx.x;  // NN*64 exact
    int n = gid >> 6, c = gid & 63;
    const float* t2 = T2 + (size_t)n * 32;
    float acc = 0.f;
    #pragma unroll
    for (int k = 0; k < 32; k++) acc += t2[k] * W2[k * 64 + c];
    O2[(size_t)n * 64 + c] = fmaxf(acc + b2[c], 0.f);
}

// Fused layer 3+4 projection: GCN-agg O2 (64ch) -> W3 -> relu -> W4 -> h4/alphas
__global__ void __launch_bounds__(256) k_fused34(const float* __restrict__ O,
                                                 const float* __restrict__ W3,
                                                 const float* __restrict__ b3,
                                                 const float* __restrict__ W4,
                                                 const float* __restrict__ av4s,
                                                 const float* __restrict__ av4d,
                                                 const int* __restrict__ rowptr,
                                                 const int* __restrict__ col,
                                                 const float* __restrict__ dinv,
                                                 float* __restrict__ h4,
                                                 float* __restrict__ as_,
                                                 float* __restrict__ ad_) {
    __shared__ float sW3[64 * 128];
    __shared__ float sW4[128 * 2];
    __shared__ float sb3[128];
    for (int i = threadIdx.x; i < 64 * 128; i += 256) sW3[i] = W3[i];
    if (threadIdx.x < 128) {
        sW4[2 * threadIdx.x] = W4[2 * threadIdx.x];
        sW4[2 * threadIdx.x + 1] = W4[2 * threadIdx.x + 1];
        sb3[threadIdx.x] = b3[threadIdx.x];
    }
    __syncthreads();

    int wid = threadIdx.x >> 6;
    int lane = threadIdx.x & 63;
    int half = lane >> 5;
    int lw = lane & 31;
    int n = blockIdx.x * 8 + wid * 2 + half;

    int beg = rowptr[n], end = rowptr[n + 1];
    float dn = dinv[n];
    float ax = 0.f, ay = 0.f;   // channels 2*lw, 2*lw+1
    #pragma unroll 2
    for (int e = beg; e < end; e++) {
        int s = clampN(col[e]);
        float w = dinv[s] * dn;
        float2 f = *(const float2*)(O + (size_t)s * 64 + 2 * lw);
        ax += w * f.x;
        ay += w * f.y;
    }

    float a0 = 0.f, a1 = 0.f, a2 = 0.f, a3 = 0.f;
    #pragma unroll
    for (int k = 0; k < 64; k++) {
        int srcl = half * 32 + (k >> 1);
        float tk = (k & 1) ? __shfl(ay, srcl, 64) : __shfl(ax, srcl, 64);
        const float* wrow = &sW3[k * 128 + lw];
        a0 += tk * wrow[0];
        a1 += tk * wrow[32];
        a2 += tk * wrow[64];
        a3 += tk * wrow[96];
    }
    a0 = fmaxf(a0 + sb3[lw], 0.f);
    a1 = fmaxf(a1 + sb3[lw + 32], 0.f);
    a2 = fmaxf(a2 + sb3[lw + 64], 0.f);
    a3 = fmaxf(a3 + sb3[lw + 96], 0.f);

    float p0 = a0 * sW4[2 * lw] + a1 * sW4[2 * (lw + 32)] +
               a2 * sW4[2 * (lw + 64)] + a3 * sW4[2 * (lw + 96)];
    float p1 = a0 * sW4[2 * lw + 1] + a1 * sW4[2 * (lw + 32) + 1] +
               a2 * sW4[2 * (lw + 64) + 1] + a3 * sW4[2 * (lw + 96) + 1];
    #pragma unroll
    for (int off = 16; off > 0; off >>= 1) {
        p0 += __shfl_down(p0, off, 32);
        p1 += __shfl_down(p1, off, 32);
    }
    if (lw == 0) {
        h4[n * 2 + 0] = p0;
        h4[n * 2 + 1] = p1;
        as_[n] = p0 * av4s[0] + p1 * av4s[1];
        ad_[n] = p0 * av4d[0] + p1 * av4d[1];
    }
}

// final GAT (2 ch) + log_softmax
__global__ void k_final(const float* __restrict__ h4, const float* __restrict__ as_,
                        const float* __restrict__ ad_, const int* __restrict__ rowptr,
                        const int* __restrict__ col, const float* __restrict__ b,
                        float* __restrict__ out) {
    int n = blockIdx.x * 256 + threadIdx.x;
    if (n >= NN) return;
    int beg = rowptr[n], end = rowptr[n + 1];
    float adn = ad_[n];
    float m = -1e30f, denom = 0.f, a0 = 0.f, a1 = 0.f;
    for (int e = beg; e < end; e++) {
        int s = clampN(col[e]);
        float ee = as_[s] + adn;
        ee = (ee > 0.f) ? ee : 0.2f * ee;
        float mn = fmaxf(m, ee);
        float sc = __expf(m - mn);
        float p = __expf(ee - mn);
        denom = denom * sc + p;
        a0 = a0 * sc + p * h4[s * 2 + 0];
        a1 = a1 * sc + p * h4[s * 2 + 1];
        m = mn;
    }
    float inv = 1.0f / (denom + 1e-16f);
    float v0 = a0 * inv + b[0];
    float v1 = a1 * inv + b[1];
    float mx = fmaxf(v0, v1);
    float lse = mx + logf(__expf(v0 - mx) + __expf(v1 - mx));
    out[n * 2 + 0] = v0 - lse;
    out[n * 2 + 1] = v1 - lse;
}

__global__ void k_sentinel(float* __restrict__ out, float v) {
    int i = blockIdx.x * 256 + threadIdx.x;
    if (i < NN * 2) out[i] = v;
}

// ---------------- launch ----------------

extern "C" void kernel_launch(void* const* d_in, const int* in_sizes, int n_in,
                              void* d_out, int out_size, void* d_ws, size_t ws_size,
                              hipStream_t stream) {
    const float* x    = (const float*)d_in[0];
    const int* ei     = (const int*)d_in[1];
    const float* W1   = (const float*)d_in[2];
    const float* b1   = (const float*)d_in[3];
    const float* W2   = (const float*)d_in[4];
    const float* a2s  = (const float*)d_in[5];
    const float* a2d  = (const float*)d_in[6];
    const float* b2   = (const float*)d_in[7];
    const float* W3   = (const float*)d_in[8];
    const float* b3   = (const float*)d_in[9];
    const float* W4   = (const float*)d_in[10];
    const float* a4s  = (const float*)d_in[11];
    const float* a4d  = (const float*)d_in[12];
    const float* b4   = (const float*)d_in[13];
    float* out = (float*)d_out;

    char* base = (char*)d_ws;
    size_t off = 0;
    auto alloc = [&](size_t bytes) {
        char* q = base + off;
        off += (bytes + 255) & ~(size_t)255;
        return q;
    };
    float* bufA  = (float*)alloc((size_t)NN * 64 * 4);   // xp -> O1 -> O2
    float* bufB  = (float*)alloc((size_t)NN * 64 * 4);   // T1 -> T2
    int* col     = (int*)alloc((size_t)NT * 4);
    int* rowptr  = (int*)alloc((size_t)(NN + 1) * 4);
    int* cursor  = (int*)alloc((size_t)NN * 4);
    float* dinv  = (float*)alloc((size_t)NN * 4);
    float* as_   = (float*)alloc((size_t)NN * 4);
    float* ad_   = (float*)alloc((size_t)NN * 4);
    float* h4    = (float*)alloc((size_t)NN * 2 * 4);
    int* part    = (int*)alloc(512 * 4);
    int* flag    = (int*)alloc(256);
    float* va2   = (float*)alloc(32 * 4);
    float* vd2   = (float*)alloc(32 * 4);

    float code = 0.f;
    if (off > ws_size)            code = 1000.f + (float)(ws_size >> 20);
    else if (n_in != 14)          code = 2000.f + 10.f * (float)n_in;
    else if (out_size != NN * 2)  code = 3400.f;
    if (code != 0.f) {
        k_sentinel<<<(NN * 2 + 255) / 256, 256, 0, stream>>>(out, code);
        return;
    }

    const int NB = (NN + 255) / 256;

    // CSR build + small precompute
    k_flag0<<<1, 64, 0, stream>>>(flag);
    k_detect<<<1, 256, 0, stream>>>(ei, flag);
    k_deg_init<<<NB, 256, 0, stream>>>(cursor);
    k_count<<<(NE + 255) / 256, 256, 0, stream>>>(ei, flag, cursor);
    k_scan1<<<NB, 256, 0, stream>>>(cursor, rowptr, part);
    k_scan2<<<1, 512, 0, stream>>>(part, NB);
    k_scan3<<<NB, 256, 0, stream>>>(rowptr, part, cursor);
    k_prep<<<NB, 256, 0, stream>>>(rowptr, cursor, dinv);
    k_fill<<<(NT + 255) / 256, 256, 0, stream>>>(ei, flag, cursor, col);
    k_padx<<<NN * 8 / 256, 256, 0, stream>>>(x, bufA);
    k_vecs<<<1, 64, 0, stream>>>(W2, a2s, a2d, va2, vd2);

    // layer 1 (GCN 7->32): aggregate 8-ch x, then dense + alpha2
    k_agg1<<<NN * 8 / 256, 256, 0, stream>>>(bufA, rowptr, col, dinv, bufB);
    k_mm1a<<<NN * 32 / 256, 256, 0, stream>>>(bufB, W1, b1, va2, vd2, bufA, as_, ad_);
    // layer 2 (GAT 32->64): softmax-aggregate 32-ch O1, then dense
    k_agg2<<<NN * 32 / 256, 256, 0, stream>>>(bufA, as_, ad_, rowptr, col, bufB);
    k_mm2<<<NN * 64 / 256, 256, 0, stream>>>(bufB, W2, b2, bufA);
    // layers 3+4 fused: GCN-agg 64-ch O2 -> W3 -> relu -> W4 -> h4/alphas
    k_fused34<<<NN / 8, 256, 0, stream>>>(bufA, W3, b3, W4, a4s, a4d, rowptr, col,
                                          dinv, h4, as_, ad_);
    // layer 4 aggregation + log_softmax
    k_final<<<NB, 256, 0, stream>>>(h4, as_, ad_, rowptr, col, b4, out);
}

// Round 10
// 599.154 us; speedup vs baseline: 1.3758x; 1.1077x over previous
//
#include <hip/hip_runtime.h>

#define NN 100000
#define NE 1600000
#define NT (NN + NE)

static __device__ __forceinline__ int clampN(int s) {
    return ((unsigned)s < (unsigned)NN) ? s : 0;
}
static __device__ __forceinline__ int ld_src(const int* ei, int is32, int e) {
    return is32 ? ei[e] : ei[2 * e];
}
static __device__ __forceinline__ int ld_dst(const int* ei, int is32, int e) {
    return is32 ? ei[NE + e] : ei[2 * NE + 2 * e];
}

// ---------------- init: cursor=1, edge-dtype detect, padx, alpha2 vecs ----------------

__global__ void __launch_bounds__(256) k_init(const float* __restrict__ x,
                                              const float* __restrict__ W2,
                                              const float* __restrict__ a2s,
                                              const float* __restrict__ a2d,
                                              const int* __restrict__ ei,
                                              int* __restrict__ cursor,
                                              float* __restrict__ xp,
                                              float* __restrict__ va2,
                                              float* __restrict__ vd2,
                                              int* __restrict__ flag) {
    int idx = blockIdx.x * 256 + threadIdx.x;   // grid covers NN*8
    if (blockIdx.x == 0) {
        if (threadIdx.x == 0) flag[0] = 0;
        __syncthreads();
        int nz = 0;
        for (int i = threadIdx.x; i < 4096; i += 256) nz |= ei[2 * i + 1];
        if (nz) atomicOr(flag, 1);
    }
    if (blockIdx.x == 1 && threadIdx.x < 64) {
        int t = threadIdx.x;
        if (t < 32) {
            float a = 0.f;
            for (int c = 0; c < 64; c++) a += W2[t * 64 + c] * a2s[c];
            va2[t] = a;
        } else {
            int k = t - 32;
            float a = 0.f;
            for (int c = 0; c < 64; c++) a += W2[k * 64 + c] * a2d[c];
            vd2[k] = a;
        }
    }
    if (idx < NN) cursor[idx] = 1;               // self-loop seed
    if (idx < NN * 8) {
        int n = idx >> 3, c = idx & 7;
        xp[idx] = (c < 7) ? x[n * 7 + c] : 0.f;  // pad 7->8
    }
}

// ---------------- CSR construction ----------------

__global__ void k_count(const int* __restrict__ ei, const int* __restrict__ flag,
                        int* __restrict__ cursor) {
    int e = blockIdx.x * 256 + threadIdx.x;
    if (e >= NE) return;
    int d = ld_dst(ei, flag[0], e);
    if ((unsigned)d < (unsigned)NN) atomicAdd(&cursor[d], 1);
}

__global__ void k_scan1(const int* __restrict__ deg, int* __restrict__ rowptr,
                        int* __restrict__ part) {
    __shared__ int sm[256];
    int i = blockIdx.x * 256 + threadIdx.x;
    int v = (i < NN) ? deg[i] : 0;
    sm[threadIdx.x] = v;
    __syncthreads();
    for (int off = 1; off < 256; off <<= 1) {
        int t = (threadIdx.x >= off) ? sm[threadIdx.x - off] : 0;
        __syncthreads();
        sm[threadIdx.x] += t;
        __syncthreads();
    }
    if (i < NN) rowptr[i] = sm[threadIdx.x] - v;
    if (threadIdx.x == 255) part[blockIdx.x] = sm[255];
}

__global__ void k_scan2(int* __restrict__ part, int nb) {
    __shared__ int sm[512];
    int t = threadIdx.x;
    int v = (t < nb) ? part[t] : 0;
    sm[t] = v;
    __syncthreads();
    for (int off = 1; off < 512; off <<= 1) {
        int u = (t >= off) ? sm[t - off] : 0;
        __syncthreads();
        sm[t] += u;
        __syncthreads();
    }
    if (t < nb) part[t] = sm[t] - v;
}

// scan3 + prep merged: finalize rowptr, set fill cursor, dinv from deg (=cursor's counts)
__global__ void k_scan3(int* __restrict__ rowptr, const int* __restrict__ part,
                        int* __restrict__ cursor, float* __restrict__ dinv) {
    int i = blockIdx.x * 256 + threadIdx.x;
    if (i < NN) {
        int d = cursor[i];                       // original degree count
        int r = rowptr[i] + part[blockIdx.x];
        rowptr[i] = r;
        cursor[i] = r;                           // fill cursor
        dinv[i] = rsqrtf((float)(d > 0 ? d : 1));
        if (i == NN - 1) rowptr[NN] = r + d;
    }
}

__global__ void k_fill(const int* __restrict__ ei, const int* __restrict__ flag,
                       int* __restrict__ cursor, int* __restrict__ col) {
    int e = blockIdx.x * 256 + threadIdx.x;
    if (e < NE) {
        int is32 = flag[0];
        int d = ld_dst(ei, is32, e);
        if ((unsigned)d < (unsigned)NN) {
            int s = clampN(ld_src(ei, is32, e));
            int p = atomicAdd(&cursor[d], 1);
            if ((unsigned)p < (unsigned)NT) col[p] = s;
        }
    } else if (e < NT) {
        int i = e - NE;
        int p = atomicAdd(&cursor[i], 1);
        if ((unsigned)p < (unsigned)NT) col[p] = i;
    }
}

// ---------------- layer 1: GCN aggregate (8ch) then dense 7->32 ----------------

// 2 lanes/node, float4 each
__global__ void __launch_bounds__(256) k_agg1(const float* __restrict__ xp,
                                              const int* __restrict__ rowptr,
                                              const int* __restrict__ col,
                                              const float* __restrict__ dinv,
                                              float* __restrict__ T1) {
    int gid = blockIdx.x * 256 + threadIdx.x;
    int n = gid >> 1;
    int lane = gid & 1;
    if (n >= NN) return;
    int beg = rowptr[n], end = rowptr[n + 1];
    float4 acc = {0.f, 0.f, 0.f, 0.f};
    #pragma unroll 4
    for (int e = beg; e < end; e++) {
        int s = clampN(col[e]);
        float w = dinv[s];
        float4 f = *(const float4*)(xp + (size_t)s * 8 + lane * 4);
        acc.x += w * f.x; acc.y += w * f.y; acc.z += w * f.z; acc.w += w * f.w;
    }
    float dn = dinv[n];
    acc.x *= dn; acc.y *= dn; acc.z *= dn; acc.w *= dn;
    *(float4*)(T1 + (size_t)n * 8 + lane * 4) = acc;
}

// O1 = ReLU(T1 @ W1 + b1) + alpha2 dots (32 lanes/node)
__global__ void k_mm1a(const float* __restrict__ T1, const float* __restrict__ W1,
                       const float* __restrict__ b1, const float* __restrict__ va2,
                       const float* __restrict__ vd2, float* __restrict__ O1,
                       float* __restrict__ as_, float* __restrict__ ad_) {
    int idx = blockIdx.x * 256 + threadIdx.x;  // NN*32 exact
    int n = idx >> 5, c = idx & 31;
    const float* t1 = T1 + (size_t)n * 8;
    float acc = 0.f;
    #pragma unroll
    for (int k = 0; k < 7; k++) acc += t1[k] * W1[k * 32 + c];
    float o = fmaxf(acc + b1[c], 0.f);
    O1[(size_t)n * 32 + c] = o;
    float vs = o * va2[c];
    float vd = o * vd2[c];
    #pragma unroll
    for (int off = 16; off > 0; off >>= 1) {
        vs += __shfl_down(vs, off, 32);
        vd += __shfl_down(vd, off, 32);
    }
    if (c == 0) { as_[n] = vs; ad_[n] = vd; }
}

// ---------------- layer 2: GAT two-pass softmax aggregate (32ch), then dense ----------------

// 8 lanes/node, float4 each; pass1 strided max + shfl_xor(w=8); pass2 independent FMAs
__global__ void __launch_bounds__(256) k_agg2(const float* __restrict__ O1,
                                              const float* __restrict__ as_,
                                              const float* __restrict__ ad_,
                                              const int* __restrict__ rowptr,
                                              const int* __restrict__ col,
                                              float* __restrict__ T2) {
    int gid = blockIdx.x * 256 + threadIdx.x;  // NN*8 exact
    int n = gid >> 3;
    int lane = gid & 7;
    int beg = rowptr[n], end = rowptr[n + 1];
    float adn = ad_[n];
    float m = -1e30f;
    for (int e = beg + lane; e < end; e += 8) {
        float ee = as_[clampN(col[e])] + adn;
        ee = (ee > 0.f) ? ee : 0.2f * ee;
        m = fmaxf(m, ee);
    }
    m = fmaxf(m, __shfl_xor(m, 1, 8));
    m = fmaxf(m, __shfl_xor(m, 2, 8));
    m = fmaxf(m, __shfl_xor(m, 4, 8));
    float den = 0.f;
    float4 acc = {0.f, 0.f, 0.f, 0.f};
    #pragma unroll 2
    for (int e = beg; e < end; e++) {
        int s = clampN(col[e]);
        float ee = as_[s] + adn;
        ee = (ee > 0.f) ? ee : 0.2f * ee;
        float p = __expf(ee - m);
        den += p;
        float4 f = *(const float4*)(O1 + (size_t)s * 32 + lane * 4);
        acc.x += p * f.x; acc.y += p * f.y; acc.z += p * f.z; acc.w += p * f.w;
    }
    float inv = 1.0f / (den + 1e-16f);
    acc.x *= inv; acc.y *= inv; acc.z *= inv; acc.w *= inv;
    *(float4*)(T2 + (size_t)n * 32 + lane * 4) = acc;
}

// O2 = ReLU(T2 @ W2 + b2) * dinv[n]   (dinv folded for layer-3 gather)
__global__ void k_mm2(const float* __restrict__ T2, const float* __restrict__ W2,
                      const float* __restrict__ b2, const float* __restrict__ dinv,
                      float* __restrict__ O2) {
    int gid = blockIdx.x * 256 + threadIdx.x;  // NN*64 exact
    int n = gid >> 6, c = gid & 63;
    const float* t2 = T2 + (size_t)n * 32;
    float acc = 0.f;
    #pragma unroll
    for (int k = 0; k < 32; k++) acc += t2[k] * W2[k * 64 + c];
    O2[(size_t)n * 64 + c] = fmaxf(acc + b2[c], 0.f) * dinv[n];
}

// ---------------- layer 3: pure gather-sum (dinv pre-folded), 16 lanes/node ----------------

__global__ void __launch_bounds__(256) k_agg3(const float* __restrict__ O2,
                                              const int* __restrict__ rowptr,
                                              const int* __restrict__ col,
                                              const float* __restrict__ dinv,
                                              float* __restrict__ T3) {
    int gid = blockIdx.x * 256 + threadIdx.x;  // NN*16 exact
    int n = gid >> 4;
    int lane = gid & 15;
    int beg = rowptr[n], end = rowptr[n + 1];
    float4 acc = {0.f, 0.f, 0.f, 0.f};
    #pragma unroll 4
    for (int e = beg; e < end; e++) {
        int s = clampN(col[e]);
        float4 f = *(const float4*)(O2 + (size_t)s * 64 + lane * 4);
        acc.x += f.x; acc.y += f.y; acc.z += f.z; acc.w += f.w;
    }
    float dn = dinv[n];
    acc.x *= dn; acc.y *= dn; acc.z *= dn; acc.w *= dn;
    *(float4*)(T3 + (size_t)n * 64 + lane * 4) = acc;
}

// ---------------- dense: T3 -> W3 -> relu -> W4 -> h4, alpha4 ----------------

__global__ void __launch_bounds__(256) k_mm34(const float* __restrict__ T3,
                                              const float* __restrict__ W3,
                                              const float* __restrict__ b3,
                                              const float* __restrict__ W4,
                                              const float* __restrict__ av4s,
                                              const float* __restrict__ av4d,
                                              float* __restrict__ h4,
                                              float* __restrict__ as_,
                                              float* __restrict__ ad_) {
    __shared__ float sW3[64 * 128];
    __shared__ float sW4[128 * 2];
    __shared__ float sb3[128];
    for (int i = threadIdx.x; i < 64 * 128; i += 256) sW3[i] = W3[i];
    if (threadIdx.x < 128) {
        sW4[2 * threadIdx.x] = W4[2 * threadIdx.x];
        sW4[2 * threadIdx.x + 1] = W4[2 * threadIdx.x + 1];
        sb3[threadIdx.x] = b3[threadIdx.x];
    }
    __syncthreads();

    int wid = threadIdx.x >> 6;
    int lane = threadIdx.x & 63;
    int half = lane >> 5;
    int lw = lane & 31;
    int n = blockIdx.x * 8 + wid * 2 + half;   // grid NN/8 exact

    float2 t = *(const float2*)(T3 + (size_t)n * 64 + 2 * lw);
    float ax = t.x, ay = t.y;                   // channels 2lw, 2lw+1

    float a0 = 0.f, a1 = 0.f, a2 = 0.f, a3 = 0.f;
    #pragma unroll
    for (int k = 0; k < 64; k++) {
        int srcl = half * 32 + (k >> 1);
        float tk = (k & 1) ? __shfl(ay, srcl, 64) : __shfl(ax, srcl, 64);
        const float* wrow = &sW3[k * 128 + lw];
        a0 += tk * wrow[0];
        a1 += tk * wrow[32];
        a2 += tk * wrow[64];
        a3 += tk * wrow[96];
    }
    a0 = fmaxf(a0 + sb3[lw], 0.f);
    a1 = fmaxf(a1 + sb3[lw + 32], 0.f);
    a2 = fmaxf(a2 + sb3[lw + 64], 0.f);
    a3 = fmaxf(a3 + sb3[lw + 96], 0.f);

    float p0 = a0 * sW4[2 * lw] + a1 * sW4[2 * (lw + 32)] +
               a2 * sW4[2 * (lw + 64)] + a3 * sW4[2 * (lw + 96)];
    float p1 = a0 * sW4[2 * lw + 1] + a1 * sW4[2 * (lw + 32) + 1] +
               a2 * sW4[2 * (lw + 64) + 1] + a3 * sW4[2 * (lw + 96) + 1];
    #pragma unroll
    for (int off = 16; off > 0; off >>= 1) {
        p0 += __shfl_down(p0, off, 32);
        p1 += __shfl_down(p1, off, 32);
    }
    if (lw == 0) {
        h4[n * 2 + 0] = p0;
        h4[n * 2 + 1] = p1;
        as_[n] = p0 * av4s[0] + p1 * av4s[1];
        ad_[n] = p0 * av4d[0] + p1 * av4d[1];
    }
}

// ---------------- final GAT (2ch) + log_softmax, two-pass softmax ----------------

__global__ void k_final(const float* __restrict__ h4, const float* __restrict__ as_,
                        const float* __restrict__ ad_, const int* __restrict__ rowptr,
                        const int* __restrict__ col, const float* __restrict__ b,
                        float* __restrict__ out) {
    int n = blockIdx.x * 256 + threadIdx.x;
    if (n >= NN) return;
    int beg = rowptr[n], end = rowptr[n + 1];
    float adn = ad_[n];
    float m = -1e30f;
    for (int e = beg; e < end; e++) {
        float ee = as_[clampN(col[e])] + adn;
        ee = (ee > 0.f) ? ee : 0.2f * ee;
        m = fmaxf(m, ee);
    }
    float den = 0.f, a0 = 0.f, a1 = 0.f;
    for (int e = beg; e < end; e++) {
        int s = clampN(col[e]);
        float ee = as_[s] + adn;
        ee = (ee > 0.f) ? ee : 0.2f * ee;
        float p = __expf(ee - m);
        den += p;
        float2 h = *(const float2*)(h4 + (size_t)s * 2);
        a0 += p * h.x;
        a1 += p * h.y;
    }
    float inv = 1.0f / (den + 1e-16f);
    float v0 = a0 * inv + b[0];
    float v1 = a1 * inv + b[1];
    float mx = fmaxf(v0, v1);
    float lse = mx + logf(__expf(v0 - mx) + __expf(v1 - mx));
    out[n * 2 + 0] = v0 - lse;
    out[n * 2 + 1] = v1 - lse;
}

__global__ void k_sentinel(float* __restrict__ out, float v) {
    int i = blockIdx.x * 256 + threadIdx.x;
    if (i < NN * 2) out[i] = v;
}

// ---------------- launch ----------------

extern "C" void kernel_launch(void* const* d_in, const int* in_sizes, int n_in,
                              void* d_out, int out_size, void* d_ws, size_t ws_size,
                              hipStream_t stream) {
    const float* x    = (const float*)d_in[0];
    const int* ei     = (const int*)d_in[1];
    const float* W1   = (const float*)d_in[2];
    const float* b1   = (const float*)d_in[3];
    const float* W2   = (const float*)d_in[4];
    const float* a2s  = (const float*)d_in[5];
    const float* a2d  = (const float*)d_in[6];
    const float* b2   = (const float*)d_in[7];
    const float* W3   = (const float*)d_in[8];
    const float* b3   = (const float*)d_in[9];
    const float* W4   = (const float*)d_in[10];
    const float* a4s  = (const float*)d_in[11];
    const float* a4d  = (const float*)d_in[12];
    const float* b4   = (const float*)d_in[13];
    float* out = (float*)d_out;

    char* base = (char*)d_ws;
    size_t off = 0;
    auto alloc = [&](size_t bytes) {
        char* q = base + off;
        off += (bytes + 255) & ~(size_t)255;
        return q;
    };
    float* bufA  = (float*)alloc((size_t)NN * 64 * 4);   // xp -> O1 -> O2
    float* bufB  = (float*)alloc((size_t)NN * 64 * 4);   // T1 -> T2 -> T3
    int* col     = (int*)alloc((size_t)NT * 4);
    int* rowptr  = (int*)alloc((size_t)(NN + 1) * 4);
    int* cursor  = (int*)alloc((size_t)NN * 4);
    float* dinv  = (float*)alloc((size_t)NN * 4);
    float* as_   = (float*)alloc((size_t)NN * 4);
    float* ad_   = (float*)alloc((size_t)NN * 4);
    float* h4    = (float*)alloc((size_t)NN * 2 * 4);
    int* part    = (int*)alloc(512 * 4);
    int* flag    = (int*)alloc(256);
    float* va2   = (float*)alloc(32 * 4);
    float* vd2   = (float*)alloc(32 * 4);

    float code = 0.f;
    if (off > ws_size)            code = 1000.f + (float)(ws_size >> 20);
    else if (n_in != 14)          code = 2000.f + 10.f * (float)n_in;
    else if (out_size != NN * 2)  code = 3400.f;
    if (code != 0.f) {
        k_sentinel<<<(NN * 2 + 255) / 256, 256, 0, stream>>>(out, code);
        return;
    }

    const int NB = (NN + 255) / 256;

    // init + CSR build
    k_init<<<NN * 8 / 256, 256, 0, stream>>>(x, W2, a2s, a2d, ei, cursor, bufA,
                                             va2, vd2, flag);
    k_count<<<(NE + 255) / 256, 256, 0, stream>>>(ei, flag, cursor);
    k_scan1<<<NB, 256, 0, stream>>>(cursor, rowptr, part);
    k_scan2<<<1, 512, 0, stream>>>(part, NB);
    k_scan3<<<NB, 256, 0, stream>>>(rowptr, part, cursor, dinv);
    k_fill<<<(NT + 255) / 256, 256, 0, stream>>>(ei, flag, cursor, col);

    // layer 1: GCN
    k_agg1<<<(NN * 2 + 255) / 256, 256, 0, stream>>>(bufA, rowptr, col, dinv, bufB);
    k_mm1a<<<NN * 32 / 256, 256, 0, stream>>>(bufB, W1, b1, va2, vd2, bufA, as_, ad_);
    // layer 2: GAT
    k_agg2<<<NN * 8 / 256, 256, 0, stream>>>(bufA, as_, ad_, rowptr, col, bufB);
    k_mm2<<<NN * 64 / 256, 256, 0, stream>>>(bufB, W2, b2, dinv, bufA);
    // layer 3: GCN (dinv folded into O2)
    k_agg3<<<NN * 16 / 256, 256, 0, stream>>>(bufA, rowptr, col, dinv, bufB);
    // layers 3/4 dense + alpha4
    k_mm34<<<NN / 8, 256, 0, stream>>>(bufB, W3, b3, W4, a4s, a4d, h4, as_, ad_);
    // layer 4 aggregation + log_softmax
    k_final<<<NB, 256, 0, stream>>>(h4, as_, ad_, rowptr, col, b4, out);
}

// Round 11
// 453.166 us; speedup vs baseline: 1.8190x; 1.3222x over previous
//
#include <hip/hip_runtime.h>

#define NN 100000
#define NE 1600000
#define NT (NN + NE)
#define NBKT 256
#define BSZ 391          // nodes per bucket; 256*391 = 100096 >= NN
#define BCAP 10240       // staging entries per bucket (avg 6641, 45 sigma slack)

static __device__ __forceinline__ int clampN(int s) {
    return ((unsigned)s < (unsigned)NN) ? s : 0;
}
static __device__ __forceinline__ int ld_src(const int* ei, int is32, int e) {
    return is32 ? ei[e] : ei[2 * e];
}
static __device__ __forceinline__ int ld_dst(const int* ei, int is32, int e) {
    return is32 ? ei[NE + e] : ei[2 * NE + 2 * e];
}

// ---------------- init: flag detect, padx, alpha2 vecs, zero bucket cursors ----------------

__global__ void __launch_bounds__(256) k_init(const float* __restrict__ x,
                                              const float* __restrict__ W2,
                                              const float* __restrict__ a2s,
                                              const float* __restrict__ a2d,
                                              const int* __restrict__ ei,
                                              float* __restrict__ xp,
                                              float* __restrict__ va2,
                                              float* __restrict__ vd2,
                                              int* __restrict__ flag,
                                              int* __restrict__ gcur) {
    int idx = blockIdx.x * 256 + threadIdx.x;   // grid covers NN*8
    if (blockIdx.x == 0) {
        if (threadIdx.x == 0) flag[0] = 0;
        __syncthreads();
        int nz = 0;
        for (int i = threadIdx.x; i < 4096; i += 256) nz |= ei[2 * i + 1];
        if (nz) atomicOr(flag, 1);
        if (threadIdx.x < NBKT) gcur[threadIdx.x] = 0;
    }
    if (blockIdx.x == 1 && threadIdx.x < 64) {
        int t = threadIdx.x;
        if (t < 32) {
            float a = 0.f;
            for (int c = 0; c < 64; c++) a += W2[t * 64 + c] * a2s[c];
            va2[t] = a;
        } else {
            int k = t - 32;
            float a = 0.f;
            for (int c = 0; c < 64; c++) a += W2[k * 64 + c] * a2d[c];
            vd2[k] = a;
        }
    }
    if (idx < NN * 8) {
        int n = idx >> 3, c = idx & 7;
        xp[idx] = (c < 7) ? x[n * 7 + c] : 0.f;  // pad 7->8
    }
}

// ---------------- phase B1: bin edges (incl self-loops) into bucket staging ----------------

__global__ void __launch_bounds__(256) k_binA(const int* __restrict__ ei,
                                              const int* __restrict__ flag,
                                              int* __restrict__ gcur,
                                              unsigned int* __restrict__ staging) {
    __shared__ int hist[NBKT];
    __shared__ int gbase[NBKT];
    __shared__ int cnt2[NBKT];
    int tid = threadIdx.x;
    if (tid < NBKT) { hist[tid] = 0; }
    __syncthreads();

    int base = blockIdx.x * 4096;
    int is32 = flag[0];
    int d[16], s[16];
    #pragma unroll
    for (int i = 0; i < 16; i++) {
        int e = base + i * 256 + tid;
        d[i] = -1;
        if (e < NE) {
            int dd = ld_dst(ei, is32, e);
            if ((unsigned)dd < (unsigned)NN) { d[i] = dd; s[i] = clampN(ld_src(ei, is32, e)); }
        } else if (e < NT) {
            d[i] = e - NE; s[i] = e - NE;        // self-loop
        }
        if (d[i] >= 0) atomicAdd(&hist[d[i] / BSZ], 1);
    }
    __syncthreads();
    if (tid < NBKT) {
        int c = hist[tid];
        gbase[tid] = c ? atomicAdd(&gcur[tid], c) : 0;
        cnt2[tid] = 0;
    }
    __syncthreads();
    #pragma unroll
    for (int i = 0; i < 16; i++) {
        if (d[i] >= 0) {
            int b = d[i] / BSZ;
            int pos = gbase[b] + atomicAdd(&cnt2[b], 1);
            if (pos < BCAP)
                staging[(size_t)b * BCAP + pos] =
                    ((unsigned)(d[i] - b * BSZ) << 17) | (unsigned)s[i];
        }
    }
}

// ---------------- phase B2a: per-bucket degree histogram (dense writes) ----------------

__global__ void __launch_bounds__(256) k_hist(const unsigned int* __restrict__ staging,
                                              const int* __restrict__ gcur,
                                              int* __restrict__ deg) {
    __shared__ int h[BSZ];
    int b = blockIdx.x;
    for (int l = threadIdx.x; l < BSZ; l += 256) h[l] = 0;
    __syncthreads();
    int cnt = min(gcur[b], BCAP);
    const unsigned int* st = staging + (size_t)b * BCAP;
    for (int i = threadIdx.x; i < cnt; i += 256)
        atomicAdd(&h[st[i] >> 17], 1);
    __syncthreads();
    for (int l = threadIdx.x; l < BSZ; l += 256) {
        int g = b * BSZ + l;
        if (g < NN) deg[g] = h[l];
    }
}

// ---------------- scans over deg -> rowptr, dinv ----------------

__global__ void k_scan1(const int* __restrict__ deg, int* __restrict__ rowptr,
                        int* __restrict__ part) {
    __shared__ int sm[256];
    int i = blockIdx.x * 256 + threadIdx.x;
    int v = (i < NN) ? deg[i] : 0;
    sm[threadIdx.x] = v;
    __syncthreads();
    for (int off = 1; off < 256; off <<= 1) {
        int t = (threadIdx.x >= off) ? sm[threadIdx.x - off] : 0;
        __syncthreads();
        sm[threadIdx.x] += t;
        __syncthreads();
    }
    if (i < NN) rowptr[i] = sm[threadIdx.x] - v;
    if (threadIdx.x == 255) part[blockIdx.x] = sm[255];
}

__global__ void k_scan2(int* __restrict__ part, int nb) {
    __shared__ int sm[512];
    int t = threadIdx.x;
    int v = (t < nb) ? part[t] : 0;
    sm[t] = v;
    __syncthreads();
    for (int off = 1; off < 512; off <<= 1) {
        int u = (t >= off) ? sm[t - off] : 0;
        __syncthreads();
        sm[t] += u;
        __syncthreads();
    }
    if (t < nb) part[t] = sm[t] - v;
}

__global__ void k_scan3(int* __restrict__ rowptr, const int* __restrict__ part,
                        const int* __restrict__ deg, float* __restrict__ dinv) {
    int i = blockIdx.x * 256 + threadIdx.x;
    if (i < NN) {
        int d = deg[i];
        int r = rowptr[i] + part[blockIdx.x];
        rowptr[i] = r;
        dinv[i] = rsqrtf((float)(d > 0 ? d : 1));
        if (i == NN - 1) rowptr[NN] = r + d;
    }
}

// ---------------- phase B2b: per-bucket scatter into col (L2-local windows) ----------------

__global__ void __launch_bounds__(256) k_scat(const unsigned int* __restrict__ staging,
                                              const int* __restrict__ gcur,
                                              const int* __restrict__ rowptr,
                                              int* __restrict__ col) {
    __shared__ int cur[BSZ];
    int b = blockIdx.x;
    for (int l = threadIdx.x; l < BSZ; l += 256) {
        int g = b * BSZ + l;
        cur[l] = (g < NN) ? rowptr[g] : 0;
    }
    __syncthreads();
    int cnt = min(gcur[b], BCAP);
    const unsigned int* st = staging + (size_t)b * BCAP;
    for (int i = threadIdx.x; i < cnt; i += 256) {
        unsigned int w = st[i];
        int l = w >> 17;
        int s = w & 0x1FFFF;
        int p = atomicAdd(&cur[l], 1);
        if ((unsigned)p < (unsigned)NT) col[p] = s;
    }
}

// ---------------- layer 1: GCN aggregate (8ch) then dense 7->32 ----------------

__global__ void __launch_bounds__(256) k_agg1(const float* __restrict__ xp,
                                              const int* __restrict__ rowptr,
                                              const int* __restrict__ col,
                                              const float* __restrict__ dinv,
                                              float* __restrict__ T1) {
    int gid = blockIdx.x * 256 + threadIdx.x;
    int n = gid >> 1;
    int lane = gid & 1;
    if (n >= NN) return;
    int beg = rowptr[n], end = rowptr[n + 1];
    float4 acc = {0.f, 0.f, 0.f, 0.f};
    #pragma unroll 4
    for (int e = beg; e < end; e++) {
        int s = clampN(col[e]);
        float w = dinv[s];
        float4 f = *(const float4*)(xp + (size_t)s * 8 + lane * 4);
        acc.x += w * f.x; acc.y += w * f.y; acc.z += w * f.z; acc.w += w * f.w;
    }
    float dn = dinv[n];
    acc.x *= dn; acc.y *= dn; acc.z *= dn; acc.w *= dn;
    *(float4*)(T1 + (size_t)n * 8 + lane * 4) = acc;
}

__global__ void k_mm1a(const float* __restrict__ T1, const float* __restrict__ W1,
                       const float* __restrict__ b1, const float* __restrict__ va2,
                       const float* __restrict__ vd2, float* __restrict__ O1,
                       float* __restrict__ as_, float* __restrict__ ad_) {
    int idx = blockIdx.x * 256 + threadIdx.x;  // NN*32 exact
    int n = idx >> 5, c = idx & 31;
    const float* t1 = T1 + (size_t)n * 8;
    float acc = 0.f;
    #pragma unroll
    for (int k = 0; k < 7; k++) acc += t1[k] * W1[k * 32 + c];
    float o = fmaxf(acc + b1[c], 0.f);
    O1[(size_t)n * 32 + c] = o;
    float vs = o * va2[c];
    float vd = o * vd2[c];
    #pragma unroll
    for (int off = 16; off > 0; off >>= 1) {
        vs += __shfl_down(vs, off, 32);
        vd += __shfl_down(vd, off, 32);
    }
    if (c == 0) { as_[n] = vs; ad_[n] = vd; }
}

// ---------------- layer 2: GAT two-pass softmax aggregate (32ch), then dense ----------------

__global__ void __launch_bounds__(256) k_agg2(const float* __restrict__ O1,
                                              const float* __restrict__ as_,
                                              const float* __restrict__ ad_,
                                              const int* __restrict__ rowptr,
                                              const int* __restrict__ col,
                                              float* __restrict__ T2) {
    int gid = blockIdx.x * 256 + threadIdx.x;  // NN*8 exact
    int n = gid >> 3;
    int lane = gid & 7;
    int beg = rowptr[n], end = rowptr[n + 1];
    float adn = ad_[n];
    float m = -1e30f;
    for (int e = beg + lane; e < end; e += 8) {
        float ee = as_[clampN(col[e])] + adn;
        ee = (ee > 0.f) ? ee : 0.2f * ee;
        m = fmaxf(m, ee);
    }
    m = fmaxf(m, __shfl_xor(m, 1, 8));
    m = fmaxf(m, __shfl_xor(m, 2, 8));
    m = fmaxf(m, __shfl_xor(m, 4, 8));
    float den = 0.f;
    float4 acc = {0.f, 0.f, 0.f, 0.f};
    #pragma unroll 2
    for (int e = beg; e < end; e++) {
        int s = clampN(col[e]);
        float ee = as_[s] + adn;
        ee = (ee > 0.f) ? ee : 0.2f * ee;
        float p = __expf(ee - m);
        den += p;
        float4 f = *(const float4*)(O1 + (size_t)s * 32 + lane * 4);
        acc.x += p * f.x; acc.y += p * f.y; acc.z += p * f.z; acc.w += p * f.w;
    }
    float inv = 1.0f / (den + 1e-16f);
    acc.x *= inv; acc.y *= inv; acc.z *= inv; acc.w *= inv;
    *(float4*)(T2 + (size_t)n * 32 + lane * 4) = acc;
}

__global__ void k_mm2(const float* __restrict__ T2, const float* __restrict__ W2,
                      const float* __restrict__ b2, const float* __restrict__ dinv,
                      float* __restrict__ O2) {
    int gid = blockIdx.x * 256 + threadIdx.x;  // NN*64 exact
    int n = gid >> 6, c = gid & 63;
    const float* t2 = T2 + (size_t)n * 32;
    float acc = 0.f;
    #pragma unroll
    for (int k = 0; k < 32; k++) acc += t2[k] * W2[k * 64 + c];
    O2[(size_t)n * 64 + c] = fmaxf(acc + b2[c], 0.f) * dinv[n];
}

// ---------------- layer 3: pure gather-sum (dinv pre-folded), 16 lanes/node ----------------

__global__ void __launch_bounds__(256) k_agg3(const float* __restrict__ O2,
                                              const int* __restrict__ rowptr,
                                              const int* __restrict__ col,
                                              const float* __restrict__ dinv,
                                              float* __restrict__ T3) {
    int gid = blockIdx.x * 256 + threadIdx.x;  // NN*16 exact
    int n = gid >> 4;
    int lane = gid & 15;
    int beg = rowptr[n], end = rowptr[n + 1];
    float4 acc = {0.f, 0.f, 0.f, 0.f};
    #pragma unroll 4
    for (int e = beg; e < end; e++) {
        int s = clampN(col[e]);
        float4 f = *(const float4*)(O2 + (size_t)s * 64 + lane * 4);
        acc.x += f.x; acc.y += f.y; acc.z += f.z; acc.w += f.w;
    }
    float dn = dinv[n];
    acc.x *= dn; acc.y *= dn; acc.z *= dn; acc.w *= dn;
    *(float4*)(T3 + (size_t)n * 64 + lane * 4) = acc;
}

// ---------------- dense: T3 -> W3 -> relu -> W4 -> h4, alpha4 ----------------

__global__ void __launch_bounds__(256) k_mm34(const float* __restrict__ T3,
                                              const float* __restrict__ W3,
                                              const float* __restrict__ b3,
                                              const float* __restrict__ W4,
                                              const float* __restrict__ av4s,
                                              const float* __restrict__ av4d,
                                              float* __restrict__ h4,
                                              float* __restrict__ as_,
                                              float* __restrict__ ad_) {
    __shared__ float sW3[64 * 128];
    __shared__ float sW4[128 * 2];
    __shared__ float sb3[128];
    for (int i = threadIdx.x; i < 64 * 128; i += 256) sW3[i] = W3[i];
    if (threadIdx.x < 128) {
        sW4[2 * threadIdx.x] = W4[2 * threadIdx.x];
        sW4[2 * threadIdx.x + 1] = W4[2 * threadIdx.x + 1];
        sb3[threadIdx.x] = b3[threadIdx.x];
    }
    __syncthreads();

    int wid = threadIdx.x >> 6;
    int lane = threadIdx.x & 63;
    int half = lane >> 5;
    int lw = lane & 31;
    int n = blockIdx.x * 8 + wid * 2 + half;   // grid NN/8 exact

    float2 t = *(const float2*)(T3 + (size_t)n * 64 + 2 * lw);
    float ax = t.x, ay = t.y;

    float a0 = 0.f, a1 = 0.f, a2 = 0.f, a3 = 0.f;
    #pragma unroll
    for (int k = 0; k < 64; k++) {
        int srcl = half * 32 + (k >> 1);
        float tk = (k & 1) ? __shfl(ay, srcl, 64) : __shfl(ax, srcl, 64);
        const float* wrow = &sW3[k * 128 + lw];
        a0 += tk * wrow[0];
        a1 += tk * wrow[32];
        a2 += tk * wrow[64];
        a3 += tk * wrow[96];
    }
    a0 = fmaxf(a0 + sb3[lw], 0.f);
    a1 = fmaxf(a1 + sb3[lw + 32], 0.f);
    a2 = fmaxf(a2 + sb3[lw + 64], 0.f);
    a3 = fmaxf(a3 + sb3[lw + 96], 0.f);

    float p0 = a0 * sW4[2 * lw] + a1 * sW4[2 * (lw + 32)] +
               a2 * sW4[2 * (lw + 64)] + a3 * sW4[2 * (lw + 96)];
    float p1 = a0 * sW4[2 * lw + 1] + a1 * sW4[2 * (lw + 32) + 1] +
               a2 * sW4[2 * (lw + 64) + 1] + a3 * sW4[2 * (lw + 96) + 1];
    #pragma unroll
    for (int off = 16; off > 0; off >>= 1) {
        p0 += __shfl_down(p0, off, 32);
        p1 += __shfl_down(p1, off, 32);
    }
    if (lw == 0) {
        h4[n * 2 + 0] = p0;
        h4[n * 2 + 1] = p1;
        as_[n] = p0 * av4s[0] + p1 * av4s[1];
        ad_[n] = p0 * av4d[0] + p1 * av4d[1];
    }
}

// ---------------- final GAT (2ch) + log_softmax, two-pass softmax ----------------

__global__ void k_final(const float* __restrict__ h4, const float* __restrict__ as_,
                        const float* __restrict__ ad_, const int* __restrict__ rowptr,
                        const int* __restrict__ col, const float* __restrict__ b,
                        float* __restrict__ out) {
    int n = blockIdx.x * 256 + threadIdx.x;
    if (n >= NN) return;
    int beg = rowptr[n], end = rowptr[n + 1];
    float adn = ad_[n];
    float m = -1e30f;
    for (int e = beg; e < end; e++) {
        float ee = as_[clampN(col[e])] + adn;
        ee = (ee > 0.f) ? ee : 0.2f * ee;
        m = fmaxf(m, ee);
    }
    float den = 0.f, a0 = 0.f, a1 = 0.f;
    for (int e = beg; e < end; e++) {
        int s = clampN(col[e]);
        float ee = as_[s] + adn;
        ee = (ee > 0.f) ? ee : 0.2f * ee;
        float p = __expf(ee - m);
        den += p;
        float2 h = *(const float2*)(h4 + (size_t)s * 2);
        a0 += p * h.x;
        a1 += p * h.y;
    }
    float inv = 1.0f / (den + 1e-16f);
    float v0 = a0 * inv + b[0];
    float v1 = a1 * inv + b[1];
    float mx = fmaxf(v0, v1);
    float lse = mx + logf(__expf(v0 - mx) + __expf(v1 - mx));
    out[n * 2 + 0] = v0 - lse;
    out[n * 2 + 1] = v1 - lse;
}

__global__ void k_sentinel(float* __restrict__ out, float v) {
    int i = blockIdx.x * 256 + threadIdx.x;
    if (i < NN * 2) out[i] = v;
}

// ---------------- launch ----------------

extern "C" void kernel_launch(void* const* d_in, const int* in_sizes, int n_in,
                              void* d_out, int out_size, void* d_ws, size_t ws_size,
                              hipStream_t stream) {
    const float* x    = (const float*)d_in[0];
    const int* ei     = (const int*)d_in[1];
    const float* W1   = (const float*)d_in[2];
    const float* b1   = (const float*)d_in[3];
    const float* W2   = (const float*)d_in[4];
    const float* a2s  = (const float*)d_in[5];
    const float* a2d  = (const float*)d_in[6];
    const float* b2   = (const float*)d_in[7];
    const float* W3   = (const float*)d_in[8];
    const float* b3   = (const float*)d_in[9];
    const float* W4   = (const float*)d_in[10];
    const float* a4s  = (const float*)d_in[11];
    const float* a4d  = (const float*)d_in[12];
    const float* b4   = (const float*)d_in[13];
    float* out = (float*)d_out;

    char* base = (char*)d_ws;
    size_t off = 0;
    auto alloc = [&](size_t bytes) {
        char* q = base + off;
        off += (bytes + 255) & ~(size_t)255;
        return q;
    };
    float* bufA  = (float*)alloc((size_t)NN * 64 * 4);          // xp -> O1 -> O2
    float* bufB  = (float*)alloc((size_t)NN * 64 * 4);          // T1 -> T2 -> T3
    unsigned int* staging = (unsigned int*)alloc((size_t)NBKT * BCAP * 4);  // 10.5 MB
    int* col     = (int*)alloc((size_t)NT * 4);
    int* rowptr  = (int*)alloc((size_t)(NN + 1) * 4);
    int* deg     = (int*)alloc((size_t)NN * 4);
    float* dinv  = (float*)alloc((size_t)NN * 4);
    float* as_   = (float*)alloc((size_t)NN * 4);
    float* ad_   = (float*)alloc((size_t)NN * 4);
    float* h4    = (float*)alloc((size_t)NN * 2 * 4);
    int* part    = (int*)alloc(512 * 4);
    int* flag    = (int*)alloc(256);
    int* gcur    = (int*)alloc(NBKT * 4);
    float* va2   = (float*)alloc(32 * 4);
    float* vd2   = (float*)alloc(32 * 4);

    float code = 0.f;
    if (off > ws_size)            code = 1000.f + (float)(ws_size >> 20);
    else if (n_in != 14)          code = 2000.f + 10.f * (float)n_in;
    else if (out_size != NN * 2)  code = 3400.f;
    if (code != 0.f) {
        k_sentinel<<<(NN * 2 + 255) / 256, 256, 0, stream>>>(out, code);
        return;
    }

    const int NB = (NN + 255) / 256;
    const int NTILE = (NT + 4095) / 4096;

    // init + CSR build (bucketed counting sort, dense writes)
    k_init<<<NN * 8 / 256, 256, 0, stream>>>(x, W2, a2s, a2d, ei, bufA, va2, vd2,
                                             flag, gcur);
    k_binA<<<NTILE, 256, 0, stream>>>(ei, flag, gcur, staging);
    k_hist<<<NBKT, 256, 0, stream>>>(staging, gcur, deg);
    k_scan1<<<NB, 256, 0, stream>>>(deg, rowptr, part);
    k_scan2<<<1, 512, 0, stream>>>(part, NB);
    k_scan3<<<NB, 256, 0, stream>>>(rowptr, part, deg, dinv);
    k_scat<<<NBKT, 256, 0, stream>>>(staging, gcur, rowptr, col);

    // layer 1: GCN
    k_agg1<<<(NN * 2 + 255) / 256, 256, 0, stream>>>(bufA, rowptr, col, dinv, bufB);
    k_mm1a<<<NN * 32 / 256, 256, 0, stream>>>(bufB, W1, b1, va2, vd2, bufA, as_, ad_);
    // layer 2: GAT
    k_agg2<<<NN * 8 / 256, 256, 0, stream>>>(bufA, as_, ad_, rowptr, col, bufB);
    k_mm2<<<NN * 64 / 256, 256, 0, stream>>>(bufB, W2, b2, dinv, bufA);
    // layer 3: GCN (dinv folded into O2)
    k_agg3<<<NN * 16 / 256, 256, 0, stream>>>(bufA, rowptr, col, dinv, bufB);
    // layers 3/4 dense + alpha4
    k_mm34<<<NN / 8, 256, 0, stream>>>(bufB, W3, b3, W4, a4s, a4d, h4, as_, ad_);
    // layer 4 aggregation + log_softmax
    k_final<<<NB, 256, 0, stream>>>(h4, as_, ad_, rowptr, col, b4, out);
}

// Round 12
// 386.359 us; speedup vs baseline: 2.1335x; 1.1729x over previous
//
#include <hip/hip_runtime.h>

#define NN 100000
#define NE 1600000
#define NT (NN + NE)
#define NBKT 256
#define BSZ 391          // nodes per bucket; 256*391 = 100096 >= NN
#define BCAP 10240       // staging entries per bucket (avg 6641, 45 sigma slack)

static __device__ __forceinline__ int clampN(int s) {
    return ((unsigned)s < (unsigned)NN) ? s : 0;
}
static __device__ __forceinline__ int ld_src(const int* ei, int is32, int e) {
    return is32 ? ei[e] : ei[2 * e];
}
static __device__ __forceinline__ int ld_dst(const int* ei, int is32, int e) {
    return is32 ? ei[NE + e] : ei[2 * NE + 2 * e];
}

#define FMA4(acc, s, v) { acc.x += (s)*(v).x; acc.y += (s)*(v).y; \
                          acc.z += (s)*(v).z; acc.w += (s)*(v).w; }

// ---------------- init: flag detect, padx, alpha2 vecs, zero bucket cursors ----------------

__global__ void __launch_bounds__(256) k_init(const float* __restrict__ x,
                                              const float* __restrict__ W2,
                                              const float* __restrict__ a2s,
                                              const float* __restrict__ a2d,
                                              const int* __restrict__ ei,
                                              float* __restrict__ xp,
                                              float* __restrict__ va2,
                                              float* __restrict__ vd2,
                                              int* __restrict__ flag,
                                              int* __restrict__ gcur) {
    int idx = blockIdx.x * 256 + threadIdx.x;   // grid covers NN*8
    if (blockIdx.x == 0) {
        if (threadIdx.x == 0) flag[0] = 0;
        __syncthreads();
        int nz = 0;
        for (int i = threadIdx.x; i < 4096; i += 256) nz |= ei[2 * i + 1];
        if (nz) atomicOr(flag, 1);
        if (threadIdx.x < NBKT) gcur[threadIdx.x] = 0;
    }
    if (blockIdx.x == 1 && threadIdx.x < 64) {
        int t = threadIdx.x;
        if (t < 32) {
            float a = 0.f;
            for (int c = 0; c < 64; c++) a += W2[t * 64 + c] * a2s[c];
            va2[t] = a;
        } else {
            int k = t - 32;
            float a = 0.f;
            for (int c = 0; c < 64; c++) a += W2[k * 64 + c] * a2d[c];
            vd2[k] = a;
        }
    }
    if (idx < NN * 8) {
        int n = idx >> 3, c = idx & 7;
        xp[idx] = (c < 7) ? x[n * 7 + c] : 0.f;  // pad 7->8
    }
}

// ---------------- phase B1: bin edges (incl self-loops) into bucket staging ----------------

__global__ void __launch_bounds__(256) k_binA(const int* __restrict__ ei,
                                              const int* __restrict__ flag,
                                              int* __restrict__ gcur,
                                              unsigned int* __restrict__ staging) {
    __shared__ int hist[NBKT];
    __shared__ int gbase[NBKT];
    __shared__ int cnt2[NBKT];
    int tid = threadIdx.x;
    if (tid < NBKT) { hist[tid] = 0; }
    __syncthreads();

    int base = blockIdx.x * 4096;
    int is32 = flag[0];
    int d[16], s[16];
    #pragma unroll
    for (int i = 0; i < 16; i++) {
        int e = base + i * 256 + tid;
        d[i] = -1;
        if (e < NE) {
            int dd = ld_dst(ei, is32, e);
            if ((unsigned)dd < (unsigned)NN) { d[i] = dd; s[i] = clampN(ld_src(ei, is32, e)); }
        } else if (e < NT) {
            d[i] = e - NE; s[i] = e - NE;        // self-loop
        }
        if (d[i] >= 0) atomicAdd(&hist[d[i] / BSZ], 1);
    }
    __syncthreads();
    if (tid < NBKT) {
        int c = hist[tid];
        gbase[tid] = c ? atomicAdd(&gcur[tid], c) : 0;
        cnt2[tid] = 0;
    }
    __syncthreads();
    #pragma unroll
    for (int i = 0; i < 16; i++) {
        if (d[i] >= 0) {
            int b = d[i] / BSZ;
            int pos = gbase[b] + atomicAdd(&cnt2[b], 1);
            if (pos < BCAP)
                staging[(size_t)b * BCAP + pos] =
                    ((unsigned)(d[i] - b * BSZ) << 17) | (unsigned)s[i];
        }
    }
}

// ---------------- phase B2a: per-bucket degree histogram (dense writes) ----------------

__global__ void __launch_bounds__(256) k_hist(const unsigned int* __restrict__ staging,
                                              const int* __restrict__ gcur,
                                              int* __restrict__ deg) {
    __shared__ int h[BSZ];
    int b = blockIdx.x;
    for (int l = threadIdx.x; l < BSZ; l += 256) h[l] = 0;
    __syncthreads();
    int cnt = min(gcur[b], BCAP);
    const unsigned int* st = staging + (size_t)b * BCAP;
    for (int i = threadIdx.x; i < cnt; i += 256)
        atomicAdd(&h[st[i] >> 17], 1);
    __syncthreads();
    for (int l = threadIdx.x; l < BSZ; l += 256) {
        int g = b * BSZ + l;
        if (g < NN) deg[g] = h[l];
    }
}

// ---------------- scans over deg -> rowptr, dinv ----------------

__global__ void k_scan1(const int* __restrict__ deg, int* __restrict__ rowptr,
                        int* __restrict__ part) {
    __shared__ int sm[256];
    int i = blockIdx.x * 256 + threadIdx.x;
    int v = (i < NN) ? deg[i] : 0;
    sm[threadIdx.x] = v;
    __syncthreads();
    for (int off = 1; off < 256; off <<= 1) {
        int t = (threadIdx.x >= off) ? sm[threadIdx.x - off] : 0;
        __syncthreads();
        sm[threadIdx.x] += t;
        __syncthreads();
    }
    if (i < NN) rowptr[i] = sm[threadIdx.x] - v;
    if (threadIdx.x == 255) part[blockIdx.x] = sm[255];
}

__global__ void k_scan2(int* __restrict__ part, int nb) {
    __shared__ int sm[512];
    int t = threadIdx.x;
    int v = (t < nb) ? part[t] : 0;
    sm[t] = v;
    __syncthreads();
    for (int off = 1; off < 512; off <<= 1) {
        int u = (t >= off) ? sm[t - off] : 0;
        __syncthreads();
        sm[t] += u;
        __syncthreads();
    }
    if (t < nb) part[t] = sm[t] - v;
}

__global__ void k_scan3(int* __restrict__ rowptr, const int* __restrict__ part,
                        const int* __restrict__ deg, float* __restrict__ dinv) {
    int i = blockIdx.x * 256 + threadIdx.x;
    if (i < NN) {
        int d = deg[i];
        int r = rowptr[i] + part[blockIdx.x];
        rowptr[i] = r;
        dinv[i] = rsqrtf((float)(d > 0 ? d : 1));
        if (i == NN - 1) rowptr[NN] = r + d;
    }
}

// ---------------- phase B2b: per-bucket scatter into col (L2-local windows) ----------------

__global__ void __launch_bounds__(256) k_scat(const unsigned int* __restrict__ staging,
                                              const int* __restrict__ gcur,
                                              const int* __restrict__ rowptr,
                                              int* __restrict__ col) {
    __shared__ int cur[BSZ];
    int b = blockIdx.x;
    for (int l = threadIdx.x; l < BSZ; l += 256) {
        int g = b * BSZ + l;
        cur[l] = (g < NN) ? rowptr[g] : 0;
    }
    __syncthreads();
    int cnt = min(gcur[b], BCAP);
    const unsigned int* st = staging + (size_t)b * BCAP;
    for (int i = threadIdx.x; i < cnt; i += 256) {
        unsigned int w = st[i];
        int l = w >> 17;
        int s = w & 0x1FFFF;
        int p = atomicAdd(&cur[l], 1);
        if ((unsigned)p < (unsigned)NT) col[p] = s;
    }
}

// ---------------- layer 1: GCN aggregate (8ch) then dense 7->32 ----------------

__global__ void __launch_bounds__(256) k_agg1(const float* __restrict__ xp,
                                              const int* __restrict__ rowptr,
                                              const int* __restrict__ col,
                                              const float* __restrict__ dinv,
                                              float* __restrict__ T1) {
    int gid = blockIdx.x * 256 + threadIdx.x;
    int n = gid >> 1;
    int lane = gid & 1;
    if (n >= NN) return;
    int beg = rowptr[n], end = rowptr[n + 1];
    float4 acc = {0.f, 0.f, 0.f, 0.f};
    #pragma unroll 4
    for (int e = beg; e < end; e++) {
        int s = clampN(col[e]);
        float w = dinv[s];
        float4 f = *(const float4*)(xp + (size_t)s * 8 + lane * 4);
        acc.x += w * f.x; acc.y += w * f.y; acc.z += w * f.z; acc.w += w * f.w;
    }
    float dn = dinv[n];
    acc.x *= dn; acc.y *= dn; acc.z *= dn; acc.w *= dn;
    *(float4*)(T1 + (size_t)n * 8 + lane * 4) = acc;
}

__global__ void k_mm1a(const float* __restrict__ T1, const float* __restrict__ W1,
                       const float* __restrict__ b1, const float* __restrict__ va2,
                       const float* __restrict__ vd2, float* __restrict__ O1,
                       float* __restrict__ as_, float* __restrict__ ad_) {
    int idx = blockIdx.x * 256 + threadIdx.x;  // NN*32 exact
    int n = idx >> 5, c = idx & 31;
    const float* t1 = T1 + (size_t)n * 8;
    float acc = 0.f;
    #pragma unroll
    for (int k = 0; k < 7; k++) acc += t1[k] * W1[k * 32 + c];
    float o = fmaxf(acc + b1[c], 0.f);
    O1[(size_t)n * 32 + c] = o;
    float vs = o * va2[c];
    float vd = o * vd2[c];
    #pragma unroll
    for (int off = 16; off > 0; off >>= 1) {
        vs += __shfl_down(vs, off, 32);
        vd += __shfl_down(vd, off, 32);
    }
    if (c == 0) { as_[n] = vs; ad_[n] = vd; }
}

// ---------------- layer 2: GAT two-pass softmax aggregate (32ch), then dense ----------------

__global__ void __launch_bounds__(256) k_agg2(const float* __restrict__ O1,
                                              const float* __restrict__ as_,
                                              const float* __restrict__ ad_,
                                              const int* __restrict__ rowptr,
                                              const int* __restrict__ col,
                                              float* __restrict__ T2) {
    int gid = blockIdx.x * 256 + threadIdx.x;  // NN*8 exact
    int n = gid >> 3;
    int lane = gid & 7;
    int beg = rowptr[n], end = rowptr[n + 1];
    float adn = ad_[n];
    float m = -1e30f;
    for (int e = beg + lane; e < end; e += 8) {
        float ee = as_[clampN(col[e])] + adn;
        ee = (ee > 0.f) ? ee : 0.2f * ee;
        m = fmaxf(m, ee);
    }
    m = fmaxf(m, __shfl_xor(m, 1, 8));
    m = fmaxf(m, __shfl_xor(m, 2, 8));
    m = fmaxf(m, __shfl_xor(m, 4, 8));
    float den = 0.f;
    float4 acc = {0.f, 0.f, 0.f, 0.f};
    #pragma unroll 2
    for (int e = beg; e < end; e++) {
        int s = clampN(col[e]);
        float ee = as_[s] + adn;
        ee = (ee > 0.f) ? ee : 0.2f * ee;
        float p = __expf(ee - m);
        den += p;
        float4 f = *(const float4*)(O1 + (size_t)s * 32 + lane * 4);
        acc.x += p * f.x; acc.y += p * f.y; acc.z += p * f.z; acc.w += p * f.w;
    }
    float inv = 1.0f / (den + 1e-16f);
    acc.x *= inv; acc.y *= inv; acc.z *= inv; acc.w *= inv;
    *(float4*)(T2 + (size_t)n * 32 + lane * 4) = acc;
}

__global__ void k_mm2(const float* __restrict__ T2, const float* __restrict__ W2,
                      const float* __restrict__ b2, const float* __restrict__ dinv,
                      float* __restrict__ O2) {
    int gid = blockIdx.x * 256 + threadIdx.x;  // NN*64 exact
    int n = gid >> 6, c = gid & 63;
    const float* t2 = T2 + (size_t)n * 32;
    float acc = 0.f;
    #pragma unroll
    for (int k = 0; k < 32; k++) acc += t2[k] * W2[k * 64 + c];
    O2[(size_t)n * 64 + c] = fmaxf(acc + b2[c], 0.f) * dinv[n];
}

// ---------------- layer 3: pure gather-sum (dinv pre-folded), 16 lanes/node ----------------

__global__ void __launch_bounds__(256) k_agg3(const float* __restrict__ O2,
                                              const int* __restrict__ rowptr,
                                              const int* __restrict__ col,
                                              const float* __restrict__ dinv,
                                              float* __restrict__ T3) {
    int gid = blockIdx.x * 256 + threadIdx.x;  // NN*16 exact
    int n = gid >> 4;
    int lane = gid & 15;
    int beg = rowptr[n], end = rowptr[n + 1];
    float4 acc = {0.f, 0.f, 0.f, 0.f};
    #pragma unroll 4
    for (int e = beg; e < end; e++) {
        int s = clampN(col[e]);
        float4 f = *(const float4*)(O2 + (size_t)s * 64 + lane * 4);
        acc.x += f.x; acc.y += f.y; acc.z += f.z; acc.w += f.w;
    }
    float dn = dinv[n];
    acc.x *= dn; acc.y *= dn; acc.z *= dn; acc.w *= dn;
    *(float4*)(T3 + (size_t)n * 64 + lane * 4) = acc;
}

// ---------------- dense: T3 -> W3 -> relu -> W4 -> h4, alpha4 ----------------
// 32 nodes/block; T3 tile + W3 in LDS; b128 reads; no shfl in the hot loop.

__global__ void __launch_bounds__(256) k_mm34(const float* __restrict__ T3,
                                              const float* __restrict__ W3,
                                              const float* __restrict__ b3,
                                              const float* __restrict__ W4,
                                              const float* __restrict__ av4s,
                                              const float* __restrict__ av4d,
                                              float* __restrict__ h4,
                                              float* __restrict__ as_,
                                              float* __restrict__ ad_) {
    __shared__ float sW3[64 * 128];   // 32 KB
    __shared__ float sT3[32 * 64];    // 8 KB
    __shared__ float sW4[128 * 2];
    __shared__ float sb3[128];

    // stage W3: 2048 float4s, 8 per thread (coalesced)
    {
        const float4* g = (const float4*)W3;
        float4* s4 = (float4*)sW3;
        #pragma unroll
        for (int i = 0; i < 8; i++) s4[threadIdx.x + 256 * i] = g[threadIdx.x + 256 * i];
    }
    // stage T3 tile: 512 float4s, 2 per thread
    {
        const float4* g = (const float4*)(T3 + (size_t)blockIdx.x * 32 * 64);
        float4* s4 = (float4*)sT3;
        s4[threadIdx.x] = g[threadIdx.x];
        s4[threadIdx.x + 256] = g[threadIdx.x + 256];
    }
    if (threadIdx.x < 128) {
        sb3[threadIdx.x] = b3[threadIdx.x];
        sW4[2 * threadIdx.x] = W4[2 * threadIdx.x];
        sW4[2 * threadIdx.x + 1] = W4[2 * threadIdx.x + 1];
    }
    __syncthreads();

    int w = threadIdx.x >> 6;
    int lane = threadIdx.x & 63;
    int half = lane >> 5;
    int lw = lane & 31;
    int lbase = w * 8 + half * 4;    // local node base (4 nodes per half-wave)
    int c4 = lw * 4;                 // 4 consecutive channels per lane

    float4 acc0 = {0,0,0,0}, acc1 = {0,0,0,0}, acc2 = {0,0,0,0}, acc3 = {0,0,0,0};
    #pragma unroll 4
    for (int k4 = 0; k4 < 16; k4++) {
        float4 t0 = *(const float4*)&sT3[(lbase + 0) * 64 + 4 * k4];
        float4 t1 = *(const float4*)&sT3[(lbase + 1) * 64 + 4 * k4];
        float4 t2 = *(const float4*)&sT3[(lbase + 2) * 64 + 4 * k4];
        float4 t3 = *(const float4*)&sT3[(lbase + 3) * 64 + 4 * k4];
        #pragma unroll
        for (int j = 0; j < 4; j++) {
            float4 wv = *(const float4*)&sW3[(4 * k4 + j) * 128 + c4];
            float s0 = ((const float*)&t0)[j];
            float s1 = ((const float*)&t1)[j];
            float s2 = ((const float*)&t2)[j];
            float s3 = ((const float*)&t3)[j];
            FMA4(acc0, s0, wv);
            FMA4(acc1, s1, wv);
            FMA4(acc2, s2, wv);
            FMA4(acc3, s3, wv);
        }
    }

    // epilogue: relu(+b3) then project to 2 ch, reduce over 32 lanes
    float4 bb = *(const float4*)&sb3[c4];
    float w40x = sW4[2 * c4],     w41x = sW4[2 * c4 + 1];
    float w40y = sW4[2 * c4 + 2], w41y = sW4[2 * c4 + 3];
    float w40z = sW4[2 * c4 + 4], w41z = sW4[2 * c4 + 5];
    float w40w = sW4[2 * c4 + 6], w41w = sW4[2 * c4 + 7];
    float av4s0 = av4s[0], av4s1 = av4s[1];
    float av4d0 = av4d[0], av4d1 = av4d[1];

    #pragma unroll
    for (int n = 0; n < 4; n++) {
        float4 a = (n == 0) ? acc0 : (n == 1) ? acc1 : (n == 2) ? acc2 : acc3;
        a.x = fmaxf(a.x + bb.x, 0.f);
        a.y = fmaxf(a.y + bb.y, 0.f);
        a.z = fmaxf(a.z + bb.z, 0.f);
        a.w = fmaxf(a.w + bb.w, 0.f);
        float p0 = a.x * w40x + a.y * w40y + a.z * w40z + a.w * w40w;
        float p1 = a.x * w41x + a.y * w41y + a.z * w41z + a.w * w41w;
        #pragma unroll
        for (int off = 16; off > 0; off >>= 1) {
            p0 += __shfl_down(p0, off, 32);
            p1 += __shfl_down(p1, off, 32);
        }
        if (lw == 0) {
            int gn = blockIdx.x * 32 + lbase + n;
            h4[gn * 2 + 0] = p0;
            h4[gn * 2 + 1] = p1;
            as_[gn] = p0 * av4s0 + p1 * av4s1;
            ad_[gn] = p0 * av4d0 + p1 * av4d1;
        }
    }
}

// ---------------- final GAT (2ch) + log_softmax, two-pass softmax ----------------

__global__ void k_final(const float* __restrict__ h4, const float* __restrict__ as_,
                        const float* __restrict__ ad_, const int* __restrict__ rowptr,
                        const int* __restrict__ col, const float* __restrict__ b,
                        float* __restrict__ out) {
    int n = blockIdx.x * 256 + threadIdx.x;
    if (n >= NN) return;
    int beg = rowptr[n], end = rowptr[n + 1];
    float adn = ad_[n];
    float m = -1e30f;
    for (int e = beg; e < end; e++) {
        float ee = as_[clampN(col[e])] + adn;
        ee = (ee > 0.f) ? ee : 0.2f * ee;
        m = fmaxf(m, ee);
    }
    float den = 0.f, a0 = 0.f, a1 = 0.f;
    for (int e = beg; e < end; e++) {
        int s = clampN(col[e]);
        float ee = as_[s] + adn;
        ee = (ee > 0.f) ? ee : 0.2f * ee;
        float p = __expf(ee - m);
        den += p;
        float2 h = *(const float2*)(h4 + (size_t)s * 2);
        a0 += p * h.x;
        a1 += p * h.y;
    }
    float inv = 1.0f / (den + 1e-16f);
    float v0 = a0 * inv + b[0];
    float v1 = a1 * inv + b[1];
    float mx = fmaxf(v0, v1);
    float lse = mx + logf(__expf(v0 - mx) + __expf(v1 - mx));
    out[n * 2 + 0] = v0 - lse;
    out[n * 2 + 1] = v1 - lse;
}

__global__ void k_sentinel(float* __restrict__ out, float v) {
    int i = blockIdx.x * 256 + threadIdx.x;
    if (i < NN * 2) out[i] = v;
}

// ---------------- launch ----------------

extern "C" void kernel_launch(void* const* d_in, const int* in_sizes, int n_in,
                              void* d_out, int out_size, void* d_ws, size_t ws_size,
                              hipStream_t stream) {
    const float* x    = (const float*)d_in[0];
    const int* ei     = (const int*)d_in[1];
    const float* W1   = (const float*)d_in[2];
    const float* b1   = (const float*)d_in[3];
    const float* W2   = (const float*)d_in[4];
    const float* a2s  = (const float*)d_in[5];
    const float* a2d  = (const float*)d_in[6];
    const float* b2   = (const float*)d_in[7];
    const float* W3   = (const float*)d_in[8];
    const float* b3   = (const float*)d_in[9];
    const float* W4   = (const float*)d_in[10];
    const float* a4s  = (const float*)d_in[11];
    const float* a4d  = (const float*)d_in[12];
    const float* b4   = (const float*)d_in[13];
    float* out = (float*)d_out;

    char* base = (char*)d_ws;
    size_t off = 0;
    auto alloc = [&](size_t bytes) {
        char* q = base + off;
        off += (bytes + 255) & ~(size_t)255;
        return q;
    };
    float* bufA  = (float*)alloc((size_t)NN * 64 * 4);          // xp -> O1 -> O2
    float* bufB  = (float*)alloc((size_t)NN * 64 * 4);          // T1 -> T2 -> T3
    unsigned int* staging = (unsigned int*)alloc((size_t)NBKT * BCAP * 4);  // 10.5 MB
    int* col     = (int*)alloc((size_t)NT * 4);
    int* rowptr  = (int*)alloc((size_t)(NN + 1) * 4);
    int* deg     = (int*)alloc((size_t)NN * 4);
    float* dinv  = (float*)alloc((size_t)NN * 4);
    float* as_   = (float*)alloc((size_t)NN * 4);
    float* ad_   = (float*)alloc((size_t)NN * 4);
    float* h4    = (float*)alloc((size_t)NN * 2 * 4);
    int* part    = (int*)alloc(512 * 4);
    int* flag    = (int*)alloc(256);
    int* gcur    = (int*)alloc(NBKT * 4);
    float* va2   = (float*)alloc(32 * 4);
    float* vd2   = (float*)alloc(32 * 4);

    float code = 0.f;
    if (off > ws_size)            code = 1000.f + (float)(ws_size >> 20);
    else if (n_in != 14)          code = 2000.f + 10.f * (float)n_in;
    else if (out_size != NN * 2)  code = 3400.f;
    if (code != 0.f) {
        k_sentinel<<<(NN * 2 + 255) / 256, 256, 0, stream>>>(out, code);
        return;
    }

    const int NB = (NN + 255) / 256;
    const int NTILE = (NT + 4095) / 4096;

    // init + CSR build (bucketed counting sort, dense writes)
    k_init<<<NN * 8 / 256, 256, 0, stream>>>(x, W2, a2s, a2d, ei, bufA, va2, vd2,
                                             flag, gcur);
    k_binA<<<NTILE, 256, 0, stream>>>(ei, flag, gcur, staging);
    k_hist<<<NBKT, 256, 0, stream>>>(staging, gcur, deg);
    k_scan1<<<NB, 256, 0, stream>>>(deg, rowptr, part);
    k_scan2<<<1, 512, 0, stream>>>(part, NB);
    k_scan3<<<NB, 256, 0, stream>>>(rowptr, part, deg, dinv);
    k_scat<<<NBKT, 256, 0, stream>>>(staging, gcur, rowptr, col);

    // layer 1: GCN
    k_agg1<<<(NN * 2 + 255) / 256, 256, 0, stream>>>(bufA, rowptr, col, dinv, bufB);
    k_mm1a<<<NN * 32 / 256, 256, 0, stream>>>(bufB, W1, b1, va2, vd2, bufA, as_, ad_);
    // layer 2: GAT
    k_agg2<<<NN * 8 / 256, 256, 0, stream>>>(bufA, as_, ad_, rowptr, col, bufB);
    k_mm2<<<NN * 64 / 256, 256, 0, stream>>>(bufB, W2, b2, dinv, bufA);
    // layer 3: GCN (dinv folded into O2)
    k_agg3<<<NN * 16 / 256, 256, 0, stream>>>(bufA, rowptr, col, dinv, bufB);
    // layers 3/4 dense + alpha4 (32 nodes/block)
    k_mm34<<<NN / 32, 256, 0, stream>>>(bufB, W3, b3, W4, a4s, a4d, h4, as_, ad_);
    // layer 4 aggregation + log_softmax
    k_final<<<NB, 256, 0, stream>>>(h4, as_, ad_, rowptr, col, b4, out);
}

// Round 13
// 364.770 us; speedup vs baseline: 2.2598x; 1.0592x over previous
//
#include <hip/hip_runtime.h>
#include <hip/hip_bf16.h>

#define NN 100000
#define NE 1600000
#define NT (NN + NE)
#define NBKT 256
#define BSZ 391          // nodes per bucket; 256*391 = 100096 >= NN
#define BCAP 10240       // staging entries per bucket

typedef unsigned int u32;
typedef unsigned short u16;

static __device__ __forceinline__ int clampN(int s) {
    return ((unsigned)s < (unsigned)NN) ? s : 0;
}
static __device__ __forceinline__ int ld_src(const int* ei, int is32, int e) {
    return is32 ? ei[e] : ei[2 * e];
}
static __device__ __forceinline__ int ld_dst(const int* ei, int is32, int e) {
    return is32 ? ei[NE + e] : ei[2 * NE + 2 * e];
}
static __device__ __forceinline__ float2 b2x2(u32 u) {
    float2 r;
    r.x = __uint_as_float((u & 0xffffu) << 16);
    r.y = __uint_as_float(u & 0xffff0000u);
    return r;
}
static __device__ __forceinline__ u16 f2bs(float f) {
    union { __hip_bfloat16 b; u16 u; } cv;
    cv.b = __float2bfloat16(f);
    return cv.u;
}
static __device__ __forceinline__ u32 pack2(float x, float y) {
    return ((u32)f2bs(y) << 16) | (u32)f2bs(x);
}

#define FMA4(acc, s, v) { acc.x += (s)*(v).x; acc.y += (s)*(v).y; \
                          acc.z += (s)*(v).z; acc.w += (s)*(v).w; }

// ---------------- init ----------------

__global__ void __launch_bounds__(256) k_init(const float* __restrict__ x,
                                              const float* __restrict__ W2,
                                              const float* __restrict__ a2s,
                                              const float* __restrict__ a2d,
                                              const int* __restrict__ ei,
                                              float* __restrict__ xp,
                                              float* __restrict__ va2,
                                              float* __restrict__ vd2,
                                              int* __restrict__ flag,
                                              int* __restrict__ gcur) {
    int idx = blockIdx.x * 256 + threadIdx.x;   // grid covers NN*8
    if (blockIdx.x == 0) {
        if (threadIdx.x == 0) flag[0] = 0;
        __syncthreads();
        int nz = 0;
        for (int i = threadIdx.x; i < 4096; i += 256) nz |= ei[2 * i + 1];
        if (nz) atomicOr(flag, 1);
        if (threadIdx.x < NBKT) gcur[threadIdx.x] = 0;
    }
    if (blockIdx.x == 1 && threadIdx.x < 64) {
        int t = threadIdx.x;
        if (t < 32) {
            float a = 0.f;
            for (int c = 0; c < 64; c++) a += W2[t * 64 + c] * a2s[c];
            va2[t] = a;
        } else {
            int k = t - 32;
            float a = 0.f;
            for (int c = 0; c < 64; c++) a += W2[k * 64 + c] * a2d[c];
            vd2[k] = a;
        }
    }
    if (idx < NN * 8) {
        int n = idx >> 3, c = idx & 7;
        xp[idx] = (c < 7) ? x[n * 7 + c] : 0.f;  // pad 7->8, fp32
    }
}

// ---------------- CSR build (bucketed counting sort) ----------------

__global__ void __launch_bounds__(256) k_binA(const int* __restrict__ ei,
                                              const int* __restrict__ flag,
                                              int* __restrict__ gcur,
                                              u32* __restrict__ staging) {
    __shared__ int hist[NBKT];
    __shared__ int gbase[NBKT];
    __shared__ int cnt2[NBKT];
    int tid = threadIdx.x;
    if (tid < NBKT) hist[tid] = 0;
    __syncthreads();

    int base = blockIdx.x * 4096;
    int is32 = flag[0];
    int d[16], s[16];
    #pragma unroll
    for (int i = 0; i < 16; i++) {
        int e = base + i * 256 + tid;
        d[i] = -1;
        if (e < NE) {
            int dd = ld_dst(ei, is32, e);
            if ((unsigned)dd < (unsigned)NN) { d[i] = dd; s[i] = clampN(ld_src(ei, is32, e)); }
        } else if (e < NT) {
            d[i] = e - NE; s[i] = e - NE;
        }
        if (d[i] >= 0) atomicAdd(&hist[d[i] / BSZ], 1);
    }
    __syncthreads();
    if (tid < NBKT) {
        int c = hist[tid];
        gbase[tid] = c ? atomicAdd(&gcur[tid], c) : 0;
        cnt2[tid] = 0;
    }
    __syncthreads();
    #pragma unroll
    for (int i = 0; i < 16; i++) {
        if (d[i] >= 0) {
            int b = d[i] / BSZ;
            int pos = gbase[b] + atomicAdd(&cnt2[b], 1);
            if (pos < BCAP)
                staging[(size_t)b * BCAP + pos] =
                    ((unsigned)(d[i] - b * BSZ) << 17) | (unsigned)s[i];
        }
    }
}

__global__ void __launch_bounds__(256) k_hist(const u32* __restrict__ staging,
                                              const int* __restrict__ gcur,
                                              int* __restrict__ deg) {
    __shared__ int h[BSZ];
    int b = blockIdx.x;
    for (int l = threadIdx.x; l < BSZ; l += 256) h[l] = 0;
    __syncthreads();
    int cnt = min(gcur[b], BCAP);
    const u32* st = staging + (size_t)b * BCAP;
    for (int i = threadIdx.x; i < cnt; i += 256)
        atomicAdd(&h[st[i] >> 17], 1);
    __syncthreads();
    for (int l = threadIdx.x; l < BSZ; l += 256) {
        int g = b * BSZ + l;
        if (g < NN) deg[g] = h[l];
    }
}

__global__ void k_scan1(const int* __restrict__ deg, int* __restrict__ rowptr,
                        int* __restrict__ part) {
    __shared__ int sm[256];
    int i = blockIdx.x * 256 + threadIdx.x;
    int v = (i < NN) ? deg[i] : 0;
    sm[threadIdx.x] = v;
    __syncthreads();
    for (int off = 1; off < 256; off <<= 1) {
        int t = (threadIdx.x >= off) ? sm[threadIdx.x - off] : 0;
        __syncthreads();
        sm[threadIdx.x] += t;
        __syncthreads();
    }
    if (i < NN) rowptr[i] = sm[threadIdx.x] - v;
    if (threadIdx.x == 255) part[blockIdx.x] = sm[255];
}

__global__ void k_scan2(int* __restrict__ part, int nb) {
    __shared__ int sm[512];
    int t = threadIdx.x;
    int v = (t < nb) ? part[t] : 0;
    sm[t] = v;
    __syncthreads();
    for (int off = 1; off < 512; off <<= 1) {
        int u = (t >= off) ? sm[t - off] : 0;
        __syncthreads();
        sm[t] += u;
        __syncthreads();
    }
    if (t < nb) part[t] = sm[t] - v;
}

__global__ void k_scan3(int* __restrict__ rowptr, const int* __restrict__ part,
                        const int* __restrict__ deg, float* __restrict__ dinv) {
    int i = blockIdx.x * 256 + threadIdx.x;
    if (i < NN) {
        int d = deg[i];
        int r = rowptr[i] + part[blockIdx.x];
        rowptr[i] = r;
        dinv[i] = rsqrtf((float)(d > 0 ? d : 1));
        if (i == NN - 1) rowptr[NN] = r + d;
    }
}

__global__ void __launch_bounds__(256) k_scat(const u32* __restrict__ staging,
                                              const int* __restrict__ gcur,
                                              const int* __restrict__ rowptr,
                                              int* __restrict__ col) {
    __shared__ int cur[BSZ];
    int b = blockIdx.x;
    for (int l = threadIdx.x; l < BSZ; l += 256) {
        int g = b * BSZ + l;
        cur[l] = (g < NN) ? rowptr[g] : 0;
    }
    __syncthreads();
    int cnt = min(gcur[b], BCAP);
    const u32* st = staging + (size_t)b * BCAP;
    for (int i = threadIdx.x; i < cnt; i += 256) {
        u32 w = st[i];
        int l = w >> 17;
        int s = w & 0x1FFFF;
        int p = atomicAdd(&cur[l], 1);
        if ((unsigned)p < (unsigned)NT) col[p] = s;
    }
}

// ---------------- layer 1: GCN agg (fp32 8ch), dense 7->32 (bf16 out) ----------------

__global__ void __launch_bounds__(256) k_agg1(const float* __restrict__ xp,
                                              const int* __restrict__ rowptr,
                                              const int* __restrict__ col,
                                              const float* __restrict__ dinv,
                                              float* __restrict__ T1) {
    int gid = blockIdx.x * 256 + threadIdx.x;
    int n = gid >> 1;
    int lane = gid & 1;
    if (n >= NN) return;
    int beg = rowptr[n], end = rowptr[n + 1];
    float4 acc = {0.f, 0.f, 0.f, 0.f};
    #pragma unroll 4
    for (int e = beg; e < end; e++) {
        int s = clampN(col[e]);
        float w = dinv[s];
        float4 f = *(const float4*)(xp + (size_t)s * 8 + lane * 4);
        FMA4(acc, w, f);
    }
    float dn = dinv[n];
    acc.x *= dn; acc.y *= dn; acc.z *= dn; acc.w *= dn;
    *(float4*)(T1 + (size_t)n * 8 + lane * 4) = acc;
}

// O1 packed bf16: thread computes channels 2c,2c+1; alpha2 dots reduced over 16 lanes
__global__ void k_mm1a(const float* __restrict__ T1, const float* __restrict__ W1,
                       const float* __restrict__ b1, const float* __restrict__ va2,
                       const float* __restrict__ vd2, u32* __restrict__ O1b,
                       float* __restrict__ as_, float* __restrict__ ad_) {
    int idx = blockIdx.x * 256 + threadIdx.x;  // NN*16 exact
    int n = idx >> 4, c = idx & 15;            // channel pair c -> 2c,2c+1
    const float* t1 = T1 + (size_t)n * 8;
    float a0 = 0.f, a1 = 0.f;
    #pragma unroll
    for (int k = 0; k < 7; k++) {
        float t = t1[k];
        a0 += t * W1[k * 32 + 2 * c];
        a1 += t * W1[k * 32 + 2 * c + 1];
    }
    float o0 = fmaxf(a0 + b1[2 * c], 0.f);
    float o1 = fmaxf(a1 + b1[2 * c + 1], 0.f);
    O1b[(size_t)n * 16 + c] = pack2(o0, o1);
    float vs = o0 * va2[2 * c] + o1 * va2[2 * c + 1];
    float vd = o0 * vd2[2 * c] + o1 * vd2[2 * c + 1];
    #pragma unroll
    for (int off = 8; off > 0; off >>= 1) {
        vs += __shfl_down(vs, off, 16);
        vd += __shfl_down(vd, off, 16);
    }
    if (c == 0) { as_[n] = vs; ad_[n] = vd; }
}

// ---------------- layer 2: GAT two-pass softmax agg (bf16 rows, 4 lanes/node) ----------------

__global__ void __launch_bounds__(256) k_agg2(const u32* __restrict__ O1b,
                                              const float* __restrict__ as_,
                                              const float* __restrict__ ad_,
                                              const int* __restrict__ rowptr,
                                              const int* __restrict__ col,
                                              float* __restrict__ T2) {
    int gid = blockIdx.x * 256 + threadIdx.x;  // NN*4 exact
    int n = gid >> 2;
    int lane = gid & 3;                        // channels 8*lane .. 8*lane+7
    int beg = rowptr[n], end = rowptr[n + 1];
    float adn = ad_[n];
    float m = -1e30f;
    for (int e = beg + lane; e < end; e += 4) {
        float ee = as_[clampN(col[e])] + adn;
        ee = (ee > 0.f) ? ee : 0.2f * ee;
        m = fmaxf(m, ee);
    }
    m = fmaxf(m, __shfl_xor(m, 1, 4));
    m = fmaxf(m, __shfl_xor(m, 2, 4));
    float den = 0.f;
    float4 accA = {0,0,0,0}, accB = {0,0,0,0};
    for (int e = beg; e < end; e++) {
        int s = clampN(col[e]);
        float ee = as_[s] + adn;
        ee = (ee > 0.f) ? ee : 0.2f * ee;
        float p = __expf(ee - m);
        den += p;
        uint4 w = *(const uint4*)(O1b + (size_t)s * 16 + lane * 4);
        float2 f0 = b2x2(w.x), f1 = b2x2(w.y), f2 = b2x2(w.z), f3 = b2x2(w.w);
        accA.x += p * f0.x; accA.y += p * f0.y; accA.z += p * f1.x; accA.w += p * f1.y;
        accB.x += p * f2.x; accB.y += p * f2.y; accB.z += p * f3.x; accB.w += p * f3.y;
    }
    float inv = 1.0f / (den + 1e-16f);
    accA.x *= inv; accA.y *= inv; accA.z *= inv; accA.w *= inv;
    accB.x *= inv; accB.y *= inv; accB.z *= inv; accB.w *= inv;
    float* dst = T2 + (size_t)n * 32 + lane * 8;
    *(float4*)dst = accA;
    *(float4*)(dst + 4) = accB;
}

// O2 packed bf16 with dinv folded: thread computes channels 2c,2c+1
__global__ void k_mm2(const float* __restrict__ T2, const float* __restrict__ W2,
                      const float* __restrict__ b2, const float* __restrict__ dinv,
                      u32* __restrict__ O2b) {
    int gid = blockIdx.x * 256 + threadIdx.x;  // NN*32 exact
    int n = gid >> 5, c = gid & 31;            // channel pair -> 2c,2c+1
    const float* t2 = T2 + (size_t)n * 32;
    float a0 = 0.f, a1 = 0.f;
    #pragma unroll
    for (int k = 0; k < 32; k++) {
        float t = t2[k];
        a0 += t * W2[k * 64 + 2 * c];
        a1 += t * W2[k * 64 + 2 * c + 1];
    }
    float dn = dinv[n];
    float o0 = fmaxf(a0 + b2[2 * c], 0.f) * dn;
    float o1 = fmaxf(a1 + b2[2 * c + 1], 0.f) * dn;
    O2b[(size_t)n * 32 + c] = pack2(o0, o1);
}

// ---------------- layer 3: gather-sum over bf16 rows, 8 lanes/node ----------------

__global__ void __launch_bounds__(256) k_agg3(const u32* __restrict__ O2b,
                                              const int* __restrict__ rowptr,
                                              const int* __restrict__ col,
                                              const float* __restrict__ dinv,
                                              float* __restrict__ T3) {
    int gid = blockIdx.x * 256 + threadIdx.x;  // NN*8 exact
    int n = gid >> 3;
    int lane = gid & 7;                        // channels 8*lane .. +7
    int beg = rowptr[n], end = rowptr[n + 1];
    float4 accA = {0,0,0,0}, accB = {0,0,0,0};
    #pragma unroll 2
    for (int e = beg; e < end; e++) {
        int s = clampN(col[e]);
        uint4 w = *(const uint4*)(O2b + (size_t)s * 32 + lane * 4);
        float2 f0 = b2x2(w.x), f1 = b2x2(w.y), f2 = b2x2(w.z), f3 = b2x2(w.w);
        accA.x += f0.x; accA.y += f0.y; accA.z += f1.x; accA.w += f1.y;
        accB.x += f2.x; accB.y += f2.y; accB.z += f3.x; accB.w += f3.y;
    }
    float dn = dinv[n];
    accA.x *= dn; accA.y *= dn; accA.z *= dn; accA.w *= dn;
    accB.x *= dn; accB.y *= dn; accB.z *= dn; accB.w *= dn;
    float* dst = T3 + (size_t)n * 64 + lane * 8;
    *(float4*)dst = accA;
    *(float4*)(dst + 4) = accB;
}

// ---------------- dense: T3 -> W3 -> relu -> W4; h4as packed float4 ----------------

__global__ void __launch_bounds__(256) k_mm34(const float* __restrict__ T3,
                                              const float* __restrict__ W3,
                                              const float* __restrict__ b3,
                                              const float* __restrict__ W4,
                                              const float* __restrict__ av4s,
                                              const float* __restrict__ av4d,
                                              float4* __restrict__ h4as,
                                              float* __restrict__ as_,
                                              float* __restrict__ ad_) {
    __shared__ float sW3[64 * 128];
    __shared__ float sT3[32 * 64];
    __shared__ float sW4[128 * 2];
    __shared__ float sb3[128];
    {
        const float4* g = (const float4*)W3;
        float4* s4 = (float4*)sW3;
        #pragma unroll
        for (int i = 0; i < 8; i++) s4[threadIdx.x + 256 * i] = g[threadIdx.x + 256 * i];
    }
    {
        const float4* g = (const float4*)(T3 + (size_t)blockIdx.x * 32 * 64);
        float4* s4 = (float4*)sT3;
        s4[threadIdx.x] = g[threadIdx.x];
        s4[threadIdx.x + 256] = g[threadIdx.x + 256];
    }
    if (threadIdx.x < 128) {
        sb3[threadIdx.x] = b3[threadIdx.x];
        sW4[2 * threadIdx.x] = W4[2 * threadIdx.x];
        sW4[2 * threadIdx.x + 1] = W4[2 * threadIdx.x + 1];
    }
    __syncthreads();

    int w = threadIdx.x >> 6;
    int lane = threadIdx.x & 63;
    int half = lane >> 5;
    int lw = lane & 31;
    int lbase = w * 8 + half * 4;
    int c4 = lw * 4;

    float4 acc0 = {0,0,0,0}, acc1 = {0,0,0,0}, acc2 = {0,0,0,0}, acc3 = {0,0,0,0};
    #pragma unroll 4
    for (int k4 = 0; k4 < 16; k4++) {
        float4 t0 = *(const float4*)&sT3[(lbase + 0) * 64 + 4 * k4];
        float4 t1 = *(const float4*)&sT3[(lbase + 1) * 64 + 4 * k4];
        float4 t2 = *(const float4*)&sT3[(lbase + 2) * 64 + 4 * k4];
        float4 t3 = *(const float4*)&sT3[(lbase + 3) * 64 + 4 * k4];
        #pragma unroll
        for (int j = 0; j < 4; j++) {
            float4 wv = *(const float4*)&sW3[(4 * k4 + j) * 128 + c4];
            FMA4(acc0, ((const float*)&t0)[j], wv);
            FMA4(acc1, ((const float*)&t1)[j], wv);
            FMA4(acc2, ((const float*)&t2)[j], wv);
            FMA4(acc3, ((const float*)&t3)[j], wv);
        }
    }

    float4 bb = *(const float4*)&sb3[c4];
    float w40x = sW4[2 * c4],     w41x = sW4[2 * c4 + 1];
    float w40y = sW4[2 * c4 + 2], w41y = sW4[2 * c4 + 3];
    float w40z = sW4[2 * c4 + 4], w41z = sW4[2 * c4 + 5];
    float w40w = sW4[2 * c4 + 6], w41w = sW4[2 * c4 + 7];
    float av4s0 = av4s[0], av4s1 = av4s[1];
    float av4d0 = av4d[0], av4d1 = av4d[1];

    #pragma unroll
    for (int n = 0; n < 4; n++) {
        float4 a = (n == 0) ? acc0 : (n == 1) ? acc1 : (n == 2) ? acc2 : acc3;
        a.x = fmaxf(a.x + bb.x, 0.f);
        a.y = fmaxf(a.y + bb.y, 0.f);
        a.z = fmaxf(a.z + bb.z, 0.f);
        a.w = fmaxf(a.w + bb.w, 0.f);
        float p0 = a.x * w40x + a.y * w40y + a.z * w40z + a.w * w40w;
        float p1 = a.x * w41x + a.y * w41y + a.z * w41z + a.w * w41w;
        #pragma unroll
        for (int off = 16; off > 0; off >>= 1) {
            p0 += __shfl_down(p0, off, 32);
            p1 += __shfl_down(p1, off, 32);
        }
        if (lw == 0) {
            int gn = blockIdx.x * 32 + lbase + n;
            float asv = p0 * av4s0 + p1 * av4s1;
            float4 pk = {p0, p1, asv, 0.f};
            h4as[gn] = pk;
            as_[gn] = asv;
            ad_[gn] = p0 * av4d0 + p1 * av4d1;
        }
    }
}

// ---------------- final GAT (2ch) + log_softmax, 4 lanes/node ----------------

__global__ void k_final(const float4* __restrict__ h4as, const float* __restrict__ as_,
                        const float* __restrict__ ad_, const int* __restrict__ rowptr,
                        const int* __restrict__ col, const float* __restrict__ b,
                        float* __restrict__ out) {
    int gid = blockIdx.x * 256 + threadIdx.x;  // NN*4
    int n = gid >> 2;
    int lane = gid & 3;
    if (n >= NN) return;
    int beg = rowptr[n], end = rowptr[n + 1];
    float adn = ad_[n];
    float m = -1e30f;
    for (int e = beg + lane; e < end; e += 4) {
        float ee = as_[clampN(col[e])] + adn;
        ee = (ee > 0.f) ? ee : 0.2f * ee;
        m = fmaxf(m, ee);
    }
    m = fmaxf(m, __shfl_xor(m, 1, 4));
    m = fmaxf(m, __shfl_xor(m, 2, 4));
    float den = 0.f, a0 = 0.f, a1 = 0.f;
    for (int e = beg + lane; e < end; e += 4) {
        int s = clampN(col[e]);
        float4 h = h4as[s];
        float ee = h.z + adn;
        ee = (ee > 0.f) ? ee : 0.2f * ee;
        float p = __expf(ee - m);
        den += p;
        a0 += p * h.x;
        a1 += p * h.y;
    }
    den += __shfl_xor(den, 1, 4); den += __shfl_xor(den, 2, 4);
    a0  += __shfl_xor(a0, 1, 4);  a0  += __shfl_xor(a0, 2, 4);
    a1  += __shfl_xor(a1, 1, 4);  a1  += __shfl_xor(a1, 2, 4);
    if (lane == 0) {
        float inv = 1.0f / (den + 1e-16f);
        float v0 = a0 * inv + b[0];
        float v1 = a1 * inv + b[1];
        float mx = fmaxf(v0, v1);
        float lse = mx + logf(__expf(v0 - mx) + __expf(v1 - mx));
        float2 o = {v0 - lse, v1 - lse};
        *(float2*)(out + n * 2) = o;
    }
}

__global__ void k_sentinel(float* __restrict__ out, float v) {
    int i = blockIdx.x * 256 + threadIdx.x;
    if (i < NN * 2) out[i] = v;
}

// ---------------- launch ----------------

extern "C" void kernel_launch(void* const* d_in, const int* in_sizes, int n_in,
                              void* d_out, int out_size, void* d_ws, size_t ws_size,
                              hipStream_t stream) {
    const float* x    = (const float*)d_in[0];
    const int* ei     = (const int*)d_in[1];
    const float* W1   = (const float*)d_in[2];
    const float* b1   = (const float*)d_in[3];
    const float* W2   = (const float*)d_in[4];
    const float* a2s  = (const float*)d_in[5];
    const float* a2d  = (const float*)d_in[6];
    const float* b2   = (const float*)d_in[7];
    const float* W3   = (const float*)d_in[8];
    const float* b3   = (const float*)d_in[9];
    const float* W4   = (const float*)d_in[10];
    const float* a4s  = (const float*)d_in[11];
    const float* a4d  = (const float*)d_in[12];
    const float* b4   = (const float*)d_in[13];
    float* out = (float*)d_out;

    char* base = (char*)d_ws;
    size_t off = 0;
    auto alloc = [&](size_t bytes) {
        char* q = base + off;
        off += (bytes + 255) & ~(size_t)255;
        return q;
    };
    float* bufA  = (float*)alloc((size_t)NN * 64 * 4);   // xp -> O1b -> O2b
    float* bufB  = (float*)alloc((size_t)NN * 64 * 4);   // T1 -> T2 -> T3
    u32* staging = (u32*)alloc((size_t)NBKT * BCAP * 4);
    int* col     = (int*)alloc((size_t)NT * 4);
    int* rowptr  = (int*)alloc((size_t)(NN + 1) * 4);
    int* deg     = (int*)alloc((size_t)NN * 4);
    float* dinv  = (float*)alloc((size_t)NN * 4);
    float* as_   = (float*)alloc((size_t)NN * 4);
    float* ad_   = (float*)alloc((size_t)NN * 4);
    float4* h4as = (float4*)alloc((size_t)NN * 16);
    int* part    = (int*)alloc(512 * 4);
    int* flag    = (int*)alloc(256);
    int* gcur    = (int*)alloc(NBKT * 4);
    float* va2   = (float*)alloc(32 * 4);
    float* vd2   = (float*)alloc(32 * 4);

    float code = 0.f;
    if (off > ws_size)            code = 1000.f + (float)(ws_size >> 20);
    else if (n_in != 14)          code = 2000.f + 10.f * (float)n_in;
    else if (out_size != NN * 2)  code = 3400.f;
    if (code != 0.f) {
        k_sentinel<<<(NN * 2 + 255) / 256, 256, 0, stream>>>(out, code);
        return;
    }

    const int NB = (NN + 255) / 256;
    const int NTILE = (NT + 4095) / 4096;

    k_init<<<NN * 8 / 256, 256, 0, stream>>>(x, W2, a2s, a2d, ei, bufA, va2, vd2,
                                             flag, gcur);
    k_binA<<<NTILE, 256, 0, stream>>>(ei, flag, gcur, staging);
    k_hist<<<NBKT, 256, 0, stream>>>(staging, gcur, deg);
    k_scan1<<<NB, 256, 0, stream>>>(deg, rowptr, part);
    k_scan2<<<1, 512, 0, stream>>>(part, NB);
    k_scan3<<<NB, 256, 0, stream>>>(rowptr, part, deg, dinv);
    k_scat<<<NBKT, 256, 0, stream>>>(staging, gcur, rowptr, col);

    // layer 1: GCN (xp fp32 in bufA; T1 in bufB; O1b bf16 back into bufA)
    k_agg1<<<(NN * 2 + 255) / 256, 256, 0, stream>>>(bufA, rowptr, col, dinv, bufB);
    k_mm1a<<<NN * 16 / 256, 256, 0, stream>>>(bufB, W1, b1, va2, vd2, (u32*)bufA,
                                              as_, ad_);
    // layer 2: GAT (T2 fp32 in bufB; O2b bf16 into bufA)
    k_agg2<<<NN * 4 / 256, 256, 0, stream>>>((const u32*)bufA, as_, ad_, rowptr, col,
                                             bufB);
    k_mm2<<<NN * 32 / 256, 256, 0, stream>>>(bufB, W2, b2, dinv, (u32*)bufA);
    // layer 3: GCN gather over bf16 rows (T3 fp32 into bufB)
    k_agg3<<<NN * 8 / 256, 256, 0, stream>>>((const u32*)bufA, rowptr, col, dinv, bufB);
    // dense 3/4
    k_mm34<<<NN / 32, 256, 0, stream>>>(bufB, W3, b3, W4, a4s, a4d, h4as, as_, ad_);
    // layer 4 agg + log_softmax
    k_final<<<NN * 4 / 256 + 1, 256, 0, stream>>>(h4as, as_, ad_, rowptr, col, b4, out);
}

// Round 14
// 310.587 us; speedup vs baseline: 2.6540x; 1.1745x over previous
//
#include <hip/hip_runtime.h>
#include <hip/hip_bf16.h>

#define NN 100000
#define NE 1600000
#define NT (NN + NE)
#define NBKT 256
#define BSZ 391          // nodes per bucket; 256*391 = 100096 >= NN
#define BCAP 10240       // staging entries per bucket

typedef unsigned int u32;
typedef unsigned short u16;

static __device__ __forceinline__ int clampN(int s) {
    return ((unsigned)s < (unsigned)NN) ? s : 0;
}
static __device__ __forceinline__ int ld_src(const int* ei, int is32, int e) {
    return is32 ? ei[e] : ei[2 * e];
}
static __device__ __forceinline__ int ld_dst(const int* ei, int is32, int e) {
    return is32 ? ei[NE + e] : ei[2 * NE + 2 * e];
}
static __device__ __forceinline__ float2 b2x2(u32 u) {
    float2 r;
    r.x = __uint_as_float((u & 0xffffu) << 16);
    r.y = __uint_as_float(u & 0xffff0000u);
    return r;
}
static __device__ __forceinline__ u16 f2bs(float f) {
    union { __hip_bfloat16 b; u16 u; } cv;
    cv.b = __float2bfloat16(f);
    return cv.u;
}
static __device__ __forceinline__ u32 pack2(float x, float y) {
    return ((u32)f2bs(y) << 16) | (u32)f2bs(x);
}

#define FMA4(acc, s, v) { acc.x += (s)*(v).x; acc.y += (s)*(v).y; \
                          acc.z += (s)*(v).z; acc.w += (s)*(v).w; }

// ---------------- init ----------------

__global__ void __launch_bounds__(256) k_init(const float* __restrict__ x,
                                              const float* __restrict__ W2,
                                              const float* __restrict__ a2s,
                                              const float* __restrict__ a2d,
                                              const int* __restrict__ ei,
                                              float* __restrict__ xp,
                                              float* __restrict__ va2,
                                              float* __restrict__ vd2,
                                              int* __restrict__ flag,
                                              int* __restrict__ gcur) {
    int idx = blockIdx.x * 256 + threadIdx.x;   // grid covers NN*8
    if (blockIdx.x == 0) {
        if (threadIdx.x == 0) flag[0] = 0;
        __syncthreads();
        int nz = 0;
        for (int i = threadIdx.x; i < 4096; i += 256) nz |= ei[2 * i + 1];
        if (nz) atomicOr(flag, 1);
        if (threadIdx.x < NBKT) gcur[threadIdx.x] = 0;
    }
    if (blockIdx.x == 1 && threadIdx.x < 64) {
        int t = threadIdx.x;
        if (t < 32) {
            float a = 0.f;
            for (int c = 0; c < 64; c++) a += W2[t * 64 + c] * a2s[c];
            va2[t] = a;
        } else {
            int k = t - 32;
            float a = 0.f;
            for (int c = 0; c < 64; c++) a += W2[k * 64 + c] * a2d[c];
            vd2[k] = a;
        }
    }
    if (idx < NN * 8) {
        int n = idx >> 3, c = idx & 7;
        xp[idx] = (c < 7) ? x[n * 7 + c] : 0.f;  // pad 7->8, fp32
    }
}

// ---------------- CSR build (bucketed counting sort) ----------------

__global__ void __launch_bounds__(256) k_binA(const int* __restrict__ ei,
                                              const int* __restrict__ flag,
                                              int* __restrict__ gcur,
                                              u32* __restrict__ staging) {
    __shared__ int hist[NBKT];
    __shared__ int gbase[NBKT];
    __shared__ int cnt2[NBKT];
    int tid = threadIdx.x;
    if (tid < NBKT) hist[tid] = 0;
    __syncthreads();

    int base = blockIdx.x * 4096;
    int is32 = flag[0];
    int d[16], s[16];
    #pragma unroll
    for (int i = 0; i < 16; i++) {
        int e = base + i * 256 + tid;
        d[i] = -1;
        if (e < NE) {
            int dd = ld_dst(ei, is32, e);
            if ((unsigned)dd < (unsigned)NN) { d[i] = dd; s[i] = clampN(ld_src(ei, is32, e)); }
        } else if (e < NT) {
            d[i] = e - NE; s[i] = e - NE;
        }
        if (d[i] >= 0) atomicAdd(&hist[d[i] / BSZ], 1);
    }
    __syncthreads();
    if (tid < NBKT) {
        int c = hist[tid];
        gbase[tid] = c ? atomicAdd(&gcur[tid], c) : 0;
        cnt2[tid] = 0;
    }
    __syncthreads();
    #pragma unroll
    for (int i = 0; i < 16; i++) {
        if (d[i] >= 0) {
            int b = d[i] / BSZ;
            int pos = gbase[b] + atomicAdd(&cnt2[b], 1);
            if (pos < BCAP)
                staging[(size_t)b * BCAP + pos] =
                    ((unsigned)(d[i] - b * BSZ) << 17) | (unsigned)s[i];
        }
    }
}

__global__ void __launch_bounds__(256) k_hist(const u32* __restrict__ staging,
                                              const int* __restrict__ gcur,
                                              int* __restrict__ deg) {
    __shared__ int h[BSZ];
    int b = blockIdx.x;
    for (int l = threadIdx.x; l < BSZ; l += 256) h[l] = 0;
    __syncthreads();
    int cnt = min(gcur[b], BCAP);
    const u32* st = staging + (size_t)b * BCAP;
    for (int i = threadIdx.x; i < cnt; i += 256)
        atomicAdd(&h[st[i] >> 17], 1);
    __syncthreads();
    for (int l = threadIdx.x; l < BSZ; l += 256) {
        int g = b * BSZ + l;
        if (g < NN) deg[g] = h[l];
    }
}

__global__ void k_scan1(const int* __restrict__ deg, int* __restrict__ rowptr,
                        int* __restrict__ part) {
    __shared__ int sm[256];
    int i = blockIdx.x * 256 + threadIdx.x;
    int v = (i < NN) ? deg[i] : 0;
    sm[threadIdx.x] = v;
    __syncthreads();
    for (int off = 1; off < 256; off <<= 1) {
        int t = (threadIdx.x >= off) ? sm[threadIdx.x - off] : 0;
        __syncthreads();
        sm[threadIdx.x] += t;
        __syncthreads();
    }
    if (i < NN) rowptr[i] = sm[threadIdx.x] - v;
    if (threadIdx.x == 255) part[blockIdx.x] = sm[255];
}

__global__ void k_scan2(int* __restrict__ part, int nb) {
    __shared__ int sm[512];
    int t = threadIdx.x;
    int v = (t < nb) ? part[t] : 0;
    sm[t] = v;
    __syncthreads();
    for (int off = 1; off < 512; off <<= 1) {
        int u = (t >= off) ? sm[t - off] : 0;
        __syncthreads();
        sm[t] += u;
        __syncthreads();
    }
    if (t < nb) part[t] = sm[t] - v;
}

__global__ void k_scan3(int* __restrict__ rowptr, const int* __restrict__ part,
                        const int* __restrict__ deg, float* __restrict__ dinv) {
    int i = blockIdx.x * 256 + threadIdx.x;
    if (i < NN) {
        int d = deg[i];
        int r = rowptr[i] + part[blockIdx.x];
        rowptr[i] = r;
        dinv[i] = rsqrtf((float)(d > 0 ? d : 1));
        if (i == NN - 1) rowptr[NN] = r + d;
    }
}

__global__ void __launch_bounds__(256) k_scat(const u32* __restrict__ staging,
                                              const int* __restrict__ gcur,
                                              const int* __restrict__ rowptr,
                                              int* __restrict__ col) {
    __shared__ int cur[BSZ];
    int b = blockIdx.x;
    for (int l = threadIdx.x; l < BSZ; l += 256) {
        int g = b * BSZ + l;
        cur[l] = (g < NN) ? rowptr[g] : 0;
    }
    __syncthreads();
    int cnt = min(gcur[b], BCAP);
    const u32* st = staging + (size_t)b * BCAP;
    for (int i = threadIdx.x; i < cnt; i += 256) {
        u32 w = st[i];
        int l = w >> 17;
        int s = w & 0x1FFFF;
        int p = atomicAdd(&cur[l], 1);
        if ((unsigned)p < (unsigned)NT) col[p] = s;
    }
}

// ---------------- layer 1: GCN agg (fp32 8ch) ----------------

__global__ void __launch_bounds__(256) k_agg1(const float* __restrict__ xp,
                                              const int* __restrict__ rowptr,
                                              const int* __restrict__ col,
                                              const float* __restrict__ dinv,
                                              float* __restrict__ T1) {
    int gid = blockIdx.x * 256 + threadIdx.x;
    int n = gid >> 1;
    int lane = gid & 1;
    if (n >= NN) return;
    int beg = rowptr[n], end = rowptr[n + 1];
    float4 acc = {0.f, 0.f, 0.f, 0.f};
    #pragma unroll 4
    for (int e = beg; e < end; e++) {
        int s = clampN(col[e]);
        float w = dinv[s];
        float4 f = *(const float4*)(xp + (size_t)s * 8 + lane * 4);
        FMA4(acc, w, f);
    }
    float dn = dinv[n];
    acc.x *= dn; acc.y *= dn; acc.z *= dn; acc.w *= dn;
    *(float4*)(T1 + (size_t)n * 8 + lane * 4) = acc;
}

// O1 bf16; LDS-staged W1; 8 threads/node, 4 ch each; alpha via shfl_xor(w=8)
__global__ void __launch_bounds__(256) k_mm1a(const float* __restrict__ T1,
                                              const float* __restrict__ W1,
                                              const float* __restrict__ b1,
                                              const float* __restrict__ va2,
                                              const float* __restrict__ vd2,
                                              u32* __restrict__ O1b,
                                              float* __restrict__ as_,
                                              float* __restrict__ ad_) {
    __shared__ float sW1[7 * 32];
    __shared__ float sb1[32], sva[32], svd[32];
    if (threadIdx.x < 224) sW1[threadIdx.x] = W1[threadIdx.x];
    if (threadIdx.x >= 224) {
        int c = threadIdx.x - 224;
        sb1[c] = b1[c]; sva[c] = va2[c]; svd[c] = vd2[c];
    }
    __syncthreads();
    int gid = blockIdx.x * 256 + threadIdx.x;  // NN*8 exact
    int n = gid >> 3;
    int l = gid & 7;
    int c4 = l * 4;
    const float4* t4 = (const float4*)(T1 + (size_t)n * 8);
    float4 ta = t4[0], tb = t4[1];
    float t[8] = {ta.x, ta.y, ta.z, ta.w, tb.x, tb.y, tb.z, tb.w};
    float4 a = {0, 0, 0, 0};
    #pragma unroll
    for (int k = 0; k < 7; k++) {
        float4 wv = *(const float4*)&sW1[k * 32 + c4];
        FMA4(a, t[k], wv);
    }
    float o0 = fmaxf(a.x + sb1[c4], 0.f);
    float o1 = fmaxf(a.y + sb1[c4 + 1], 0.f);
    float o2 = fmaxf(a.z + sb1[c4 + 2], 0.f);
    float o3 = fmaxf(a.w + sb1[c4 + 3], 0.f);
    uint2 pk = {pack2(o0, o1), pack2(o2, o3)};
    *(uint2*)(O1b + (size_t)n * 16 + l * 2) = pk;
    float vs = o0 * sva[c4] + o1 * sva[c4 + 1] + o2 * sva[c4 + 2] + o3 * sva[c4 + 3];
    float vd = o0 * svd[c4] + o1 * svd[c4 + 1] + o2 * svd[c4 + 2] + o3 * svd[c4 + 3];
    vs += __shfl_xor(vs, 1, 8); vs += __shfl_xor(vs, 2, 8); vs += __shfl_xor(vs, 4, 8);
    vd += __shfl_xor(vd, 1, 8); vd += __shfl_xor(vd, 2, 8); vd += __shfl_xor(vd, 4, 8);
    if (l == 0) { as_[n] = vs; ad_[n] = vd; }
}

// ---------------- layer 2: GAT two-pass softmax agg (bf16 rows, 4 lanes/node) ----------------

__global__ void __launch_bounds__(256) k_agg2(const u32* __restrict__ O1b,
                                              const float* __restrict__ as_,
                                              const float* __restrict__ ad_,
                                              const int* __restrict__ rowptr,
                                              const int* __restrict__ col,
                                              float* __restrict__ T2) {
    int gid = blockIdx.x * 256 + threadIdx.x;  // NN*4 exact
    int n = gid >> 2;
    int lane = gid & 3;                        // channels 8*lane .. 8*lane+7
    int beg = rowptr[n], end = rowptr[n + 1];
    float adn = ad_[n];
    float m = -1e30f;
    for (int e = beg + lane; e < end; e += 4) {
        float ee = as_[clampN(col[e])] + adn;
        ee = (ee > 0.f) ? ee : 0.2f * ee;
        m = fmaxf(m, ee);
    }
    m = fmaxf(m, __shfl_xor(m, 1, 4));
    m = fmaxf(m, __shfl_xor(m, 2, 4));
    float den = 0.f;
    float4 accA = {0,0,0,0}, accB = {0,0,0,0};
    for (int e = beg; e < end; e++) {
        int s = clampN(col[e]);
        float ee = as_[s] + adn;
        ee = (ee > 0.f) ? ee : 0.2f * ee;
        float p = __expf(ee - m);
        den += p;
        uint4 w = *(const uint4*)(O1b + (size_t)s * 16 + lane * 4);
        float2 f0 = b2x2(w.x), f1 = b2x2(w.y), f2 = b2x2(w.z), f3 = b2x2(w.w);
        accA.x += p * f0.x; accA.y += p * f0.y; accA.z += p * f1.x; accA.w += p * f1.y;
        accB.x += p * f2.x; accB.y += p * f2.y; accB.z += p * f3.x; accB.w += p * f3.y;
    }
    float inv = 1.0f / (den + 1e-16f);
    accA.x *= inv; accA.y *= inv; accA.z *= inv; accA.w *= inv;
    accB.x *= inv; accB.y *= inv; accB.z *= inv; accB.w *= inv;
    float* dst = T2 + (size_t)n * 32 + lane * 8;
    *(float4*)dst = accA;
    *(float4*)(dst + 4) = accB;
}

// ---------------- dense 32->64: LDS-tiled; O2 bf16 with dinv folded ----------------
// 32 nodes/block; 16 groups x 16 lanes; each group: 2 nodes, lane: 4 consecutive ch.
// sT2 rows stride 36 floats -> group-broadcast reads land on distinct bank quads.

__global__ void __launch_bounds__(256) k_mm2(const float* __restrict__ T2,
                                             const float* __restrict__ W2,
                                             const float* __restrict__ b2,
                                             const float* __restrict__ dinv,
                                             u32* __restrict__ O2b) {
    __shared__ float sW2[32 * 64];    // 8 KB
    __shared__ float sT2[32 * 36];    // 4.6 KB, stride 36
    __shared__ float sb2[64];
    {
        const float4* g = (const float4*)W2;
        float4* s4 = (float4*)sW2;
        s4[threadIdx.x] = g[threadIdx.x];
        s4[threadIdx.x + 256] = g[threadIdx.x + 256];
    }
    {
        const float4* g = (const float4*)(T2 + (size_t)blockIdx.x * 32 * 32);
        int node = threadIdx.x >> 3, j = threadIdx.x & 7;
        ((float4*)sT2)[node * 9 + j] = g[threadIdx.x];
    }
    if (threadIdx.x < 64) sb2[threadIdx.x] = b2[threadIdx.x];
    __syncthreads();

    int grp = threadIdx.x >> 4;      // 16 groups
    int l = threadIdx.x & 15;
    int c4 = l * 4;
    int lbase = grp * 2;             // 2 nodes per group

    float4 acc0 = {0,0,0,0}, acc1 = {0,0,0,0};
    #pragma unroll
    for (int k4 = 0; k4 < 8; k4++) {
        float4 t0 = *(const float4*)&sT2[(lbase + 0) * 36 + 4 * k4];
        float4 t1 = *(const float4*)&sT2[(lbase + 1) * 36 + 4 * k4];
        #pragma unroll
        for (int j = 0; j < 4; j++) {
            float4 wv = *(const float4*)&sW2[(4 * k4 + j) * 64 + c4];
            FMA4(acc0, ((const float*)&t0)[j], wv);
            FMA4(acc1, ((const float*)&t1)[j], wv);
        }
    }
    float4 bb = *(const float4*)&sb2[c4];
    int n0 = blockIdx.x * 32 + lbase;
    float d0 = dinv[n0], d1 = dinv[n0 + 1];
    {
        float o0 = fmaxf(acc0.x + bb.x, 0.f) * d0;
        float o1 = fmaxf(acc0.y + bb.y, 0.f) * d0;
        float o2 = fmaxf(acc0.z + bb.z, 0.f) * d0;
        float o3 = fmaxf(acc0.w + bb.w, 0.f) * d0;
        uint2 pk = {pack2(o0, o1), pack2(o2, o3)};
        *(uint2*)(O2b + (size_t)n0 * 32 + l * 2) = pk;
    }
    {
        float o0 = fmaxf(acc1.x + bb.x, 0.f) * d1;
        float o1 = fmaxf(acc1.y + bb.y, 0.f) * d1;
        float o2 = fmaxf(acc1.z + bb.z, 0.f) * d1;
        float o3 = fmaxf(acc1.w + bb.w, 0.f) * d1;
        uint2 pk = {pack2(o0, o1), pack2(o2, o3)};
        *(uint2*)(O2b + (size_t)(n0 + 1) * 32 + l * 2) = pk;
    }
}

// ---------------- layer 3: gather-sum over bf16 rows, 8 lanes/node ----------------

__global__ void __launch_bounds__(256) k_agg3(const u32* __restrict__ O2b,
                                              const int* __restrict__ rowptr,
                                              const int* __restrict__ col,
                                              const float* __restrict__ dinv,
                                              float* __restrict__ T3) {
    int gid = blockIdx.x * 256 + threadIdx.x;  // NN*8 exact
    int n = gid >> 3;
    int lane = gid & 7;                        // channels 8*lane .. +7
    int beg = rowptr[n], end = rowptr[n + 1];
    float4 accA = {0,0,0,0}, accB = {0,0,0,0};
    #pragma unroll 2
    for (int e = beg; e < end; e++) {
        int s = clampN(col[e]);
        uint4 w = *(const uint4*)(O2b + (size_t)s * 32 + lane * 4);
        float2 f0 = b2x2(w.x), f1 = b2x2(w.y), f2 = b2x2(w.z), f3 = b2x2(w.w);
        accA.x += f0.x; accA.y += f0.y; accA.z += f1.x; accA.w += f1.y;
        accB.x += f2.x; accB.y += f2.y; accB.z += f3.x; accB.w += f3.y;
    }
    float dn = dinv[n];
    accA.x *= dn; accA.y *= dn; accA.z *= dn; accA.w *= dn;
    accB.x *= dn; accB.y *= dn; accB.z *= dn; accB.w *= dn;
    float* dst = T3 + (size_t)n * 64 + lane * 8;
    *(float4*)dst = accA;
    *(float4*)(dst + 4) = accB;
}

// ---------------- dense: T3 -> W3 -> relu -> W4; h4as packed float4 ----------------

__global__ void __launch_bounds__(256) k_mm34(const float* __restrict__ T3,
                                              const float* __restrict__ W3,
                                              const float* __restrict__ b3,
                                              const float* __restrict__ W4,
                                              const float* __restrict__ av4s,
                                              const float* __restrict__ av4d,
                                              float4* __restrict__ h4as,
                                              float* __restrict__ as_,
                                              float* __restrict__ ad_) {
    __shared__ float sW3[64 * 128];
    __shared__ float sT3[32 * 64];
    __shared__ float sW4[128 * 2];
    __shared__ float sb3[128];
    {
        const float4* g = (const float4*)W3;
        float4* s4 = (float4*)sW3;
        #pragma unroll
        for (int i = 0; i < 8; i++) s4[threadIdx.x + 256 * i] = g[threadIdx.x + 256 * i];
    }
    {
        const float4* g = (const float4*)(T3 + (size_t)blockIdx.x * 32 * 64);
        float4* s4 = (float4*)sT3;
        s4[threadIdx.x] = g[threadIdx.x];
        s4[threadIdx.x + 256] = g[threadIdx.x + 256];
    }
    if (threadIdx.x < 128) {
        sb3[threadIdx.x] = b3[threadIdx.x];
        sW4[2 * threadIdx.x] = W4[2 * threadIdx.x];
        sW4[2 * threadIdx.x + 1] = W4[2 * threadIdx.x + 1];
    }
    __syncthreads();

    int w = threadIdx.x >> 6;
    int lane = threadIdx.x & 63;
    int half = lane >> 5;
    int lw = lane & 31;
    int lbase = w * 8 + half * 4;
    int c4 = lw * 4;

    float4 acc0 = {0,0,0,0}, acc1 = {0,0,0,0}, acc2 = {0,0,0,0}, acc3 = {0,0,0,0};
    #pragma unroll 4
    for (int k4 = 0; k4 < 16; k4++) {
        float4 t0 = *(const float4*)&sT3[(lbase + 0) * 64 + 4 * k4];
        float4 t1 = *(const float4*)&sT3[(lbase + 1) * 64 + 4 * k4];
        float4 t2 = *(const float4*)&sT3[(lbase + 2) * 64 + 4 * k4];
        float4 t3 = *(const float4*)&sT3[(lbase + 3) * 64 + 4 * k4];
        #pragma unroll
        for (int j = 0; j < 4; j++) {
            float4 wv = *(const float4*)&sW3[(4 * k4 + j) * 128 + c4];
            FMA4(acc0, ((const float*)&t0)[j], wv);
            FMA4(acc1, ((const float*)&t1)[j], wv);
            FMA4(acc2, ((const float*)&t2)[j], wv);
            FMA4(acc3, ((const float*)&t3)[j], wv);
        }
    }

    float4 bb = *(const float4*)&sb3[c4];
    float w40x = sW4[2 * c4],     w41x = sW4[2 * c4 + 1];
    float w40y = sW4[2 * c4 + 2], w41y = sW4[2 * c4 + 3];
    float w40z = sW4[2 * c4 + 4], w41z = sW4[2 * c4 + 5];
    float w40w = sW4[2 * c4 + 6], w41w = sW4[2 * c4 + 7];
    float av4s0 = av4s[0], av4s1 = av4s[1];
    float av4d0 = av4d[0], av4d1 = av4d[1];

    #pragma unroll
    for (int n = 0; n < 4; n++) {
        float4 a = (n == 0) ? acc0 : (n == 1) ? acc1 : (n == 2) ? acc2 : acc3;
        a.x = fmaxf(a.x + bb.x, 0.f);
        a.y = fmaxf(a.y + bb.y, 0.f);
        a.z = fmaxf(a.z + bb.z, 0.f);
        a.w = fmaxf(a.w + bb.w, 0.f);
        float p0 = a.x * w40x + a.y * w40y + a.z * w40z + a.w * w40w;
        float p1 = a.x * w41x + a.y * w41y + a.z * w41z + a.w * w41w;
        #pragma unroll
        for (int off = 16; off > 0; off >>= 1) {
            p0 += __shfl_down(p0, off, 32);
            p1 += __shfl_down(p1, off, 32);
        }
        if (lw == 0) {
            int gn = blockIdx.x * 32 + lbase + n;
            float asv = p0 * av4s0 + p1 * av4s1;
            float4 pk = {p0, p1, asv, 0.f};
            h4as[gn] = pk;
            as_[gn] = asv;
            ad_[gn] = p0 * av4d0 + p1 * av4d1;
        }
    }
}

// ---------------- final GAT (2ch) + log_softmax, 4 lanes/node ----------------

__global__ void k_final(const float4* __restrict__ h4as, const float* __restrict__ as_,
                        const float* __restrict__ ad_, const int* __restrict__ rowptr,
                        const int* __restrict__ col, const float* __restrict__ b,
                        float* __restrict__ out) {
    int gid = blockIdx.x * 256 + threadIdx.x;  // NN*4
    int n = gid >> 2;
    int lane = gid & 3;
    if (n >= NN) return;
    int beg = rowptr[n], end = rowptr[n + 1];
    float adn = ad_[n];
    float m = -1e30f;
    for (int e = beg + lane; e < end; e += 4) {
        float ee = as_[clampN(col[e])] + adn;
        ee = (ee > 0.f) ? ee : 0.2f * ee;
        m = fmaxf(m, ee);
    }
    m = fmaxf(m, __shfl_xor(m, 1, 4));
    m = fmaxf(m, __shfl_xor(m, 2, 4));
    float den = 0.f, a0 = 0.f, a1 = 0.f;
    for (int e = beg + lane; e < end; e += 4) {
        int s = clampN(col[e]);
        float4 h = h4as[s];
        float ee = h.z + adn;
        ee = (ee > 0.f) ? ee : 0.2f * ee;
        float p = __expf(ee - m);
        den += p;
        a0 += p * h.x;
        a1 += p * h.y;
    }
    den += __shfl_xor(den, 1, 4); den += __shfl_xor(den, 2, 4);
    a0  += __shfl_xor(a0, 1, 4);  a0  += __shfl_xor(a0, 2, 4);
    a1  += __shfl_xor(a1, 1, 4);  a1  += __shfl_xor(a1, 2, 4);
    if (lane == 0) {
        float inv = 1.0f / (den + 1e-16f);
        float v0 = a0 * inv + b[0];
        float v1 = a1 * inv + b[1];
        float mx = fmaxf(v0, v1);
        float lse = mx + logf(__expf(v0 - mx) + __expf(v1 - mx));
        float2 o = {v0 - lse, v1 - lse};
        *(float2*)(out + n * 2) = o;
    }
}

__global__ void k_sentinel(float* __restrict__ out, float v) {
    int i = blockIdx.x * 256 + threadIdx.x;
    if (i < NN * 2) out[i] = v;
}

// ---------------- launch ----------------

extern "C" void kernel_launch(void* const* d_in, const int* in_sizes, int n_in,
                              void* d_out, int out_size, void* d_ws, size_t ws_size,
                              hipStream_t stream) {
    const float* x    = (const float*)d_in[0];
    const int* ei     = (const int*)d_in[1];
    const float* W1   = (const float*)d_in[2];
    const float* b1   = (const float*)d_in[3];
    const float* W2   = (const float*)d_in[4];
    const float* a2s  = (const float*)d_in[5];
    const float* a2d  = (const float*)d_in[6];
    const float* b2   = (const float*)d_in[7];
    const float* W3   = (const float*)d_in[8];
    const float* b3   = (const float*)d_in[9];
    const float* W4   = (const float*)d_in[10];
    const float* a4s  = (const float*)d_in[11];
    const float* a4d  = (const float*)d_in[12];
    const float* b4   = (const float*)d_in[13];
    float* out = (float*)d_out;

    char* base = (char*)d_ws;
    size_t off = 0;
    auto alloc = [&](size_t bytes) {
        char* q = base + off;
        off += (bytes + 255) & ~(size_t)255;
        return q;
    };
    float* bufA  = (float*)alloc((size_t)NN * 64 * 4);   // xp -> O1b -> O2b
    float* bufB  = (float*)alloc((size_t)NN * 64 * 4);   // T1 -> T2 -> T3
    u32* staging = (u32*)alloc((size_t)NBKT * BCAP * 4);
    int* col     = (int*)alloc((size_t)NT * 4);
    int* rowptr  = (int*)alloc((size_t)(NN + 1) * 4);
    int* deg     = (int*)alloc((size_t)NN * 4);
    float* dinv  = (float*)alloc((size_t)NN * 4);
    float* as_   = (float*)alloc((size_t)NN * 4);
    float* ad_   = (float*)alloc((size_t)NN * 4);
    float4* h4as = (float4*)alloc((size_t)NN * 16);
    int* part    = (int*)alloc(512 * 4);
    int* flag    = (int*)alloc(256);
    int* gcur    = (int*)alloc(NBKT * 4);
    float* va2   = (float*)alloc(32 * 4);
    float* vd2   = (float*)alloc(32 * 4);

    float code = 0.f;
    if (off > ws_size)            code = 1000.f + (float)(ws_size >> 20);
    else if (n_in != 14)          code = 2000.f + 10.f * (float)n_in;
    else if (out_size != NN * 2)  code = 3400.f;
    if (code != 0.f) {
        k_sentinel<<<(NN * 2 + 255) / 256, 256, 0, stream>>>(out, code);
        return;
    }

    const int NB = (NN + 255) / 256;
    const int NTILE = (NT + 4095) / 4096;

    k_init<<<NN * 8 / 256, 256, 0, stream>>>(x, W2, a2s, a2d, ei, bufA, va2, vd2,
                                             flag, gcur);
    k_binA<<<NTILE, 256, 0, stream>>>(ei, flag, gcur, staging);
    k_hist<<<NBKT, 256, 0, stream>>>(staging, gcur, deg);
    k_scan1<<<NB, 256, 0, stream>>>(deg, rowptr, part);
    k_scan2<<<1, 512, 0, stream>>>(part, NB);
    k_scan3<<<NB, 256, 0, stream>>>(rowptr, part, deg, dinv);
    k_scat<<<NBKT, 256, 0, stream>>>(staging, gcur, rowptr, col);

    // layer 1: GCN (xp fp32 in bufA; T1 in bufB; O1b bf16 back into bufA)
    k_agg1<<<(NN * 2 + 255) / 256, 256, 0, stream>>>(bufA, rowptr, col, dinv, bufB);
    k_mm1a<<<NN * 8 / 256, 256, 0, stream>>>(bufB, W1, b1, va2, vd2, (u32*)bufA,
                                             as_, ad_);
    // layer 2: GAT (T2 fp32 in bufB; O2b bf16 into bufA)
    k_agg2<<<NN * 4 / 256, 256, 0, stream>>>((const u32*)bufA, as_, ad_, rowptr, col,
                                             bufB);
    k_mm2<<<NN / 32, 256, 0, stream>>>(bufB, W2, b2, dinv, (u32*)bufA);
    // layer 3: GCN gather over bf16 rows (T3 fp32 into bufB)
    k_agg3<<<NN * 8 / 256, 256, 0, stream>>>((const u32*)bufA, rowptr, col, dinv, bufB);
    // dense 3/4
    k_mm34<<<NN / 32, 256, 0, stream>>>(bufB, W3, b3, W4, a4s, a4d, h4as, as_, ad_);
    // layer 4 agg + log_softmax
    k_final<<<NN * 4 / 256 + 1, 256, 0, stream>>>(h4as, as_, ad_, rowptr, col, b4, out);
}

// Round 15
// 308.074 us; speedup vs baseline: 2.6757x; 1.0082x over previous
//
#include <hip/hip_runtime.h>
#include <hip/hip_bf16.h>

#define NN 100000
#define NE 1600000
#define NT (NN + NE)
#define NBKT 256
#define BSZ 391          // nodes per bucket; 256*391 = 100096 >= NN
#define BCAP 10240       // staging entries per bucket

typedef unsigned int u32;
typedef unsigned short u16;

static __device__ __forceinline__ int clampN(int s) {
    return ((unsigned)s < (unsigned)NN) ? s : 0;
}
static __device__ __forceinline__ int ld_src(const int* ei, int is32, int e) {
    return is32 ? ei[e] : ei[2 * e];
}
static __device__ __forceinline__ int ld_dst(const int* ei, int is32, int e) {
    return is32 ? ei[NE + e] : ei[2 * NE + 2 * e];
}
static __device__ __forceinline__ float2 b2x2(u32 u) {
    float2 r;
    r.x = __uint_as_float((u & 0xffffu) << 16);
    r.y = __uint_as_float(u & 0xffff0000u);
    return r;
}
static __device__ __forceinline__ u16 f2bs(float f) {
    union { __hip_bfloat16 b; u16 u; } cv;
    cv.b = __float2bfloat16(f);
    return cv.u;
}
static __device__ __forceinline__ u32 pack2(float x, float y) {
    return ((u32)f2bs(y) << 16) | (u32)f2bs(x);
}

#define FMA4(acc, s, v) { acc.x += (s)*(v).x; acc.y += (s)*(v).y; \
                          acc.z += (s)*(v).z; acc.w += (s)*(v).w; }

// ---------------- init ----------------

__global__ void __launch_bounds__(256) k_init(const float* __restrict__ x,
                                              const float* __restrict__ W2,
                                              const float* __restrict__ a2s,
                                              const float* __restrict__ a2d,
                                              const int* __restrict__ ei,
                                              float* __restrict__ xp,
                                              float* __restrict__ va2,
                                              float* __restrict__ vd2,
                                              int* __restrict__ flag,
                                              int* __restrict__ gcur) {
    int idx = blockIdx.x * 256 + threadIdx.x;   // grid covers NN*8
    if (blockIdx.x == 0) {
        if (threadIdx.x == 0) flag[0] = 0;
        __syncthreads();
        int nz = 0;
        for (int i = threadIdx.x; i < 4096; i += 256) nz |= ei[2 * i + 1];
        if (nz) atomicOr(flag, 1);
        if (threadIdx.x < NBKT) gcur[threadIdx.x] = 0;
    }
    if (blockIdx.x == 1 && threadIdx.x < 64) {
        int t = threadIdx.x;
        if (t < 32) {
            float a = 0.f;
            for (int c = 0; c < 64; c++) a += W2[t * 64 + c] * a2s[c];
            va2[t] = a;
        } else {
            int k = t - 32;
            float a = 0.f;
            for (int c = 0; c < 64; c++) a += W2[k * 64 + c] * a2d[c];
            vd2[k] = a;
        }
    }
    if (idx < NN * 8) {
        int n = idx >> 3, c = idx & 7;
        xp[idx] = (c < 7) ? x[n * 7 + c] : 0.f;  // pad 7->8, fp32
    }
}

// ---------------- CSR build (bucketed counting sort) ----------------

__global__ void __launch_bounds__(256) k_binA(const int* __restrict__ ei,
                                              const int* __restrict__ flag,
                                              int* __restrict__ gcur,
                                              u32* __restrict__ staging) {
    __shared__ int hist[NBKT];
    __shared__ int gbase[NBKT];
    __shared__ int cnt2[NBKT];
    int tid = threadIdx.x;
    if (tid < NBKT) hist[tid] = 0;
    __syncthreads();

    int base = blockIdx.x * 4096;
    int is32 = flag[0];
    int d[16], s[16];
    #pragma unroll
    for (int i = 0; i < 16; i++) {
        int e = base + i * 256 + tid;
        d[i] = -1;
        if (e < NE) {
            int dd = ld_dst(ei, is32, e);
            if ((unsigned)dd < (unsigned)NN) { d[i] = dd; s[i] = clampN(ld_src(ei, is32, e)); }
        } else if (e < NT) {
            d[i] = e - NE; s[i] = e - NE;
        }
        if (d[i] >= 0) atomicAdd(&hist[d[i] / BSZ], 1);
    }
    __syncthreads();
    if (tid < NBKT) {
        int c = hist[tid];
        gbase[tid] = c ? atomicAdd(&gcur[tid], c) : 0;
        cnt2[tid] = 0;
    }
    __syncthreads();
    #pragma unroll
    for (int i = 0; i < 16; i++) {
        if (d[i] >= 0) {
            int b = d[i] / BSZ;
            int pos = gbase[b] + atomicAdd(&cnt2[b], 1);
            if (pos < BCAP)
                staging[(size_t)b * BCAP + pos] =
                    ((unsigned)(d[i] - b * BSZ) << 17) | (unsigned)s[i];
        }
    }
}

__global__ void __launch_bounds__(256) k_hist(const u32* __restrict__ staging,
                                              const int* __restrict__ gcur,
                                              int* __restrict__ deg) {
    __shared__ int h[BSZ];
    int b = blockIdx.x;
    for (int l = threadIdx.x; l < BSZ; l += 256) h[l] = 0;
    __syncthreads();
    int cnt = min(gcur[b], BCAP);
    const u32* st = staging + (size_t)b * BCAP;
    for (int i = threadIdx.x; i < cnt; i += 256)
        atomicAdd(&h[st[i] >> 17], 1);
    __syncthreads();
    for (int l = threadIdx.x; l < BSZ; l += 256) {
        int g = b * BSZ + l;
        if (g < NN) deg[g] = h[l];
    }
}

__global__ void k_scan1(const int* __restrict__ deg, int* __restrict__ rowptr,
                        int* __restrict__ part) {
    __shared__ int sm[256];
    int i = blockIdx.x * 256 + threadIdx.x;
    int v = (i < NN) ? deg[i] : 0;
    sm[threadIdx.x] = v;
    __syncthreads();
    for (int off = 1; off < 256; off <<= 1) {
        int t = (threadIdx.x >= off) ? sm[threadIdx.x - off] : 0;
        __syncthreads();
        sm[threadIdx.x] += t;
        __syncthreads();
    }
    if (i < NN) rowptr[i] = sm[threadIdx.x] - v;
    if (threadIdx.x == 255) part[blockIdx.x] = sm[255];
}

__global__ void k_scan2(int* __restrict__ part, int nb) {
    __shared__ int sm[512];
    int t = threadIdx.x;
    int v = (t < nb) ? part[t] : 0;
    sm[t] = v;
    __syncthreads();
    for (int off = 1; off < 512; off <<= 1) {
        int u = (t >= off) ? sm[t - off] : 0;
        __syncthreads();
        sm[t] += u;
        __syncthreads();
    }
    if (t < nb) part[t] = sm[t] - v;
}

__global__ void k_scan3(int* __restrict__ rowptr, const int* __restrict__ part,
                        const int* __restrict__ deg, float* __restrict__ dinv) {
    int i = blockIdx.x * 256 + threadIdx.x;
    if (i < NN) {
        int d = deg[i];
        int r = rowptr[i] + part[blockIdx.x];
        rowptr[i] = r;
        dinv[i] = rsqrtf((float)(d > 0 ? d : 1));
        if (i == NN - 1) rowptr[NN] = r + d;
    }
}

__global__ void __launch_bounds__(256) k_scat(const u32* __restrict__ staging,
                                              const int* __restrict__ gcur,
                                              const int* __restrict__ rowptr,
                                              int* __restrict__ col) {
    __shared__ int cur[BSZ];
    int b = blockIdx.x;
    for (int l = threadIdx.x; l < BSZ; l += 256) {
        int g = b * BSZ + l;
        cur[l] = (g < NN) ? rowptr[g] : 0;
    }
    __syncthreads();
    int cnt = min(gcur[b], BCAP);
    const u32* st = staging + (size_t)b * BCAP;
    for (int i = threadIdx.x; i < cnt; i += 256) {
        u32 w = st[i];
        int l = w >> 17;
        int s = w & 0x1FFFF;
        int p = atomicAdd(&cur[l], 1);
        if ((unsigned)p < (unsigned)NT) col[p] = s;
    }
}

// ---------------- layer 1: GCN agg (fp32 8ch), 4 lanes/node ----------------

__global__ void __launch_bounds__(256) k_agg1(const float* __restrict__ xp,
                                              const int* __restrict__ rowptr,
                                              const int* __restrict__ col,
                                              const float* __restrict__ dinv,
                                              float* __restrict__ T1) {
    int gid = blockIdx.x * 256 + threadIdx.x;  // NN*4 exact
    int n = gid >> 2;
    int lane = gid & 3;                        // channels 2*lane, 2*lane+1
    int beg = rowptr[n], end = rowptr[n + 1];
    float ax = 0.f, ay = 0.f;
    #pragma unroll 4
    for (int e = beg; e < end; e++) {
        int s = clampN(col[e]);
        float w = dinv[s];
        float2 f = *(const float2*)(xp + (size_t)s * 8 + lane * 2);
        ax += w * f.x;
        ay += w * f.y;
    }
    float dn = dinv[n];
    float2 o = {ax * dn, ay * dn};
    *(float2*)(T1 + (size_t)n * 8 + lane * 2) = o;
}

// O1 bf16; LDS-staged W1; 8 threads/node, 4 ch each; alpha via shfl_xor(w=8)
__global__ void __launch_bounds__(256) k_mm1a(const float* __restrict__ T1,
                                              const float* __restrict__ W1,
                                              const float* __restrict__ b1,
                                              const float* __restrict__ va2,
                                              const float* __restrict__ vd2,
                                              u32* __restrict__ O1b,
                                              float* __restrict__ as_,
                                              float* __restrict__ ad_) {
    __shared__ float sW1[7 * 32];
    __shared__ float sb1[32], sva[32], svd[32];
    if (threadIdx.x < 224) sW1[threadIdx.x] = W1[threadIdx.x];
    if (threadIdx.x >= 224) {
        int c = threadIdx.x - 224;
        sb1[c] = b1[c]; sva[c] = va2[c]; svd[c] = vd2[c];
    }
    __syncthreads();
    int gid = blockIdx.x * 256 + threadIdx.x;  // NN*8 exact
    int n = gid >> 3;
    int l = gid & 7;
    int c4 = l * 4;
    const float4* t4 = (const float4*)(T1 + (size_t)n * 8);
    float4 ta = t4[0], tb = t4[1];
    float t[8] = {ta.x, ta.y, ta.z, ta.w, tb.x, tb.y, tb.z, tb.w};
    float4 a = {0, 0, 0, 0};
    #pragma unroll
    for (int k = 0; k < 7; k++) {
        float4 wv = *(const float4*)&sW1[k * 32 + c4];
        FMA4(a, t[k], wv);
    }
    float o0 = fmaxf(a.x + sb1[c4], 0.f);
    float o1 = fmaxf(a.y + sb1[c4 + 1], 0.f);
    float o2 = fmaxf(a.z + sb1[c4 + 2], 0.f);
    float o3 = fmaxf(a.w + sb1[c4 + 3], 0.f);
    uint2 pk = {pack2(o0, o1), pack2(o2, o3)};
    *(uint2*)(O1b + (size_t)n * 16 + l * 2) = pk;
    float vs = o0 * sva[c4] + o1 * sva[c4 + 1] + o2 * sva[c4 + 2] + o3 * sva[c4 + 3];
    float vd = o0 * svd[c4] + o1 * svd[c4 + 1] + o2 * svd[c4 + 2] + o3 * svd[c4 + 3];
    vs += __shfl_xor(vs, 1, 8); vs += __shfl_xor(vs, 2, 8); vs += __shfl_xor(vs, 4, 8);
    vd += __shfl_xor(vd, 1, 8); vd += __shfl_xor(vd, 2, 8); vd += __shfl_xor(vd, 4, 8);
    if (l == 0) { as_[n] = vs; ad_[n] = vd; }
}

// ---------------- layer 2: GAT two-pass softmax agg (bf16 rows, 8 lanes/node) ----------------

__global__ void __launch_bounds__(256) k_agg2(const u32* __restrict__ O1b,
                                              const float* __restrict__ as_,
                                              const float* __restrict__ ad_,
                                              const int* __restrict__ rowptr,
                                              const int* __restrict__ col,
                                              float* __restrict__ T2) {
    int gid = blockIdx.x * 256 + threadIdx.x;  // NN*8 exact
    int n = gid >> 3;
    int lane = gid & 7;                        // channels 4*lane .. 4*lane+3
    int beg = rowptr[n], end = rowptr[n + 1];
    float adn = ad_[n];
    float m = -1e30f;
    for (int e = beg + lane; e < end; e += 8) {
        float ee = as_[clampN(col[e])] + adn;
        ee = (ee > 0.f) ? ee : 0.2f * ee;
        m = fmaxf(m, ee);
    }
    m = fmaxf(m, __shfl_xor(m, 1, 8));
    m = fmaxf(m, __shfl_xor(m, 2, 8));
    m = fmaxf(m, __shfl_xor(m, 4, 8));
    float den = 0.f;
    float4 acc = {0, 0, 0, 0};
    #pragma unroll 2
    for (int e = beg; e < end; e++) {
        int s = clampN(col[e]);
        float ee = as_[s] + adn;
        ee = (ee > 0.f) ? ee : 0.2f * ee;
        float p = __expf(ee - m);
        den += p;
        uint2 w = *(const uint2*)(O1b + (size_t)s * 16 + lane * 2);
        float2 f0 = b2x2(w.x), f1 = b2x2(w.y);
        acc.x += p * f0.x; acc.y += p * f0.y; acc.z += p * f1.x; acc.w += p * f1.y;
    }
    float inv = 1.0f / (den + 1e-16f);
    acc.x *= inv; acc.y *= inv; acc.z *= inv; acc.w *= inv;
    *(float4*)(T2 + (size_t)n * 32 + lane * 4) = acc;
}

// ---------------- dense 32->64: LDS-tiled; O2 bf16 with dinv folded ----------------

__global__ void __launch_bounds__(256) k_mm2(const float* __restrict__ T2,
                                             const float* __restrict__ W2,
                                             const float* __restrict__ b2,
                                             const float* __restrict__ dinv,
                                             u32* __restrict__ O2b) {
    __shared__ float sW2[32 * 64];    // 8 KB
    __shared__ float sT2[32 * 36];    // 4.6 KB, stride 36
    __shared__ float sb2[64];
    {
        const float4* g = (const float4*)W2;
        float4* s4 = (float4*)sW2;
        s4[threadIdx.x] = g[threadIdx.x];
        s4[threadIdx.x + 256] = g[threadIdx.x + 256];
    }
    {
        const float4* g = (const float4*)(T2 + (size_t)blockIdx.x * 32 * 32);
        int node = threadIdx.x >> 3, j = threadIdx.x & 7;
        ((float4*)sT2)[node * 9 + j] = g[threadIdx.x];
    }
    if (threadIdx.x < 64) sb2[threadIdx.x] = b2[threadIdx.x];
    __syncthreads();

    int grp = threadIdx.x >> 4;      // 16 groups
    int l = threadIdx.x & 15;
    int c4 = l * 4;
    int lbase = grp * 2;             // 2 nodes per group

    float4 acc0 = {0,0,0,0}, acc1 = {0,0,0,0};
    #pragma unroll
    for (int k4 = 0; k4 < 8; k4++) {
        float4 t0 = *(const float4*)&sT2[(lbase + 0) * 36 + 4 * k4];
        float4 t1 = *(const float4*)&sT2[(lbase + 1) * 36 + 4 * k4];
        #pragma unroll
        for (int j = 0; j < 4; j++) {
            float4 wv = *(const float4*)&sW2[(4 * k4 + j) * 64 + c4];
            FMA4(acc0, ((const float*)&t0)[j], wv);
            FMA4(acc1, ((const float*)&t1)[j], wv);
        }
    }
    float4 bb = *(const float4*)&sb2[c4];
    int n0 = blockIdx.x * 32 + lbase;
    float d0 = dinv[n0], d1 = dinv[n0 + 1];
    {
        float o0 = fmaxf(acc0.x + bb.x, 0.f) * d0;
        float o1 = fmaxf(acc0.y + bb.y, 0.f) * d0;
        float o2 = fmaxf(acc0.z + bb.z, 0.f) * d0;
        float o3 = fmaxf(acc0.w + bb.w, 0.f) * d0;
        uint2 pk = {pack2(o0, o1), pack2(o2, o3)};
        *(uint2*)(O2b + (size_t)n0 * 32 + l * 2) = pk;
    }
    {
        float o0 = fmaxf(acc1.x + bb.x, 0.f) * d1;
        float o1 = fmaxf(acc1.y + bb.y, 0.f) * d1;
        float o2 = fmaxf(acc1.z + bb.z, 0.f) * d1;
        float o3 = fmaxf(acc1.w + bb.w, 0.f) * d1;
        uint2 pk = {pack2(o0, o1), pack2(o2, o3)};
        *(uint2*)(O2b + (size_t)(n0 + 1) * 32 + l * 2) = pk;
    }
}

// ---------------- layer 3: gather-sum over bf16 rows, 8 lanes/node ----------------

__global__ void __launch_bounds__(256) k_agg3(const u32* __restrict__ O2b,
                                              const int* __restrict__ rowptr,
                                              const int* __restrict__ col,
                                              const float* __restrict__ dinv,
                                              float* __restrict__ T3) {
    int gid = blockIdx.x * 256 + threadIdx.x;  // NN*8 exact
    int n = gid >> 3;
    int lane = gid & 7;                        // channels 8*lane .. +7
    int beg = rowptr[n], end = rowptr[n + 1];
    float4 accA = {0,0,0,0}, accB = {0,0,0,0};
    #pragma unroll 2
    for (int e = beg; e < end; e++) {
        int s = clampN(col[e]);
        uint4 w = *(const uint4*)(O2b + (size_t)s * 32 + lane * 4);
        float2 f0 = b2x2(w.x), f1 = b2x2(w.y), f2 = b2x2(w.z), f3 = b2x2(w.w);
        accA.x += f0.x; accA.y += f0.y; accA.z += f1.x; accA.w += f1.y;
        accB.x += f2.x; accB.y += f2.y; accB.z += f3.x; accB.w += f3.y;
    }
    float dn = dinv[n];
    accA.x *= dn; accA.y *= dn; accA.z *= dn; accA.w *= dn;
    accB.x *= dn; accB.y *= dn; accB.z *= dn; accB.w *= dn;
    float* dst = T3 + (size_t)n * 64 + lane * 8;
    *(float4*)dst = accA;
    *(float4*)(dst + 4) = accB;
}

// ---------------- dense: T3 -> W3 -> relu -> W4; h4as packed float4 ----------------

__global__ void __launch_bounds__(256) k_mm34(const float* __restrict__ T3,
                                              const float* __restrict__ W3,
                                              const float* __restrict__ b3,
                                              const float* __restrict__ W4,
                                              const float* __restrict__ av4s,
                                              const float* __restrict__ av4d,
                                              float4* __restrict__ h4as,
                                              float* __restrict__ as_,
                                              float* __restrict__ ad_) {
    __shared__ float sW3[64 * 128];
    __shared__ float sT3[32 * 64];
    __shared__ float sW4[128 * 2];
    __shared__ float sb3[128];
    {
        const float4* g = (const float4*)W3;
        float4* s4 = (float4*)sW3;
        #pragma unroll
        for (int i = 0; i < 8; i++) s4[threadIdx.x + 256 * i] = g[threadIdx.x + 256 * i];
    }
    {
        const float4* g = (const float4*)(T3 + (size_t)blockIdx.x * 32 * 64);
        float4* s4 = (float4*)sT3;
        s4[threadIdx.x] = g[threadIdx.x];
        s4[threadIdx.x + 256] = g[threadIdx.x + 256];
    }
    if (threadIdx.x < 128) {
        sb3[threadIdx.x] = b3[threadIdx.x];
        sW4[2 * threadIdx.x] = W4[2 * threadIdx.x];
        sW4[2 * threadIdx.x + 1] = W4[2 * threadIdx.x + 1];
    }
    __syncthreads();

    int w = threadIdx.x >> 6;
    int lane = threadIdx.x & 63;
    int half = lane >> 5;
    int lw = lane & 31;
    int lbase = w * 8 + half * 4;
    int c4 = lw * 4;

    float4 acc0 = {0,0,0,0}, acc1 = {0,0,0,0}, acc2 = {0,0,0,0}, acc3 = {0,0,0,0};
    #pragma unroll 4
    for (int k4 = 0; k4 < 16; k4++) {
        float4 t0 = *(const float4*)&sT3[(lbase + 0) * 64 + 4 * k4];
        float4 t1 = *(const float4*)&sT3[(lbase + 1) * 64 + 4 * k4];
        float4 t2 = *(const float4*)&sT3[(lbase + 2) * 64 + 4 * k4];
        float4 t3 = *(const float4*)&sT3[(lbase + 3) * 64 + 4 * k4];
        #pragma unroll
        for (int j = 0; j < 4; j++) {
            float4 wv = *(const float4*)&sW3[(4 * k4 + j) * 128 + c4];
            FMA4(acc0, ((const float*)&t0)[j], wv);
            FMA4(acc1, ((const float*)&t1)[j], wv);
            FMA4(acc2, ((const float*)&t2)[j], wv);
            FMA4(acc3, ((const float*)&t3)[j], wv);
        }
    }

    float4 bb = *(const float4*)&sb3[c4];
    float w40x = sW4[2 * c4],     w41x = sW4[2 * c4 + 1];
    float w40y = sW4[2 * c4 + 2], w41y = sW4[2 * c4 + 3];
    float w40z = sW4[2 * c4 + 4], w41z = sW4[2 * c4 + 5];
    float w40w = sW4[2 * c4 + 6], w41w = sW4[2 * c4 + 7];
    float av4s0 = av4s[0], av4s1 = av4s[1];
    float av4d0 = av4d[0], av4d1 = av4d[1];

    #pragma unroll
    for (int n = 0; n < 4; n++) {
        float4 a = (n == 0) ? acc0 : (n == 1) ? acc1 : (n == 2) ? acc2 : acc3;
        a.x = fmaxf(a.x + bb.x, 0.f);
        a.y = fmaxf(a.y + bb.y, 0.f);
        a.z = fmaxf(a.z + bb.z, 0.f);
        a.w = fmaxf(a.w + bb.w, 0.f);
        float p0 = a.x * w40x + a.y * w40y + a.z * w40z + a.w * w40w;
        float p1 = a.x * w41x + a.y * w41y + a.z * w41z + a.w * w41w;
        #pragma unroll
        for (int off = 16; off > 0; off >>= 1) {
            p0 += __shfl_down(p0, off, 32);
            p1 += __shfl_down(p1, off, 32);
        }
        if (lw == 0) {
            int gn = blockIdx.x * 32 + lbase + n;
            float asv = p0 * av4s0 + p1 * av4s1;
            float4 pk = {p0, p1, asv, 0.f};
            h4as[gn] = pk;
            as_[gn] = asv;
            ad_[gn] = p0 * av4d0 + p1 * av4d1;
        }
    }
}

// ---------------- final GAT (2ch) + log_softmax, 4 lanes/node ----------------

__global__ void k_final(const float4* __restrict__ h4as, const float* __restrict__ as_,
                        const float* __restrict__ ad_, const int* __restrict__ rowptr,
                        const int* __restrict__ col, const float* __restrict__ b,
                        float* __restrict__ out) {
    int gid = blockIdx.x * 256 + threadIdx.x;  // NN*4
    int n = gid >> 2;
    int lane = gid & 2;
    if (n >= NN) return;
    int lsub = gid & 3;
    int beg = rowptr[n], end = rowptr[n + 1];
    float adn = ad_[n];
    float m = -1e30f;
    for (int e = beg + lsub; e < end; e += 4) {
        float ee = as_[clampN(col[e])] + adn;
        ee = (ee > 0.f) ? ee : 0.2f * ee;
        m = fmaxf(m, ee);
    }
    m = fmaxf(m, __shfl_xor(m, 1, 4));
    m = fmaxf(m, __shfl_xor(m, 2, 4));
    float den = 0.f, a0 = 0.f, a1 = 0.f;
    for (int e = beg + lsub; e < end; e += 4) {
        int s = clampN(col[e]);
        float4 h = h4as[s];
        float ee = h.z + adn;
        ee = (ee > 0.f) ? ee : 0.2f * ee;
        float p = __expf(ee - m);
        den += p;
        a0 += p * h.x;
        a1 += p * h.y;
    }
    den += __shfl_xor(den, 1, 4); den += __shfl_xor(den, 2, 4);
    a0  += __shfl_xor(a0, 1, 4);  a0  += __shfl_xor(a0, 2, 4);
    a1  += __shfl_xor(a1, 1, 4);  a1  += __shfl_xor(a1, 2, 4);
    if (lsub == 0) {
        float inv = 1.0f / (den + 1e-16f);
        float v0 = a0 * inv + b[0];
        float v1 = a1 * inv + b[1];
        float mx = fmaxf(v0, v1);
        float lse = mx + logf(__expf(v0 - mx) + __expf(v1 - mx));
        float2 o = {v0 - lse, v1 - lse};
        *(float2*)(out + n * 2) = o;
    }
}

__global__ void k_sentinel(float* __restrict__ out, float v) {
    int i = blockIdx.x * 256 + threadIdx.x;
    if (i < NN * 2) out[i] = v;
}

// ---------------- launch ----------------

extern "C" void kernel_launch(void* const* d_in, const int* in_sizes, int n_in,
                              void* d_out, int out_size, void* d_ws, size_t ws_size,
                              hipStream_t stream) {
    const float* x    = (const float*)d_in[0];
    const int* ei     = (const int*)d_in[1];
    const float* W1   = (const float*)d_in[2];
    const float* b1   = (const float*)d_in[3];
    const float* W2   = (const float*)d_in[4];
    const float* a2s  = (const float*)d_in[5];
    const float* a2d  = (const float*)d_in[6];
    const float* b2   = (const float*)d_in[7];
    const float* W3   = (const float*)d_in[8];
    const float* b3   = (const float*)d_in[9];
    const float* W4   = (const float*)d_in[10];
    const float* a4s  = (const float*)d_in[11];
    const float* a4d  = (const float*)d_in[12];
    const float* b4   = (const float*)d_in[13];
    float* out = (float*)d_out;

    char* base = (char*)d_ws;
    size_t off = 0;
    auto alloc = [&](size_t bytes) {
        char* q = base + off;
        off += (bytes + 255) & ~(size_t)255;
        return q;
    };
    float* bufA  = (float*)alloc((size_t)NN * 64 * 4);   // xp -> O1b -> O2b
    float* bufB  = (float*)alloc((size_t)NN * 64 * 4);   // T1 -> T2 -> T3
    u32* staging = (u32*)alloc((size_t)NBKT * BCAP * 4);
    int* col     = (int*)alloc((size_t)NT * 4);
    int* rowptr  = (int*)alloc((size_t)(NN + 1) * 4);
    int* deg     = (int*)alloc((size_t)NN * 4);
    float* dinv  = (float*)alloc((size_t)NN * 4);
    float* as_   = (float*)alloc((size_t)NN * 4);
    float* ad_   = (float*)alloc((size_t)NN * 4);
    float4* h4as = (float4*)alloc((size_t)NN * 16);
    int* part    = (int*)alloc(512 * 4);
    int* flag    = (int*)alloc(256);
    int* gcur    = (int*)alloc(NBKT * 4);
    float* va2   = (float*)alloc(32 * 4);
    float* vd2   = (float*)alloc(32 * 4);

    float code = 0.f;
    if (off > ws_size)            code = 1000.f + (float)(ws_size >> 20);
    else if (n_in != 14)          code = 2000.f + 10.f * (float)n_in;
    else if (out_size != NN * 2)  code = 3400.f;
    if (code != 0.f) {
        k_sentinel<<<(NN * 2 + 255) / 256, 256, 0, stream>>>(out, code);
        return;
    }

    const int NB = (NN + 255) / 256;
    const int NTILE = (NT + 4095) / 4096;

    k_init<<<NN * 8 / 256, 256, 0, stream>>>(x, W2, a2s, a2d, ei, bufA, va2, vd2,
                                             flag, gcur);
    k_binA<<<NTILE, 256, 0, stream>>>(ei, flag, gcur, staging);
    k_hist<<<NBKT, 256, 0, stream>>>(staging, gcur, deg);
    k_scan1<<<NB, 256, 0, stream>>>(deg, rowptr, part);
    k_scan2<<<1, 512, 0, stream>>>(part, NB);
    k_scan3<<<NB, 256, 0, stream>>>(rowptr, part, deg, dinv);
    k_scat<<<NBKT, 256, 0, stream>>>(staging, gcur, rowptr, col);

    // layer 1: GCN (xp fp32 in bufA; T1 in bufB; O1b bf16 back into bufA)
    k_agg1<<<NN * 4 / 256, 256, 0, stream>>>(bufA, rowptr, col, dinv, bufB);
    k_mm1a<<<NN * 8 / 256, 256, 0, stream>>>(bufB, W1, b1, va2, vd2, (u32*)bufA,
                                             as_, ad_);
    // layer 2: GAT (T2 fp32 in bufB; O2b bf16 into bufA)
    k_agg2<<<NN * 8 / 256, 256, 0, stream>>>((const u32*)bufA, as_, ad_, rowptr, col,
                                             bufB);
    k_mm2<<<NN / 32, 256, 0, stream>>>(bufB, W2, b2, dinv, (u32*)bufA);
    // layer 3: GCN gather over bf16 rows (T3 fp32 into bufB)
    k_agg3<<<NN * 8 / 256, 256, 0, stream>>>((const u32*)bufA, rowptr, col, dinv, bufB);
    // dense 3/4
    k_mm34<<<NN / 32, 256, 0, stream>>>(bufB, W3, b3, W4, a4s, a4d, h4as, as_, ad_);
    // layer 4 agg + log_softmax
    k_final<<<NN * 4 / 256 + 1, 256, 0, stream>>>(h4as, as_, ad_, rowptr, col, b4, out);
}

// Round 16
// 293.277 us; speedup vs baseline: 2.8107x; 1.0505x over previous
//
#include <hip/hip_runtime.h>
#include <hip/hip_bf16.h>

#define NN 100000
#define NE 1600000
#define NT (NN + NE)
#define NBKT 256
#define BSZ 391          // nodes per bucket; 256*391 = 100096 >= NN
#define BCAP 10240       // staging entries per bucket

typedef unsigned int u32;
typedef unsigned short u16;

static __device__ __forceinline__ int clampN(int s) {
    return ((unsigned)s < (unsigned)NN) ? s : 0;
}
static __device__ __forceinline__ int ld_src(const int* ei, int is32, int e) {
    return is32 ? ei[e] : ei[2 * e];
}
static __device__ __forceinline__ int ld_dst(const int* ei, int is32, int e) {
    return is32 ? ei[NE + e] : ei[2 * NE + 2 * e];
}
static __device__ __forceinline__ float2 b2x2(u32 u) {
    float2 r;
    r.x = __uint_as_float((u & 0xffffu) << 16);
    r.y = __uint_as_float(u & 0xffff0000u);
    return r;
}
static __device__ __forceinline__ u16 f2bs(float f) {
    union { __hip_bfloat16 b; u16 u; } cv;
    cv.b = __float2bfloat16(f);
    return cv.u;
}
static __device__ __forceinline__ u32 pack2(float x, float y) {
    return ((u32)f2bs(y) << 16) | (u32)f2bs(x);
}
// leaky-relu then clamp (clamp never active for |e|~O(1); guards exp overflow)
static __device__ __forceinline__ float lrelu_c(float e) {
    e = (e > 0.f) ? e : 0.2f * e;
    return fminf(e, 60.f);
}

#define FMA4(acc, s, v) { acc.x += (s)*(v).x; acc.y += (s)*(v).y; \
                          acc.z += (s)*(v).z; acc.w += (s)*(v).w; }

// ---------------- init ----------------

__global__ void __launch_bounds__(256) k_init(const float* __restrict__ x,
                                              const float* __restrict__ W2,
                                              const float* __restrict__ a2s,
                                              const float* __restrict__ a2d,
                                              const int* __restrict__ ei,
                                              float* __restrict__ xp,
                                              float* __restrict__ va2,
                                              float* __restrict__ vd2,
                                              int* __restrict__ flag,
                                              int* __restrict__ gcur) {
    int idx = blockIdx.x * 256 + threadIdx.x;   // grid covers NN*8
    if (blockIdx.x == 0) {
        if (threadIdx.x == 0) flag[0] = 0;
        __syncthreads();
        int nz = 0;
        for (int i = threadIdx.x; i < 4096; i += 256) nz |= ei[2 * i + 1];
        if (nz) atomicOr(flag, 1);
        if (threadIdx.x < NBKT) gcur[threadIdx.x] = 0;
    }
    if (blockIdx.x == 1 && threadIdx.x < 64) {
        int t = threadIdx.x;
        if (t < 32) {
            float a = 0.f;
            for (int c = 0; c < 64; c++) a += W2[t * 64 + c] * a2s[c];
            va2[t] = a;
        } else {
            int k = t - 32;
            float a = 0.f;
            for (int c = 0; c < 64; c++) a += W2[k * 64 + c] * a2d[c];
            vd2[k] = a;
        }
    }
    if (idx < NN * 8) {
        int n = idx >> 3, c = idx & 7;
        xp[idx] = (c < 7) ? x[n * 7 + c] : 0.f;  // pad 7->8, fp32
    }
}

// ---------------- CSR build (bucketed counting sort) ----------------

__global__ void __launch_bounds__(256) k_binA(const int* __restrict__ ei,
                                              const int* __restrict__ flag,
                                              int* __restrict__ gcur,
                                              u32* __restrict__ staging) {
    __shared__ int hist[NBKT];
    __shared__ int gbase[NBKT];
    __shared__ int cnt2[NBKT];
    int tid = threadIdx.x;
    if (tid < NBKT) hist[tid] = 0;
    __syncthreads();

    int base = blockIdx.x * 4096;
    int is32 = flag[0];
    int d[16], s[16];
    #pragma unroll
    for (int i = 0; i < 16; i++) {
        int e = base + i * 256 + tid;
        d[i] = -1;
        if (e < NE) {
            int dd = ld_dst(ei, is32, e);
            if ((unsigned)dd < (unsigned)NN) { d[i] = dd; s[i] = clampN(ld_src(ei, is32, e)); }
        } else if (e < NT) {
            d[i] = e - NE; s[i] = e - NE;
        }
        if (d[i] >= 0) atomicAdd(&hist[d[i] / BSZ], 1);
    }
    __syncthreads();
    if (tid < NBKT) {
        int c = hist[tid];
        gbase[tid] = c ? atomicAdd(&gcur[tid], c) : 0;
        cnt2[tid] = 0;
    }
    __syncthreads();
    #pragma unroll
    for (int i = 0; i < 16; i++) {
        if (d[i] >= 0) {
            int b = d[i] / BSZ;
            int pos = gbase[b] + atomicAdd(&cnt2[b], 1);
            if (pos < BCAP)
                staging[(size_t)b * BCAP + pos] =
                    ((unsigned)(d[i] - b * BSZ) << 17) | (unsigned)s[i];
        }
    }
}

__global__ void __launch_bounds__(256) k_hist(const u32* __restrict__ staging,
                                              const int* __restrict__ gcur,
                                              int* __restrict__ deg) {
    __shared__ int h[BSZ];
    int b = blockIdx.x;
    for (int l = threadIdx.x; l < BSZ; l += 256) h[l] = 0;
    __syncthreads();
    int cnt = min(gcur[b], BCAP);
    const u32* st = staging + (size_t)b * BCAP;
    for (int i = threadIdx.x; i < cnt; i += 256)
        atomicAdd(&h[st[i] >> 17], 1);
    __syncthreads();
    for (int l = threadIdx.x; l < BSZ; l += 256) {
        int g = b * BSZ + l;
        if (g < NN) deg[g] = h[l];
    }
}

__global__ void k_scan1(const int* __restrict__ deg, int* __restrict__ rowptr,
                        int* __restrict__ part) {
    __shared__ int sm[256];
    int i = blockIdx.x * 256 + threadIdx.x;
    int v = (i < NN) ? deg[i] : 0;
    sm[threadIdx.x] = v;
    __syncthreads();
    for (int off = 1; off < 256; off <<= 1) {
        int t = (threadIdx.x >= off) ? sm[threadIdx.x - off] : 0;
        __syncthreads();
        sm[threadIdx.x] += t;
        __syncthreads();
    }
    if (i < NN) rowptr[i] = sm[threadIdx.x] - v;
    if (threadIdx.x == 255) part[blockIdx.x] = sm[255];
}

__global__ void k_scan2(int* __restrict__ part, int nb) {
    __shared__ int sm[512];
    int t = threadIdx.x;
    int v = (t < nb) ? part[t] : 0;
    sm[t] = v;
    __syncthreads();
    for (int off = 1; off < 512; off <<= 1) {
        int u = (t >= off) ? sm[t - off] : 0;
        __syncthreads();
        sm[t] += u;
        __syncthreads();
    }
    if (t < nb) part[t] = sm[t] - v;
}

__global__ void k_scan3(int* __restrict__ rowptr, const int* __restrict__ part,
                        const int* __restrict__ deg, float* __restrict__ dinv) {
    int i = blockIdx.x * 256 + threadIdx.x;
    if (i < NN) {
        int d = deg[i];
        int r = rowptr[i] + part[blockIdx.x];
        rowptr[i] = r;
        dinv[i] = rsqrtf((float)(d > 0 ? d : 1));
        if (i == NN - 1) rowptr[NN] = r + d;
    }
}

__global__ void __launch_bounds__(256) k_scat(const u32* __restrict__ staging,
                                              const int* __restrict__ gcur,
                                              const int* __restrict__ rowptr,
                                              int* __restrict__ col) {
    __shared__ int cur[BSZ];
    int b = blockIdx.x;
    for (int l = threadIdx.x; l < BSZ; l += 256) {
        int g = b * BSZ + l;
        cur[l] = (g < NN) ? rowptr[g] : 0;
    }
    __syncthreads();
    int cnt = min(gcur[b], BCAP);
    const u32* st = staging + (size_t)b * BCAP;
    for (int i = threadIdx.x; i < cnt; i += 256) {
        u32 w = st[i];
        int l = w >> 17;
        int s = w & 0x1FFFF;
        int p = atomicAdd(&cur[l], 1);
        if ((unsigned)p < (unsigned)NT) col[p] = s;
    }
}

// ---------------- layer 1: GCN agg (fp32 8ch), 4 lanes/node ----------------

__global__ void __launch_bounds__(256) k_agg1(const float* __restrict__ xp,
                                              const int* __restrict__ rowptr,
                                              const int* __restrict__ col,
                                              const float* __restrict__ dinv,
                                              float* __restrict__ T1) {
    int gid = blockIdx.x * 256 + threadIdx.x;  // NN*4 exact
    int n = gid >> 2;
    int lane = gid & 3;                        // channels 2*lane, 2*lane+1
    int beg = rowptr[n], end = rowptr[n + 1];
    float ax = 0.f, ay = 0.f;
    #pragma unroll 4
    for (int e = beg; e < end; e++) {
        int s = clampN(col[e]);
        float w = dinv[s];
        float2 f = *(const float2*)(xp + (size_t)s * 8 + lane * 2);
        ax += w * f.x;
        ay += w * f.y;
    }
    float dn = dinv[n];
    float2 o = {ax * dn, ay * dn};
    *(float2*)(T1 + (size_t)n * 8 + lane * 2) = o;
}

// O1 bf16; LDS-staged W1; 8 threads/node, 4 ch each; alpha via shfl_xor(w=8)
__global__ void __launch_bounds__(256) k_mm1a(const float* __restrict__ T1,
                                              const float* __restrict__ W1,
                                              const float* __restrict__ b1,
                                              const float* __restrict__ va2,
                                              const float* __restrict__ vd2,
                                              u32* __restrict__ O1b,
                                              float* __restrict__ as_,
                                              float* __restrict__ ad_) {
    __shared__ float sW1[7 * 32];
    __shared__ float sb1[32], sva[32], svd[32];
    if (threadIdx.x < 224) sW1[threadIdx.x] = W1[threadIdx.x];
    if (threadIdx.x >= 224) {
        int c = threadIdx.x - 224;
        sb1[c] = b1[c]; sva[c] = va2[c]; svd[c] = vd2[c];
    }
    __syncthreads();
    int gid = blockIdx.x * 256 + threadIdx.x;  // NN*8 exact
    int n = gid >> 3;
    int l = gid & 7;
    int c4 = l * 4;
    const float4* t4 = (const float4*)(T1 + (size_t)n * 8);
    float4 ta = t4[0], tb = t4[1];
    float t[8] = {ta.x, ta.y, ta.z, ta.w, tb.x, tb.y, tb.z, tb.w};
    float4 a = {0, 0, 0, 0};
    #pragma unroll
    for (int k = 0; k < 7; k++) {
        float4 wv = *(const float4*)&sW1[k * 32 + c4];
        FMA4(a, t[k], wv);
    }
    float o0 = fmaxf(a.x + sb1[c4], 0.f);
    float o1 = fmaxf(a.y + sb1[c4 + 1], 0.f);
    float o2 = fmaxf(a.z + sb1[c4 + 2], 0.f);
    float o3 = fmaxf(a.w + sb1[c4 + 3], 0.f);
    uint2 pk = {pack2(o0, o1), pack2(o2, o3)};
    *(uint2*)(O1b + (size_t)n * 16 + l * 2) = pk;
    float vs = o0 * sva[c4] + o1 * sva[c4 + 1] + o2 * sva[c4 + 2] + o3 * sva[c4 + 3];
    float vd = o0 * svd[c4] + o1 * svd[c4 + 1] + o2 * svd[c4 + 2] + o3 * svd[c4 + 3];
    vs += __shfl_xor(vs, 1, 8); vs += __shfl_xor(vs, 2, 8); vs += __shfl_xor(vs, 4, 8);
    vd += __shfl_xor(vd, 1, 8); vd += __shfl_xor(vd, 2, 8); vd += __shfl_xor(vd, 4, 8);
    if (l == 0) { as_[n] = vs; ad_[n] = vd; }
}

// ---------------- layer 2: GAT single-pass softmax agg (no max-shift; exact) ----------------

__global__ void __launch_bounds__(256) k_agg2(const u32* __restrict__ O1b,
                                              const float* __restrict__ as_,
                                              const float* __restrict__ ad_,
                                              const int* __restrict__ rowptr,
                                              const int* __restrict__ col,
                                              float* __restrict__ T2) {
    int gid = blockIdx.x * 256 + threadIdx.x;  // NN*8 exact
    int n = gid >> 3;
    int lane = gid & 7;                        // channels 4*lane .. 4*lane+3
    int beg = rowptr[n], end = rowptr[n + 1];
    float adn = ad_[n];
    float den = 0.f;
    float4 acc = {0, 0, 0, 0};
    #pragma unroll 2
    for (int e = beg; e < end; e++) {
        int s = clampN(col[e]);
        float p = __expf(lrelu_c(as_[s] + adn));
        den += p;
        uint2 w = *(const uint2*)(O1b + (size_t)s * 16 + lane * 2);
        float2 f0 = b2x2(w.x), f1 = b2x2(w.y);
        acc.x += p * f0.x; acc.y += p * f0.y; acc.z += p * f1.x; acc.w += p * f1.y;
    }
    float inv = 1.0f / (den + 1e-16f);
    acc.x *= inv; acc.y *= inv; acc.z *= inv; acc.w *= inv;
    *(float4*)(T2 + (size_t)n * 32 + lane * 4) = acc;
}

// ---------------- dense 32->64: LDS-tiled; O2 bf16 with dinv folded ----------------

__global__ void __launch_bounds__(256) k_mm2(const float* __restrict__ T2,
                                             const float* __restrict__ W2,
                                             const float* __restrict__ b2,
                                             const float* __restrict__ dinv,
                                             u32* __restrict__ O2b) {
    __shared__ float sW2[32 * 64];    // 8 KB
    __shared__ float sT2[32 * 36];    // 4.6 KB, stride 36
    __shared__ float sb2[64];
    {
        const float4* g = (const float4*)W2;
        float4* s4 = (float4*)sW2;
        s4[threadIdx.x] = g[threadIdx.x];
        s4[threadIdx.x + 256] = g[threadIdx.x + 256];
    }
    {
        const float4* g = (const float4*)(T2 + (size_t)blockIdx.x * 32 * 32);
        int node = threadIdx.x >> 3, j = threadIdx.x & 7;
        ((float4*)sT2)[node * 9 + j] = g[threadIdx.x];
    }
    if (threadIdx.x < 64) sb2[threadIdx.x] = b2[threadIdx.x];
    __syncthreads();

    int grp = threadIdx.x >> 4;      // 16 groups
    int l = threadIdx.x & 15;
    int c4 = l * 4;
    int lbase = grp * 2;             // 2 nodes per group

    float4 acc0 = {0,0,0,0}, acc1 = {0,0,0,0};
    #pragma unroll
    for (int k4 = 0; k4 < 8; k4++) {
        float4 t0 = *(const float4*)&sT2[(lbase + 0) * 36 + 4 * k4];
        float4 t1 = *(const float4*)&sT2[(lbase + 1) * 36 + 4 * k4];
        #pragma unroll
        for (int j = 0; j < 4; j++) {
            float4 wv = *(const float4*)&sW2[(4 * k4 + j) * 64 + c4];
            FMA4(acc0, ((const float*)&t0)[j], wv);
            FMA4(acc1, ((const float*)&t1)[j], wv);
        }
    }
    float4 bb = *(const float4*)&sb2[c4];
    int n0 = blockIdx.x * 32 + lbase;
    float d0 = dinv[n0], d1 = dinv[n0 + 1];
    {
        float o0 = fmaxf(acc0.x + bb.x, 0.f) * d0;
        float o1 = fmaxf(acc0.y + bb.y, 0.f) * d0;
        float o2 = fmaxf(acc0.z + bb.z, 0.f) * d0;
        float o3 = fmaxf(acc0.w + bb.w, 0.f) * d0;
        uint2 pk = {pack2(o0, o1), pack2(o2, o3)};
        *(uint2*)(O2b + (size_t)n0 * 32 + l * 2) = pk;
    }
    {
        float o0 = fmaxf(acc1.x + bb.x, 0.f) * d1;
        float o1 = fmaxf(acc1.y + bb.y, 0.f) * d1;
        float o2 = fmaxf(acc1.z + bb.z, 0.f) * d1;
        float o3 = fmaxf(acc1.w + bb.w, 0.f) * d1;
        uint2 pk = {pack2(o0, o1), pack2(o2, o3)};
        *(uint2*)(O2b + (size_t)(n0 + 1) * 32 + l * 2) = pk;
    }
}

// ---------------- layer 3: gather-sum over bf16 rows, 8 lanes/node ----------------

__global__ void __launch_bounds__(256) k_agg3(const u32* __restrict__ O2b,
                                              const int* __restrict__ rowptr,
                                              const int* __restrict__ col,
                                              const float* __restrict__ dinv,
                                              float* __restrict__ T3) {
    int gid = blockIdx.x * 256 + threadIdx.x;  // NN*8 exact
    int n = gid >> 3;
    int lane = gid & 7;                        // channels 8*lane .. +7
    int beg = rowptr[n], end = rowptr[n + 1];
    float4 accA = {0,0,0,0}, accB = {0,0,0,0};
    #pragma unroll 2
    for (int e = beg; e < end; e++) {
        int s = clampN(col[e]);
        uint4 w = *(const uint4*)(O2b + (size_t)s * 32 + lane * 4);
        float2 f0 = b2x2(w.x), f1 = b2x2(w.y), f2 = b2x2(w.z), f3 = b2x2(w.w);
        accA.x += f0.x; accA.y += f0.y; accA.z += f1.x; accA.w += f1.y;
        accB.x += f2.x; accB.y += f2.y; accB.z += f3.x; accB.w += f3.y;
    }
    float dn = dinv[n];
    accA.x *= dn; accA.y *= dn; accA.z *= dn; accA.w *= dn;
    accB.x *= dn; accB.y *= dn; accB.z *= dn; accB.w *= dn;
    float* dst = T3 + (size_t)n * 64 + lane * 8;
    *(float4*)dst = accA;
    *(float4*)(dst + 4) = accB;
}

// ---------------- dense: T3 -> W3 -> relu -> W4; h4as packed float4 ----------------

__global__ void __launch_bounds__(256) k_mm34(const float* __restrict__ T3,
                                              const float* __restrict__ W3,
                                              const float* __restrict__ b3,
                                              const float* __restrict__ W4,
                                              const float* __restrict__ av4s,
                                              const float* __restrict__ av4d,
                                              float4* __restrict__ h4as,
                                              float* __restrict__ as_,
                                              float* __restrict__ ad_) {
    __shared__ float sW3[64 * 128];
    __shared__ float sT3[32 * 64];
    __shared__ float sW4[128 * 2];
    __shared__ float sb3[128];
    {
        const float4* g = (const float4*)W3;
        float4* s4 = (float4*)sW3;
        #pragma unroll
        for (int i = 0; i < 8; i++) s4[threadIdx.x + 256 * i] = g[threadIdx.x + 256 * i];
    }
    {
        const float4* g = (const float4*)(T3 + (size_t)blockIdx.x * 32 * 64);
        float4* s4 = (float4*)sT3;
        s4[threadIdx.x] = g[threadIdx.x];
        s4[threadIdx.x + 256] = g[threadIdx.x + 256];
    }
    if (threadIdx.x < 128) {
        sb3[threadIdx.x] = b3[threadIdx.x];
        sW4[2 * threadIdx.x] = W4[2 * threadIdx.x];
        sW4[2 * threadIdx.x + 1] = W4[2 * threadIdx.x + 1];
    }
    __syncthreads();

    int w = threadIdx.x >> 6;
    int lane = threadIdx.x & 63;
    int half = lane >> 5;
    int lw = lane & 31;
    int lbase = w * 8 + half * 4;
    int c4 = lw * 4;

    float4 acc0 = {0,0,0,0}, acc1 = {0,0,0,0}, acc2 = {0,0,0,0}, acc3 = {0,0,0,0};
    #pragma unroll 4
    for (int k4 = 0; k4 < 16; k4++) {
        float4 t0 = *(const float4*)&sT3[(lbase + 0) * 64 + 4 * k4];
        float4 t1 = *(const float4*)&sT3[(lbase + 1) * 64 + 4 * k4];
        float4 t2 = *(const float4*)&sT3[(lbase + 2) * 64 + 4 * k4];
        float4 t3 = *(const float4*)&sT3[(lbase + 3) * 64 + 4 * k4];
        #pragma unroll
        for (int j = 0; j < 4; j++) {
            float4 wv = *(const float4*)&sW3[(4 * k4 + j) * 128 + c4];
            FMA4(acc0, ((const float*)&t0)[j], wv);
            FMA4(acc1, ((const float*)&t1)[j], wv);
            FMA4(acc2, ((const float*)&t2)[j], wv);
            FMA4(acc3, ((const float*)&t3)[j], wv);
        }
    }

    float4 bb = *(const float4*)&sb3[c4];
    float w40x = sW4[2 * c4],     w41x = sW4[2 * c4 + 1];
    float w40y = sW4[2 * c4 + 2], w41y = sW4[2 * c4 + 3];
    float w40z = sW4[2 * c4 + 4], w41z = sW4[2 * c4 + 5];
    float w40w = sW4[2 * c4 + 6], w41w = sW4[2 * c4 + 7];
    float av4s0 = av4s[0], av4s1 = av4s[1];
    float av4d0 = av4d[0], av4d1 = av4d[1];

    #pragma unroll
    for (int n = 0; n < 4; n++) {
        float4 a = (n == 0) ? acc0 : (n == 1) ? acc1 : (n == 2) ? acc2 : acc3;
        a.x = fmaxf(a.x + bb.x, 0.f);
        a.y = fmaxf(a.y + bb.y, 0.f);
        a.z = fmaxf(a.z + bb.z, 0.f);
        a.w = fmaxf(a.w + bb.w, 0.f);
        float p0 = a.x * w40x + a.y * w40y + a.z * w40z + a.w * w40w;
        float p1 = a.x * w41x + a.y * w41y + a.z * w41z + a.w * w41w;
        #pragma unroll
        for (int off = 16; off > 0; off >>= 1) {
            p0 += __shfl_down(p0, off, 32);
            p1 += __shfl_down(p1, off, 32);
        }
        if (lw == 0) {
            int gn = blockIdx.x * 32 + lbase + n;
            float asv = p0 * av4s0 + p1 * av4s1;
            float4 pk = {p0, p1, asv, 0.f};
            h4as[gn] = pk;
            as_[gn] = asv;
            ad_[gn] = p0 * av4d0 + p1 * av4d1;
        }
    }
}

// ---------------- final GAT (2ch) + log_softmax, single-pass softmax, 4 lanes/node ----------------

__global__ void k_final(const float4* __restrict__ h4as, const float* __restrict__ as_,
                        const float* __restrict__ ad_, const int* __restrict__ rowptr,
                        const int* __restrict__ col, const float* __restrict__ b,
                        float* __restrict__ out) {
    int gid = blockIdx.x * 256 + threadIdx.x;  // NN*4
    int n = gid >> 2;
    if (n >= NN) return;
    int lsub = gid & 3;
    int beg = rowptr[n], end = rowptr[n + 1];
    float adn = ad_[n];
    float den = 0.f, a0 = 0.f, a1 = 0.f;
    for (int e = beg + lsub; e < end; e += 4) {
        int s = clampN(col[e]);
        float4 h = h4as[s];
        float p = __expf(lrelu_c(h.z + adn));
        den += p;
        a0 += p * h.x;
        a1 += p * h.y;
    }
    den += __shfl_xor(den, 1, 4); den += __shfl_xor(den, 2, 4);
    a0  += __shfl_xor(a0, 1, 4);  a0  += __shfl_xor(a0, 2, 4);
    a1  += __shfl_xor(a1, 1, 4);  a1  += __shfl_xor(a1, 2, 4);
    if (lsub == 0) {
        float inv = 1.0f / (den + 1e-16f);
        float v0 = a0 * inv + b[0];
        float v1 = a1 * inv + b[1];
        float mx = fmaxf(v0, v1);
        float lse = mx + logf(__expf(v0 - mx) + __expf(v1 - mx));
        float2 o = {v0 - lse, v1 - lse};
        *(float2*)(out + n * 2) = o;
    }
}

__global__ void k_sentinel(float* __restrict__ out, float v) {
    int i = blockIdx.x * 256 + threadIdx.x;
    if (i < NN * 2) out[i] = v;
}

// ---------------- launch ----------------

extern "C" void kernel_launch(void* const* d_in, const int* in_sizes, int n_in,
                              void* d_out, int out_size, void* d_ws, size_t ws_size,
                              hipStream_t stream) {
    const float* x    = (const float*)d_in[0];
    const int* ei     = (const int*)d_in[1];
    const float* W1   = (const float*)d_in[2];
    const float* b1   = (const float*)d_in[3];
    const float* W2   = (const float*)d_in[4];
    const float* a2s  = (const float*)d_in[5];
    const float* a2d  = (const float*)d_in[6];
    const float* b2   = (const float*)d_in[7];
    const float* W3   = (const float*)d_in[8];
    const float* b3   = (const float*)d_in[9];
    const float* W4   = (const float*)d_in[10];
    const float* a4s  = (const float*)d_in[11];
    const float* a4d  = (const float*)d_in[12];
    const float* b4   = (const float*)d_in[13];
    float* out = (float*)d_out;

    char* base = (char*)d_ws;
    size_t off = 0;
    auto alloc = [&](size_t bytes) {
        char* q = base + off;
        off += (bytes + 255) & ~(size_t)255;
        return q;
    };
    float* bufA  = (float*)alloc((size_t)NN * 64 * 4);   // xp -> O1b -> O2b
    float* bufB  = (float*)alloc((size_t)NN * 64 * 4);   // T1 -> T2 -> T3
    u32* staging = (u32*)alloc((size_t)NBKT * BCAP * 4);
    int* col     = (int*)alloc((size_t)NT * 4);
    int* rowptr  = (int*)alloc((size_t)(NN + 1) * 4);
    int* deg     = (int*)alloc((size_t)NN * 4);
    float* dinv  = (float*)alloc((size_t)NN * 4);
    float* as_   = (float*)alloc((size_t)NN * 4);
    float* ad_   = (float*)alloc((size_t)NN * 4);
    float4* h4as = (float4*)alloc((size_t)NN * 16);
    int* part    = (int*)alloc(512 * 4);
    int* flag    = (int*)alloc(256);
    int* gcur    = (int*)alloc(NBKT * 4);
    float* va2   = (float*)alloc(32 * 4);
    float* vd2   = (float*)alloc(32 * 4);

    float code = 0.f;
    if (off > ws_size)            code = 1000.f + (float)(ws_size >> 20);
    else if (n_in != 14)          code = 2000.f + 10.f * (float)n_in;
    else if (out_size != NN * 2)  code = 3400.f;
    if (code != 0.f) {
        k_sentinel<<<(NN * 2 + 255) / 256, 256, 0, stream>>>(out, code);
        return;
    }

    const int NB = (NN + 255) / 256;
    const int NTILE = (NT + 4095) / 4096;

    k_init<<<NN * 8 / 256, 256, 0, stream>>>(x, W2, a2s, a2d, ei, bufA, va2, vd2,
                                             flag, gcur);
    k_binA<<<NTILE, 256, 0, stream>>>(ei, flag, gcur, staging);
    k_hist<<<NBKT, 256, 0, stream>>>(staging, gcur, deg);
    k_scan1<<<NB, 256, 0, stream>>>(deg, rowptr, part);
    k_scan2<<<1, 512, 0, stream>>>(part, NB);
    k_scan3<<<NB, 256, 0, stream>>>(rowptr, part, deg, dinv);
    k_scat<<<NBKT, 256, 0, stream>>>(staging, gcur, rowptr, col);

    // layer 1: GCN (xp fp32 in bufA; T1 in bufB; O1b bf16 back into bufA)
    k_agg1<<<NN * 4 / 256, 256, 0, stream>>>(bufA, rowptr, col, dinv, bufB);
    k_mm1a<<<NN * 8 / 256, 256, 0, stream>>>(bufB, W1, b1, va2, vd2, (u32*)bufA,
                                             as_, ad_);
    // layer 2: GAT single-pass (T2 fp32 in bufB; O2b bf16 into bufA)
    k_agg2<<<NN * 8 / 256, 256, 0, stream>>>((const u32*)bufA, as_, ad_, rowptr, col,
                                             bufB);
    k_mm2<<<NN / 32, 256, 0, stream>>>(bufB, W2, b2, dinv, (u32*)bufA);
    // layer 3: GCN gather over bf16 rows (T3 fp32 into bufB)
    k_agg3<<<NN * 8 / 256, 256, 0, stream>>>((const u32*)bufA, rowptr, col, dinv, bufB);
    // dense 3/4
    k_mm34<<<NN / 32, 256, 0, stream>>>(bufB, W3, b3, W4, a4s, a4d, h4as, as_, ad_);
    // layer 4 agg + log_softmax (single-pass)
    k_final<<<NN * 4 / 256 + 1, 256, 0, stream>>>(h4as, as_, ad_, rowptr, col, b4, out);
}

// Round 17
// 284.798 us; speedup vs baseline: 2.8944x; 1.0298x over previous
//
#include <hip/hip_runtime.h>
#include <hip/hip_bf16.h>

#define NN 100000
#define NE 1600000
#define NT (NN + NE)
#define NBKT 256
#define BSZ 391          // nodes per bucket; 256*391 = 100096 >= NN
#define BCAP 10240       // staging entries per bucket

typedef unsigned int u32;
typedef unsigned short u16;

static __device__ __forceinline__ int clampN(int s) {
    return ((unsigned)s < (unsigned)NN) ? s : 0;
}
static __device__ __forceinline__ int ld_src(const int* ei, int is32, int e) {
    return is32 ? ei[e] : ei[2 * e];
}
static __device__ __forceinline__ int ld_dst(const int* ei, int is32, int e) {
    return is32 ? ei[NE + e] : ei[2 * NE + 2 * e];
}
static __device__ __forceinline__ float2 b2x2(u32 u) {
    float2 r;
    r.x = __uint_as_float((u & 0xffffu) << 16);
    r.y = __uint_as_float(u & 0xffff0000u);
    return r;
}
static __device__ __forceinline__ u16 f2bs(float f) {
    union { __hip_bfloat16 b; u16 u; } cv;
    cv.b = __float2bfloat16(f);
    return cv.u;
}
static __device__ __forceinline__ u32 pack2(float x, float y) {
    return ((u32)f2bs(y) << 16) | (u32)f2bs(x);
}
// leaky-relu then clamp (clamp never active for |e|~O(1); guards exp overflow)
static __device__ __forceinline__ float lrelu_c(float e) {
    e = (e > 0.f) ? e : 0.2f * e;
    return fminf(e, 60.f);
}

#define FMA4(acc, s, v) { acc.x += (s)*(v).x; acc.y += (s)*(v).y; \
                          acc.z += (s)*(v).z; acc.w += (s)*(v).w; }

// ---------------- init: xp packed bf16 ----------------

__global__ void __launch_bounds__(256) k_init(const float* __restrict__ x,
                                              const float* __restrict__ W2,
                                              const float* __restrict__ a2s,
                                              const float* __restrict__ a2d,
                                              const int* __restrict__ ei,
                                              u32* __restrict__ xpb,
                                              float* __restrict__ va2,
                                              float* __restrict__ vd2,
                                              int* __restrict__ flag,
                                              int* __restrict__ gcur) {
    int idx = blockIdx.x * 256 + threadIdx.x;   // grid covers NN*4
    if (blockIdx.x == 0) {
        if (threadIdx.x == 0) flag[0] = 0;
        __syncthreads();
        int nz = 0;
        for (int i = threadIdx.x; i < 4096; i += 256) nz |= ei[2 * i + 1];
        if (nz) atomicOr(flag, 1);
        if (threadIdx.x < NBKT) gcur[threadIdx.x] = 0;
    }
    if (blockIdx.x == 1 && threadIdx.x < 64) {
        int t = threadIdx.x;
        if (t < 32) {
            float a = 0.f;
            for (int c = 0; c < 64; c++) a += W2[t * 64 + c] * a2s[c];
            va2[t] = a;
        } else {
            int k = t - 32;
            float a = 0.f;
            for (int c = 0; c < 64; c++) a += W2[k * 64 + c] * a2d[c];
            vd2[k] = a;
        }
    }
    if (idx < NN * 4) {
        int n = idx >> 2, c2 = idx & 3;          // word c2 -> channels 2c2, 2c2+1
        float f0 = x[n * 7 + 2 * c2];
        float f1 = (2 * c2 + 1 < 7) ? x[n * 7 + 2 * c2 + 1] : 0.f;
        xpb[idx] = pack2(f0, f1);
    }
}

// ---------------- CSR build (bucketed counting sort) ----------------

__global__ void __launch_bounds__(256) k_binA(const int* __restrict__ ei,
                                              const int* __restrict__ flag,
                                              int* __restrict__ gcur,
                                              u32* __restrict__ staging) {
    __shared__ int hist[NBKT];
    __shared__ int gbase[NBKT];
    __shared__ int cnt2[NBKT];
    int tid = threadIdx.x;
    if (tid < NBKT) hist[tid] = 0;
    __syncthreads();

    int base = blockIdx.x * 4096;
    int is32 = flag[0];
    int d[16], s[16];
    #pragma unroll
    for (int i = 0; i < 16; i++) {
        int e = base + i * 256 + tid;
        d[i] = -1;
        if (e < NE) {
            int dd = ld_dst(ei, is32, e);
            if ((unsigned)dd < (unsigned)NN) { d[i] = dd; s[i] = clampN(ld_src(ei, is32, e)); }
        } else if (e < NT) {
            d[i] = e - NE; s[i] = e - NE;
        }
        if (d[i] >= 0) atomicAdd(&hist[d[i] / BSZ], 1);
    }
    __syncthreads();
    if (tid < NBKT) {
        int c = hist[tid];
        gbase[tid] = c ? atomicAdd(&gcur[tid], c) : 0;
        cnt2[tid] = 0;
    }
    __syncthreads();
    #pragma unroll
    for (int i = 0; i < 16; i++) {
        if (d[i] >= 0) {
            int b = d[i] / BSZ;
            int pos = gbase[b] + atomicAdd(&cnt2[b], 1);
            if (pos < BCAP)
                staging[(size_t)b * BCAP + pos] =
                    ((unsigned)(d[i] - b * BSZ) << 17) | (unsigned)s[i];
        }
    }
}

__global__ void __launch_bounds__(256) k_hist(const u32* __restrict__ staging,
                                              const int* __restrict__ gcur,
                                              int* __restrict__ deg) {
    __shared__ int h[BSZ];
    int b = blockIdx.x;
    for (int l = threadIdx.x; l < BSZ; l += 256) h[l] = 0;
    __syncthreads();
    int cnt = min(gcur[b], BCAP);
    const u32* st = staging + (size_t)b * BCAP;
    for (int i = threadIdx.x; i < cnt; i += 256)
        atomicAdd(&h[st[i] >> 17], 1);
    __syncthreads();
    for (int l = threadIdx.x; l < BSZ; l += 256) {
        int g = b * BSZ + l;
        if (g < NN) deg[g] = h[l];
    }
}

__global__ void k_scan1(const int* __restrict__ deg, int* __restrict__ rowptr,
                        int* __restrict__ part) {
    __shared__ int sm[256];
    int i = blockIdx.x * 256 + threadIdx.x;
    int v = (i < NN) ? deg[i] : 0;
    sm[threadIdx.x] = v;
    __syncthreads();
    for (int off = 1; off < 256; off <<= 1) {
        int t = (threadIdx.x >= off) ? sm[threadIdx.x - off] : 0;
        __syncthreads();
        sm[threadIdx.x] += t;
        __syncthreads();
    }
    if (i < NN) rowptr[i] = sm[threadIdx.x] - v;
    if (threadIdx.x == 255) part[blockIdx.x] = sm[255];
}

__global__ void k_scan2(int* __restrict__ part, int nb) {
    __shared__ int sm[512];
    int t = threadIdx.x;
    int v = (t < nb) ? part[t] : 0;
    sm[t] = v;
    __syncthreads();
    for (int off = 1; off < 512; off <<= 1) {
        int u = (t >= off) ? sm[t - off] : 0;
        __syncthreads();
        sm[t] += u;
        __syncthreads();
    }
    if (t < nb) part[t] = sm[t] - v;
}

__global__ void k_scan3(int* __restrict__ rowptr, const int* __restrict__ part,
                        const int* __restrict__ deg, float* __restrict__ dinv) {
    int i = blockIdx.x * 256 + threadIdx.x;
    if (i < NN) {
        int d = deg[i];
        int r = rowptr[i] + part[blockIdx.x];
        rowptr[i] = r;
        dinv[i] = rsqrtf((float)(d > 0 ? d : 1));
        if (i == NN - 1) rowptr[NN] = r + d;
    }
}

__global__ void __launch_bounds__(256) k_scat(const u32* __restrict__ staging,
                                              const int* __restrict__ gcur,
                                              const int* __restrict__ rowptr,
                                              int* __restrict__ col) {
    __shared__ int cur[BSZ];
    int b = blockIdx.x;
    for (int l = threadIdx.x; l < BSZ; l += 256) {
        int g = b * BSZ + l;
        cur[l] = (g < NN) ? rowptr[g] : 0;
    }
    __syncthreads();
    int cnt = min(gcur[b], BCAP);
    const u32* st = staging + (size_t)b * BCAP;
    for (int i = threadIdx.x; i < cnt; i += 256) {
        u32 w = st[i];
        int l = w >> 17;
        int s = w & 0x1FFFF;
        int p = atomicAdd(&cur[l], 1);
        if ((unsigned)p < (unsigned)NT) col[p] = s;
    }
}

// ---------------- layer 1: GCN agg over bf16 xp (16B rows), 4 lanes/node ----------------

__global__ void __launch_bounds__(256) k_agg1(const u32* __restrict__ xpb,
                                              const int* __restrict__ rowptr,
                                              const int* __restrict__ col,
                                              const float* __restrict__ dinv,
                                              float* __restrict__ T1) {
    int gid = blockIdx.x * 256 + threadIdx.x;  // NN*4 exact
    int n = gid >> 2;
    int lane = gid & 3;                        // channels 2*lane, 2*lane+1
    int beg = rowptr[n], end = rowptr[n + 1];
    float ax = 0.f, ay = 0.f;
    #pragma unroll 4
    for (int e = beg; e < end; e++) {
        int s = clampN(col[e]);
        float w = dinv[s];
        float2 f = b2x2(xpb[(size_t)s * 4 + lane]);
        ax += w * f.x;
        ay += w * f.y;
    }
    float dn = dinv[n];
    float2 o = {ax * dn, ay * dn};
    *(float2*)(T1 + (size_t)n * 8 + lane * 2) = o;
}

// O1 bf16; LDS-staged W1; 8 threads/node, 4 ch each; alpha via shfl_xor(w=8)
__global__ void __launch_bounds__(256) k_mm1a(const float* __restrict__ T1,
                                              const float* __restrict__ W1,
                                              const float* __restrict__ b1,
                                              const float* __restrict__ va2,
                                              const float* __restrict__ vd2,
                                              u32* __restrict__ O1b,
                                              float* __restrict__ as_,
                                              float* __restrict__ ad_) {
    __shared__ float sW1[7 * 32];
    __shared__ float sb1[32], sva[32], svd[32];
    if (threadIdx.x < 224) sW1[threadIdx.x] = W1[threadIdx.x];
    if (threadIdx.x >= 224) {
        int c = threadIdx.x - 224;
        sb1[c] = b1[c]; sva[c] = va2[c]; svd[c] = vd2[c];
    }
    __syncthreads();
    int gid = blockIdx.x * 256 + threadIdx.x;  // NN*8 exact
    int n = gid >> 3;
    int l = gid & 7;
    int c4 = l * 4;
    const float4* t4 = (const float4*)(T1 + (size_t)n * 8);
    float4 ta = t4[0], tb = t4[1];
    float t[8] = {ta.x, ta.y, ta.z, ta.w, tb.x, tb.y, tb.z, tb.w};
    float4 a = {0, 0, 0, 0};
    #pragma unroll
    for (int k = 0; k < 7; k++) {
        float4 wv = *(const float4*)&sW1[k * 32 + c4];
        FMA4(a, t[k], wv);
    }
    float o0 = fmaxf(a.x + sb1[c4], 0.f);
    float o1 = fmaxf(a.y + sb1[c4 + 1], 0.f);
    float o2 = fmaxf(a.z + sb1[c4 + 2], 0.f);
    float o3 = fmaxf(a.w + sb1[c4 + 3], 0.f);
    uint2 pk = {pack2(o0, o1), pack2(o2, o3)};
    *(uint2*)(O1b + (size_t)n * 16 + l * 2) = pk;
    float vs = o0 * sva[c4] + o1 * sva[c4 + 1] + o2 * sva[c4 + 2] + o3 * sva[c4 + 3];
    float vd = o0 * svd[c4] + o1 * svd[c4 + 1] + o2 * svd[c4 + 2] + o3 * svd[c4 + 3];
    vs += __shfl_xor(vs, 1, 8); vs += __shfl_xor(vs, 2, 8); vs += __shfl_xor(vs, 4, 8);
    vd += __shfl_xor(vd, 1, 8); vd += __shfl_xor(vd, 2, 8); vd += __shfl_xor(vd, 4, 8);
    if (l == 0) { as_[n] = vs; ad_[n] = vd; }
}

// ---------------- layer 2: GAT single-pass softmax agg (no max-shift; exact) ----------------

__global__ void __launch_bounds__(256) k_agg2(const u32* __restrict__ O1b,
                                              const float* __restrict__ as_,
                                              const float* __restrict__ ad_,
                                              const int* __restrict__ rowptr,
                                              const int* __restrict__ col,
                                              float* __restrict__ T2) {
    int gid = blockIdx.x * 256 + threadIdx.x;  // NN*8 exact
    int n = gid >> 3;
    int lane = gid & 7;                        // channels 4*lane .. 4*lane+3
    int beg = rowptr[n], end = rowptr[n + 1];
    float adn = ad_[n];
    float den = 0.f;
    float4 acc = {0, 0, 0, 0};
    #pragma unroll 2
    for (int e = beg; e < end; e++) {
        int s = clampN(col[e]);
        float p = __expf(lrelu_c(as_[s] + adn));
        den += p;
        uint2 w = *(const uint2*)(O1b + (size_t)s * 16 + lane * 2);
        float2 f0 = b2x2(w.x), f1 = b2x2(w.y);
        acc.x += p * f0.x; acc.y += p * f0.y; acc.z += p * f1.x; acc.w += p * f1.y;
    }
    float inv = 1.0f / (den + 1e-16f);
    acc.x *= inv; acc.y *= inv; acc.z *= inv; acc.w *= inv;
    *(float4*)(T2 + (size_t)n * 32 + lane * 4) = acc;
}

// ---------------- dense 32->64: LDS-tiled; O2 bf16 with dinv folded ----------------

__global__ void __launch_bounds__(256) k_mm2(const float* __restrict__ T2,
                                             const float* __restrict__ W2,
                                             const float* __restrict__ b2,
                                             const float* __restrict__ dinv,
                                             u32* __restrict__ O2b) {
    __shared__ float sW2[32 * 64];    // 8 KB
    __shared__ float sT2[32 * 36];    // 4.6 KB, stride 36
    __shared__ float sb2[64];
    {
        const float4* g = (const float4*)W2;
        float4* s4 = (float4*)sW2;
        s4[threadIdx.x] = g[threadIdx.x];
        s4[threadIdx.x + 256] = g[threadIdx.x + 256];
    }
    {
        const float4* g = (const float4*)(T2 + (size_t)blockIdx.x * 32 * 32);
        int node = threadIdx.x >> 3, j = threadIdx.x & 7;
        ((float4*)sT2)[node * 9 + j] = g[threadIdx.x];
    }
    if (threadIdx.x < 64) sb2[threadIdx.x] = b2[threadIdx.x];
    __syncthreads();

    int grp = threadIdx.x >> 4;      // 16 groups
    int l = threadIdx.x & 15;
    int c4 = l * 4;
    int lbase = grp * 2;             // 2 nodes per group

    float4 acc0 = {0,0,0,0}, acc1 = {0,0,0,0};
    #pragma unroll
    for (int k4 = 0; k4 < 8; k4++) {
        float4 t0 = *(const float4*)&sT2[(lbase + 0) * 36 + 4 * k4];
        float4 t1 = *(const float4*)&sT2[(lbase + 1) * 36 + 4 * k4];
        #pragma unroll
        for (int j = 0; j < 4; j++) {
            float4 wv = *(const float4*)&sW2[(4 * k4 + j) * 64 + c4];
            FMA4(acc0, ((const float*)&t0)[j], wv);
            FMA4(acc1, ((const float*)&t1)[j], wv);
        }
    }
    float4 bb = *(const float4*)&sb2[c4];
    int n0 = blockIdx.x * 32 + lbase;
    float d0 = dinv[n0], d1 = dinv[n0 + 1];
    {
        float o0 = fmaxf(acc0.x + bb.x, 0.f) * d0;
        float o1 = fmaxf(acc0.y + bb.y, 0.f) * d0;
        float o2 = fmaxf(acc0.z + bb.z, 0.f) * d0;
        float o3 = fmaxf(acc0.w + bb.w, 0.f) * d0;
        uint2 pk = {pack2(o0, o1), pack2(o2, o3)};
        *(uint2*)(O2b + (size_t)n0 * 32 + l * 2) = pk;
    }
    {
        float o0 = fmaxf(acc1.x + bb.x, 0.f) * d1;
        float o1 = fmaxf(acc1.y + bb.y, 0.f) * d1;
        float o2 = fmaxf(acc1.z + bb.z, 0.f) * d1;
        float o3 = fmaxf(acc1.w + bb.w, 0.f) * d1;
        uint2 pk = {pack2(o0, o1), pack2(o2, o3)};
        *(uint2*)(O2b + (size_t)(n0 + 1) * 32 + l * 2) = pk;
    }
}

// ---------------- layer 3: gather-sum over bf16 rows, 8 lanes/node ----------------

__global__ void __launch_bounds__(256) k_agg3(const u32* __restrict__ O2b,
                                              const int* __restrict__ rowptr,
                                              const int* __restrict__ col,
                                              const float* __restrict__ dinv,
                                              float* __restrict__ T3) {
    int gid = blockIdx.x * 256 + threadIdx.x;  // NN*8 exact
    int n = gid >> 3;
    int lane = gid & 7;                        // channels 8*lane .. +7
    int beg = rowptr[n], end = rowptr[n + 1];
    float4 accA = {0,0,0,0}, accB = {0,0,0,0};
    #pragma unroll 4
    for (int e = beg; e < end; e++) {
        int s = clampN(col[e]);
        uint4 w = *(const uint4*)(O2b + (size_t)s * 32 + lane * 4);
        float2 f0 = b2x2(w.x), f1 = b2x2(w.y), f2 = b2x2(w.z), f3 = b2x2(w.w);
        accA.x += f0.x; accA.y += f0.y; accA.z += f1.x; accA.w += f1.y;
        accB.x += f2.x; accB.y += f2.y; accB.z += f3.x; accB.w += f3.y;
    }
    float dn = dinv[n];
    accA.x *= dn; accA.y *= dn; accA.z *= dn; accA.w *= dn;
    accB.x *= dn; accB.y *= dn; accB.z *= dn; accB.w *= dn;
    float* dst = T3 + (size_t)n * 64 + lane * 8;
    *(float4*)dst = accA;
    *(float4*)(dst + 4) = accB;
}

// ---------------- dense: T3 -> W3 -> relu -> W4; h4as packed float4 ----------------

__global__ void __launch_bounds__(256) k_mm34(const float* __restrict__ T3,
                                              const float* __restrict__ W3,
                                              const float* __restrict__ b3,
                                              const float* __restrict__ W4,
                                              const float* __restrict__ av4s,
                                              const float* __restrict__ av4d,
                                              float4* __restrict__ h4as,
                                              float* __restrict__ as_,
                                              float* __restrict__ ad_) {
    __shared__ float sW3[64 * 128];
    __shared__ float sT3[32 * 64];
    __shared__ float sW4[128 * 2];
    __shared__ float sb3[128];
    {
        const float4* g = (const float4*)W3;
        float4* s4 = (float4*)sW3;
        #pragma unroll
        for (int i = 0; i < 8; i++) s4[threadIdx.x + 256 * i] = g[threadIdx.x + 256 * i];
    }
    {
        const float4* g = (const float4*)(T3 + (size_t)blockIdx.x * 32 * 64);
        float4* s4 = (float4*)sT3;
        s4[threadIdx.x] = g[threadIdx.x];
        s4[threadIdx.x + 256] = g[threadIdx.x + 256];
    }
    if (threadIdx.x < 128) {
        sb3[threadIdx.x] = b3[threadIdx.x];
        sW4[2 * threadIdx.x] = W4[2 * threadIdx.x];
        sW4[2 * threadIdx.x + 1] = W4[2 * threadIdx.x + 1];
    }
    __syncthreads();

    int w = threadIdx.x >> 6;
    int lane = threadIdx.x & 63;
    int half = lane >> 5;
    int lw = lane & 31;
    int lbase = w * 8 + half * 4;
    int c4 = lw * 4;

    float4 acc0 = {0,0,0,0}, acc1 = {0,0,0,0}, acc2 = {0,0,0,0}, acc3 = {0,0,0,0};
    #pragma unroll 4
    for (int k4 = 0; k4 < 16; k4++) {
        float4 t0 = *(const float4*)&sT3[(lbase + 0) * 64 + 4 * k4];
        float4 t1 = *(const float4*)&sT3[(lbase + 1) * 64 + 4 * k4];
        float4 t2 = *(const float4*)&sT3[(lbase + 2) * 64 + 4 * k4];
        float4 t3 = *(const float4*)&sT3[(lbase + 3) * 64 + 4 * k4];
        #pragma unroll
        for (int j = 0; j < 4; j++) {
            float4 wv = *(const float4*)&sW3[(4 * k4 + j) * 128 + c4];
            FMA4(acc0, ((const float*)&t0)[j], wv);
            FMA4(acc1, ((const float*)&t1)[j], wv);
            FMA4(acc2, ((const float*)&t2)[j], wv);
            FMA4(acc3, ((const float*)&t3)[j], wv);
        }
    }

    float4 bb = *(const float4*)&sb3[c4];
    float w40x = sW4[2 * c4],     w41x = sW4[2 * c4 + 1];
    float w40y = sW4[2 * c4 + 2], w41y = sW4[2 * c4 + 3];
    float w40z = sW4[2 * c4 + 4], w41z = sW4[2 * c4 + 5];
    float w40w = sW4[2 * c4 + 6], w41w = sW4[2 * c4 + 7];
    float av4s0 = av4s[0], av4s1 = av4s[1];
    float av4d0 = av4d[0], av4d1 = av4d[1];

    #pragma unroll
    for (int n = 0; n < 4; n++) {
        float4 a = (n == 0) ? acc0 : (n == 1) ? acc1 : (n == 2) ? acc2 : acc3;
        a.x = fmaxf(a.x + bb.x, 0.f);
        a.y = fmaxf(a.y + bb.y, 0.f);
        a.z = fmaxf(a.z + bb.z, 0.f);
        a.w = fmaxf(a.w + bb.w, 0.f);
        float p0 = a.x * w40x + a.y * w40y + a.z * w40z + a.w * w40w;
        float p1 = a.x * w41x + a.y * w41y + a.z * w41z + a.w * w41w;
        #pragma unroll
        for (int off = 16; off > 0; off >>= 1) {
            p0 += __shfl_down(p0, off, 32);
            p1 += __shfl_down(p1, off, 32);
        }
        if (lw == 0) {
            int gn = blockIdx.x * 32 + lbase + n;
            float asv = p0 * av4s0 + p1 * av4s1;
            float4 pk = {p0, p1, asv, 0.f};
            h4as[gn] = pk;
            as_[gn] = asv;
            ad_[gn] = p0 * av4d0 + p1 * av4d1;
        }
    }
}

// ---------------- final GAT (2ch) + log_softmax, single-pass softmax, 4 lanes/node ----------------

__global__ void k_final(const float4* __restrict__ h4as, const float* __restrict__ as_,
                        const float* __restrict__ ad_, const int* __restrict__ rowptr,
                        const int* __restrict__ col, const float* __restrict__ b,
                        float* __restrict__ out) {
    int gid = blockIdx.x * 256 + threadIdx.x;  // NN*4
    int n = gid >> 2;
    if (n >= NN) return;
    int lsub = gid & 3;
    int beg = rowptr[n], end = rowptr[n + 1];
    float adn = ad_[n];
    float den = 0.f, a0 = 0.f, a1 = 0.f;
    for (int e = beg + lsub; e < end; e += 4) {
        int s = clampN(col[e]);
        float4 h = h4as[s];
        float p = __expf(lrelu_c(h.z + adn));
        den += p;
        a0 += p * h.x;
        a1 += p * h.y;
    }
    den += __shfl_xor(den, 1, 4); den += __shfl_xor(den, 2, 4);
    a0  += __shfl_xor(a0, 1, 4);  a0  += __shfl_xor(a0, 2, 4);
    a1  += __shfl_xor(a1, 1, 4);  a1  += __shfl_xor(a1, 2, 4);
    if (lsub == 0) {
        float inv = 1.0f / (den + 1e-16f);
        float v0 = a0 * inv + b[0];
        float v1 = a1 * inv + b[1];
        float mx = fmaxf(v0, v1);
        float lse = mx + logf(__expf(v0 - mx) + __expf(v1 - mx));
        float2 o = {v0 - lse, v1 - lse};
        *(float2*)(out + n * 2) = o;
    }
}

__global__ void k_sentinel(float* __restrict__ out, float v) {
    int i = blockIdx.x * 256 + threadIdx.x;
    if (i < NN * 2) out[i] = v;
}

// ---------------- launch ----------------

extern "C" void kernel_launch(void* const* d_in, const int* in_sizes, int n_in,
                              void* d_out, int out_size, void* d_ws, size_t ws_size,
                              hipStream_t stream) {
    const float* x    = (const float*)d_in[0];
    const int* ei     = (const int*)d_in[1];
    const float* W1   = (const float*)d_in[2];
    const float* b1   = (const float*)d_in[3];
    const float* W2   = (const float*)d_in[4];
    const float* a2s  = (const float*)d_in[5];
    const float* a2d  = (const float*)d_in[6];
    const float* b2   = (const float*)d_in[7];
    const float* W3   = (const float*)d_in[8];
    const float* b3   = (const float*)d_in[9];
    const float* W4   = (const float*)d_in[10];
    const float* a4s  = (const float*)d_in[11];
    const float* a4d  = (const float*)d_in[12];
    const float* b4   = (const float*)d_in[13];
    float* out = (float*)d_out;

    char* base = (char*)d_ws;
    size_t off = 0;
    auto alloc = [&](size_t bytes) {
        char* q = base + off;
        off += (bytes + 255) & ~(size_t)255;
        return q;
    };
    float* bufA  = (float*)alloc((size_t)NN * 64 * 4);   // xpb -> O1b -> O2b
    float* bufB  = (float*)alloc((size_t)NN * 64 * 4);   // T1 -> T2 -> T3
    u32* staging = (u32*)alloc((size_t)NBKT * BCAP * 4);
    int* col     = (int*)alloc((size_t)NT * 4);
    int* rowptr  = (int*)alloc((size_t)(NN + 1) * 4);
    int* deg     = (int*)alloc((size_t)NN * 4);
    float* dinv  = (float*)alloc((size_t)NN * 4);
    float* as_   = (float*)alloc((size_t)NN * 4);
    float* ad_   = (float*)alloc((size_t)NN * 4);
    float4* h4as = (float4*)alloc((size_t)NN * 16);
    int* part    = (int*)alloc(512 * 4);
    int* flag    = (int*)alloc(256);
    int* gcur    = (int*)alloc(NBKT * 4);
    float* va2   = (float*)alloc(32 * 4);
    float* vd2   = (float*)alloc(32 * 4);

    float code = 0.f;
    if (off > ws_size)            code = 1000.f + (float)(ws_size >> 20);
    else if (n_in != 14)          code = 2000.f + 10.f * (float)n_in;
    else if (out_size != NN * 2)  code = 3400.f;
    if (code != 0.f) {
        k_sentinel<<<(NN * 2 + 255) / 256, 256, 0, stream>>>(out, code);
        return;
    }

    const int NB = (NN + 255) / 256;
    const int NTILE = (NT + 4095) / 4096;

    k_init<<<NN * 4 / 256, 256, 0, stream>>>(x, W2, a2s, a2d, ei, (u32*)bufA, va2, vd2,
                                             flag, gcur);
    k_binA<<<NTILE, 256, 0, stream>>>(ei, flag, gcur, staging);
    k_hist<<<NBKT, 256, 0, stream>>>(staging, gcur, deg);
    k_scan1<<<NB, 256, 0, stream>>>(deg, rowptr, part);
    k_scan2<<<1, 512, 0, stream>>>(part, NB);
    k_scan3<<<NB, 256, 0, stream>>>(rowptr, part, deg, dinv);
    k_scat<<<NBKT, 256, 0, stream>>>(staging, gcur, rowptr, col);

    // layer 1: GCN over bf16 xp (xpb in bufA; T1 in bufB; O1b bf16 back into bufA)
    k_agg1<<<NN * 4 / 256, 256, 0, stream>>>((const u32*)bufA, rowptr, col, dinv, bufB);
    k_mm1a<<<NN * 8 / 256, 256, 0, stream>>>(bufB, W1, b1, va2, vd2, (u32*)bufA,
                                             as_, ad_);
    // layer 2: GAT single-pass (T2 fp32 in bufB; O2b bf16 into bufA)
    k_agg2<<<NN * 8 / 256, 256, 0, stream>>>((const u32*)bufA, as_, ad_, rowptr, col,
                                             bufB);
    k_mm2<<<NN / 32, 256, 0, stream>>>(bufB, W2, b2, dinv, (u32*)bufA);
    // layer 3: GCN gather over bf16 rows (T3 fp32 into bufB)
    k_agg3<<<NN * 8 / 256, 256, 0, stream>>>((const u32*)bufA, rowptr, col, dinv, bufB);
    // dense 3/4
    k_mm34<<<NN / 32, 256, 0, stream>>>(bufB, W3, b3, W4, a4s, a4d, h4as, as_, ad_);
    // layer 4 agg + log_softmax (single-pass)
    k_final<<<NN * 4 / 256 + 1, 256, 0, stream>>>(h4as, as_, ad_, rowptr, col, b4, out);
}

// Round 18
// 270.122 us; speedup vs baseline: 3.0516x; 1.0543x over previous
//
#include <hip/hip_runtime.h>
#include <hip/hip_bf16.h>

#define NN 100000
#define NE 1600000
#define NT (NN + NE)
#define NBKT 256
#define BSZ 391          // nodes per bucket; 256*391 = 100096 >= NN
#define BCAP 10240       // staging entries per bucket

typedef unsigned int u32;
typedef unsigned short u16;

static __device__ __forceinline__ int clampN(int s) {
    return ((unsigned)s < (unsigned)NN) ? s : 0;
}
static __device__ __forceinline__ int ld_src(const int* ei, int is32, int e) {
    return is32 ? ei[e] : ei[2 * e];
}
static __device__ __forceinline__ int ld_dst(const int* ei, int is32, int e) {
    return is32 ? ei[NE + e] : ei[2 * NE + 2 * e];
}
static __device__ __forceinline__ float2 b2x2(u32 u) {
    float2 r;
    r.x = __uint_as_float((u & 0xffffu) << 16);
    r.y = __uint_as_float(u & 0xffff0000u);
    return r;
}
static __device__ __forceinline__ u16 f2bs(float f) {
    union { __hip_bfloat16 b; u16 u; } cv;
    cv.b = __float2bfloat16(f);
    return cv.u;
}
static __device__ __forceinline__ u32 pack2(float x, float y) {
    return ((u32)f2bs(y) << 16) | (u32)f2bs(x);
}
// leaky-relu then clamp (clamp never active for |e|~O(1); guards exp overflow)
static __device__ __forceinline__ float lrelu_c(float e) {
    e = (e > 0.f) ? e : 0.2f * e;
    return fminf(e, 60.f);
}

#define FMA4(acc, s, v) { acc.x += (s)*(v).x; acc.y += (s)*(v).y; \
                          acc.z += (s)*(v).z; acc.w += (s)*(v).w; }

// ---------------- init: flag/gcur zero, edge-dtype detect, xp bf16, alpha2 vecs ----------------

__global__ void __launch_bounds__(256) k_init(const float* __restrict__ x,
                                              const float* __restrict__ W2,
                                              const float* __restrict__ a2s,
                                              const float* __restrict__ a2d,
                                              const int* __restrict__ ei,
                                              u32* __restrict__ xpb,
                                              float* __restrict__ va2,
                                              float* __restrict__ vd2,
                                              int* __restrict__ flag,
                                              int* __restrict__ gcur) {
    int idx = blockIdx.x * 256 + threadIdx.x;   // grid covers NN*4
    if (blockIdx.x == 0) {
        if (threadIdx.x == 0) flag[0] = 0;
        __syncthreads();
        int nz = 0;
        for (int i = threadIdx.x; i < 4096; i += 256) nz |= ei[2 * i + 1];
        if (nz) atomicOr(flag, 1);
        if (threadIdx.x < NBKT) gcur[threadIdx.x] = 0;
    }
    if (blockIdx.x == 1 && threadIdx.x < 64) {
        int t = threadIdx.x;
        if (t < 32) {
            float a = 0.f;
            for (int c = 0; c < 64; c++) a += W2[t * 64 + c] * a2s[c];
            va2[t] = a;
        } else {
            int k = t - 32;
            float a = 0.f;
            for (int c = 0; c < 64; c++) a += W2[k * 64 + c] * a2d[c];
            vd2[k] = a;
        }
    }
    if (idx < NN * 4) {
        int n = idx >> 2, c2 = idx & 3;          // word c2 -> channels 2c2, 2c2+1
        float f0 = x[n * 7 + 2 * c2];
        float f1 = (2 * c2 + 1 < 7) ? x[n * 7 + 2 * c2 + 1] : 0.f;
        xpb[idx] = pack2(f0, f1);
    }
}

// ---------------- CSR build (bucketed counting sort) ----------------

__global__ void __launch_bounds__(256) k_binA(const int* __restrict__ ei,
                                              const int* __restrict__ flag,
                                              int* __restrict__ gcur,
                                              u32* __restrict__ staging) {
    __shared__ int hist[NBKT];
    __shared__ int gbase[NBKT];
    __shared__ int cnt2[NBKT];
    int tid = threadIdx.x;
    if (tid < NBKT) hist[tid] = 0;
    __syncthreads();

    int base = blockIdx.x * 4096;
    int is32 = flag[0];
    int d[16], s[16];
    #pragma unroll
    for (int i = 0; i < 16; i++) {
        int e = base + i * 256 + tid;
        d[i] = -1;
        if (e < NE) {
            int dd = ld_dst(ei, is32, e);
            if ((unsigned)dd < (unsigned)NN) { d[i] = dd; s[i] = clampN(ld_src(ei, is32, e)); }
        } else if (e < NT) {
            d[i] = e - NE; s[i] = e - NE;
        }
        if (d[i] >= 0) atomicAdd(&hist[d[i] / BSZ], 1);
    }
    __syncthreads();
    if (tid < NBKT) {
        int c = hist[tid];
        gbase[tid] = c ? atomicAdd(&gcur[tid], c) : 0;
        cnt2[tid] = 0;
    }
    __syncthreads();
    #pragma unroll
    for (int i = 0; i < 16; i++) {
        if (d[i] >= 0) {
            int b = d[i] / BSZ;
            int pos = gbase[b] + atomicAdd(&cnt2[b], 1);
            if (pos < BCAP)
                staging[(size_t)b * BCAP + pos] =
                    ((unsigned)(d[i] - b * BSZ) << 17) | (unsigned)s[i];
        }
    }
}

// per-bucket degree histogram + bucket-local exclusive scan (fused hist+scan1)
__global__ void __launch_bounds__(256) k_histscan(const u32* __restrict__ staging,
                                                  const int* __restrict__ gcur,
                                                  int* __restrict__ rowptr,
                                                  int* __restrict__ deg,
                                                  int* __restrict__ part) {
    __shared__ int h[512];
    __shared__ int sm[256];
    int b = blockIdx.x, tid = threadIdx.x;
    h[tid] = 0; h[tid + 256] = 0;
    __syncthreads();
    int cnt = min(gcur[b], BCAP);
    const u32* st = staging + (size_t)b * BCAP;
    for (int i = tid; i < cnt; i += 256)
        atomicAdd(&h[st[i] >> 17], 1);
    __syncthreads();
    int h0 = h[2 * tid], h1 = h[2 * tid + 1];
    int pair = h0 + h1;
    sm[tid] = pair;
    __syncthreads();
    for (int off = 1; off < 256; off <<= 1) {
        int t = (tid >= off) ? sm[tid - off] : 0;
        __syncthreads();
        sm[tid] += t;
        __syncthreads();
    }
    int excl = sm[tid] - pair;                   // exclusive over pairs
    int g0 = b * BSZ + 2 * tid;
    if (2 * tid < BSZ && g0 < NN) { rowptr[g0] = excl; deg[g0] = h0; }
    int g1 = g0 + 1;
    if (2 * tid + 1 < BSZ && g1 < NN) { rowptr[g1] = excl + h0; deg[g1] = h1; }
    if (tid == 255) part[b] = sm[255];
}

// scan over 256 bucket totals (exclusive); also finalize rowptr[NN]
__global__ void k_scan2(int* __restrict__ part, int* __restrict__ rowptr) {
    __shared__ int sm[256];
    int t = threadIdx.x;
    int v = part[t];
    sm[t] = v;
    __syncthreads();
    for (int off = 1; off < 256; off <<= 1) {
        int u = (t >= off) ? sm[t - off] : 0;
        __syncthreads();
        sm[t] += u;
        __syncthreads();
    }
    part[t] = sm[t] - v;                         // exclusive
    if (t == 0) rowptr[NN] = NT;
}

// finalize rowptr/dinv (absorbs scan3) + scatter into col (L2-local windows)
__global__ void __launch_bounds__(256) k_scat(const u32* __restrict__ staging,
                                              const int* __restrict__ gcur,
                                              const int* __restrict__ part,
                                              int* __restrict__ rowptr,
                                              const int* __restrict__ deg,
                                              float* __restrict__ dinv,
                                              int* __restrict__ col) {
    __shared__ int cur[BSZ];
    int b = blockIdx.x;
    int pb = part[b];
    for (int l = threadIdx.x; l < BSZ; l += 256) {
        int g = b * BSZ + l;
        if (g < NN) {
            int r = rowptr[g] + pb;
            rowptr[g] = r;
            cur[l] = r;
            int d = deg[g];
            dinv[g] = rsqrtf((float)(d > 0 ? d : 1));
        } else cur[l] = 0;
    }
    __syncthreads();
    int cnt = min(gcur[b], BCAP);
    const u32* st = staging + (size_t)b * BCAP;
    for (int i = threadIdx.x; i < cnt; i += 256) {
        u32 w = st[i];
        int l = w >> 17;
        int s = w & 0x1FFFF;
        int p = atomicAdd(&cur[l], 1);
        if ((unsigned)p < (unsigned)NT) col[p] = s;
    }
}

// ---------------- layer 1 fused: GCN agg (bf16 xp) -> LDS -> dense 7->32 + alpha2 ----------------
// 64 nodes/block; gather 4 lanes/node; dense 4 lanes/node x 8 ch.

__global__ void __launch_bounds__(256) k_l1(const u32* __restrict__ xpb,
                                            const int* __restrict__ rowptr,
                                            const int* __restrict__ col,
                                            const float* __restrict__ dinv,
                                            const float* __restrict__ W1,
                                            const float* __restrict__ b1,
                                            const float* __restrict__ va2,
                                            const float* __restrict__ vd2,
                                            u32* __restrict__ O1b,
                                            float* __restrict__ as_,
                                            float* __restrict__ ad_) {
    __shared__ float sW1[7 * 32];
    __shared__ float sb1[32], sva[32], svd[32];
    __shared__ float sT1[64 * 8];
    if (threadIdx.x < 224) sW1[threadIdx.x] = W1[threadIdx.x];
    else {
        int c = threadIdx.x - 224;
        sb1[c] = b1[c]; sva[c] = va2[c]; svd[c] = vd2[c];
    }
    int node_l = threadIdx.x >> 2;
    int lane = threadIdx.x & 3;
    int n = blockIdx.x * 64 + node_l;
    if (n < NN) {
        int beg = rowptr[n], end = rowptr[n + 1];
        float ax = 0.f, ay = 0.f;
        #pragma unroll 4
        for (int e = beg; e < end; e++) {
            int s = clampN(col[e]);
            float w = dinv[s];
            float2 f = b2x2(xpb[(size_t)s * 4 + lane]);
            ax += w * f.x;
            ay += w * f.y;
        }
        float dn = dinv[n];
        sT1[node_l * 8 + lane * 2] = ax * dn;
        sT1[node_l * 8 + lane * 2 + 1] = ay * dn;
    }
    __syncthreads();
    if (n >= NN) return;
    int c8 = lane * 8;
    float4 aA = {0,0,0,0}, aB = {0,0,0,0};
    #pragma unroll
    for (int k = 0; k < 7; k++) {
        float t = sT1[node_l * 8 + k];
        float4 wva = *(const float4*)&sW1[k * 32 + c8];
        float4 wvb = *(const float4*)&sW1[k * 32 + c8 + 4];
        FMA4(aA, t, wva);
        FMA4(aB, t, wvb);
    }
    float o0 = fmaxf(aA.x + sb1[c8], 0.f);
    float o1 = fmaxf(aA.y + sb1[c8 + 1], 0.f);
    float o2 = fmaxf(aA.z + sb1[c8 + 2], 0.f);
    float o3 = fmaxf(aA.w + sb1[c8 + 3], 0.f);
    float o4 = fmaxf(aB.x + sb1[c8 + 4], 0.f);
    float o5 = fmaxf(aB.y + sb1[c8 + 5], 0.f);
    float o6 = fmaxf(aB.z + sb1[c8 + 6], 0.f);
    float o7 = fmaxf(aB.w + sb1[c8 + 7], 0.f);
    uint4 pk = {pack2(o0, o1), pack2(o2, o3), pack2(o4, o5), pack2(o6, o7)};
    *(uint4*)(O1b + (size_t)n * 16 + lane * 4) = pk;
    float vs = o0 * sva[c8] + o1 * sva[c8 + 1] + o2 * sva[c8 + 2] + o3 * sva[c8 + 3]
             + o4 * sva[c8 + 4] + o5 * sva[c8 + 5] + o6 * sva[c8 + 6] + o7 * sva[c8 + 7];
    float vd = o0 * svd[c8] + o1 * svd[c8 + 1] + o2 * svd[c8 + 2] + o3 * svd[c8 + 3]
             + o4 * svd[c8 + 4] + o5 * svd[c8 + 5] + o6 * svd[c8 + 6] + o7 * svd[c8 + 7];
    vs += __shfl_xor(vs, 1, 4); vs += __shfl_xor(vs, 2, 4);
    vd += __shfl_xor(vd, 1, 4); vd += __shfl_xor(vd, 2, 4);
    if (lane == 0) { as_[n] = vs; ad_[n] = vd; }
}

// ---------------- layer 2 fused: GAT single-pass agg -> LDS -> dense 32->64 ----------------
// 32 nodes/block; gather 8 lanes/node; dense 16 groups x (2 nodes, 4 ch/lane).

__global__ void __launch_bounds__(256) k_l2(const u32* __restrict__ O1b,
                                            const float* __restrict__ as_,
                                            const float* __restrict__ ad_,
                                            const int* __restrict__ rowptr,
                                            const int* __restrict__ col,
                                            const float* __restrict__ W2,
                                            const float* __restrict__ b2,
                                            const float* __restrict__ dinv,
                                            u32* __restrict__ O2b) {
    __shared__ float sW2[32 * 64];    // 8 KB
    __shared__ float sT2[32 * 36];    // stride 36
    __shared__ float sb2[64];
    {
        const float4* g = (const float4*)W2;
        float4* s4 = (float4*)sW2;
        s4[threadIdx.x] = g[threadIdx.x];
        s4[threadIdx.x + 256] = g[threadIdx.x + 256];
    }
    if (threadIdx.x < 64) sb2[threadIdx.x] = b2[threadIdx.x];

    int node_l = threadIdx.x >> 3;
    int lane = threadIdx.x & 7;                  // channels 4*lane .. +3
    int n = blockIdx.x * 32 + node_l;            // 3125*32 = NN exact
    {
        int beg = rowptr[n], end = rowptr[n + 1];
        float adn = ad_[n];
        float den = 0.f;
        float4 acc = {0, 0, 0, 0};
        #pragma unroll 2
        for (int e = beg; e < end; e++) {
            int s = clampN(col[e]);
            float p = __expf(lrelu_c(as_[s] + adn));
            den += p;
            uint2 w = *(const uint2*)(O1b + (size_t)s * 16 + lane * 2);
            float2 f0 = b2x2(w.x), f1 = b2x2(w.y);
            acc.x += p * f0.x; acc.y += p * f0.y; acc.z += p * f1.x; acc.w += p * f1.y;
        }
        float inv = 1.0f / (den + 1e-16f);
        acc.x *= inv; acc.y *= inv; acc.z *= inv; acc.w *= inv;
        *(float4*)&sT2[node_l * 36 + lane * 4] = acc;
    }
    __syncthreads();

    int grp = threadIdx.x >> 4;      // 16 groups
    int l = threadIdx.x & 15;
    int c4 = l * 4;
    int lbase = grp * 2;             // 2 nodes per group

    float4 acc0 = {0,0,0,0}, acc1 = {0,0,0,0};
    #pragma unroll
    for (int k4 = 0; k4 < 8; k4++) {
        float4 t0 = *(const float4*)&sT2[(lbase + 0) * 36 + 4 * k4];
        float4 t1 = *(const float4*)&sT2[(lbase + 1) * 36 + 4 * k4];
        #pragma unroll
        for (int j = 0; j < 4; j++) {
            float4 wv = *(const float4*)&sW2[(4 * k4 + j) * 64 + c4];
            FMA4(acc0, ((const float*)&t0)[j], wv);
            FMA4(acc1, ((const float*)&t1)[j], wv);
        }
    }
    float4 bb = *(const float4*)&sb2[c4];
    int n0 = blockIdx.x * 32 + lbase;
    float d0 = dinv[n0], d1 = dinv[n0 + 1];
    {
        float o0 = fmaxf(acc0.x + bb.x, 0.f) * d0;
        float o1 = fmaxf(acc0.y + bb.y, 0.f) * d0;
        float o2 = fmaxf(acc0.z + bb.z, 0.f) * d0;
        float o3 = fmaxf(acc0.w + bb.w, 0.f) * d0;
        uint2 pk = {pack2(o0, o1), pack2(o2, o3)};
        *(uint2*)(O2b + (size_t)n0 * 32 + l * 2) = pk;
    }
    {
        float o0 = fmaxf(acc1.x + bb.x, 0.f) * d1;
        float o1 = fmaxf(acc1.y + bb.y, 0.f) * d1;
        float o2 = fmaxf(acc1.z + bb.z, 0.f) * d1;
        float o3 = fmaxf(acc1.w + bb.w, 0.f) * d1;
        uint2 pk = {pack2(o0, o1), pack2(o2, o3)};
        *(uint2*)(O2b + (size_t)(n0 + 1) * 32 + l * 2) = pk;
    }
}

// ---------------- layer 3: gather-sum over bf16 rows, 8 lanes/node ----------------

__global__ void __launch_bounds__(256) k_agg3(const u32* __restrict__ O2b,
                                              const int* __restrict__ rowptr,
                                              const int* __restrict__ col,
                                              const float* __restrict__ dinv,
                                              float* __restrict__ T3) {
    int gid = blockIdx.x * 256 + threadIdx.x;  // NN*8 exact
    int n = gid >> 3;
    int lane = gid & 7;                        // channels 8*lane .. +7
    int beg = rowptr[n], end = rowptr[n + 1];
    float4 accA = {0,0,0,0}, accB = {0,0,0,0};
    #pragma unroll 4
    for (int e = beg; e < end; e++) {
        int s = clampN(col[e]);
        uint4 w = *(const uint4*)(O2b + (size_t)s * 32 + lane * 4);
        float2 f0 = b2x2(w.x), f1 = b2x2(w.y), f2 = b2x2(w.z), f3 = b2x2(w.w);
        accA.x += f0.x; accA.y += f0.y; accA.z += f1.x; accA.w += f1.y;
        accB.x += f2.x; accB.y += f2.y; accB.z += f3.x; accB.w += f3.y;
    }
    float dn = dinv[n];
    accA.x *= dn; accA.y *= dn; accA.z *= dn; accA.w *= dn;
    accB.x *= dn; accB.y *= dn; accB.z *= dn; accB.w *= dn;
    float* dst = T3 + (size_t)n * 64 + lane * 8;
    *(float4*)dst = accA;
    *(float4*)(dst + 4) = accB;
}

// ---------------- dense: T3 -> W3 -> relu -> W4; h4as packed float4 ----------------

__global__ void __launch_bounds__(256) k_mm34(const float* __restrict__ T3,
                                              const float* __restrict__ W3,
                                              const float* __restrict__ b3,
                                              const float* __restrict__ W4,
                                              const float* __restrict__ av4s,
                                              const float* __restrict__ av4d,
                                              float4* __restrict__ h4as,
                                              float* __restrict__ as_,
                                              float* __restrict__ ad_) {
    __shared__ float sW3[64 * 128];
    __shared__ float sT3[32 * 64];
    __shared__ float sW4[128 * 2];
    __shared__ float sb3[128];
    {
        const float4* g = (const float4*)W3;
        float4* s4 = (float4*)sW3;
        #pragma unroll
        for (int i = 0; i < 8; i++) s4[threadIdx.x + 256 * i] = g[threadIdx.x + 256 * i];
    }
    {
        const float4* g = (const float4*)(T3 + (size_t)blockIdx.x * 32 * 64);
        float4* s4 = (float4*)sT3;
        s4[threadIdx.x] = g[threadIdx.x];
        s4[threadIdx.x + 256] = g[threadIdx.x + 256];
    }
    if (threadIdx.x < 128) {
        sb3[threadIdx.x] = b3[threadIdx.x];
        sW4[2 * threadIdx.x] = W4[2 * threadIdx.x];
        sW4[2 * threadIdx.x + 1] = W4[2 * threadIdx.x + 1];
    }
    __syncthreads();

    int w = threadIdx.x >> 6;
    int lane = threadIdx.x & 63;
    int half = lane >> 5;
    int lw = lane & 31;
    int lbase = w * 8 + half * 4;
    int c4 = lw * 4;

    float4 acc0 = {0,0,0,0}, acc1 = {0,0,0,0}, acc2 = {0,0,0,0}, acc3 = {0,0,0,0};
    #pragma unroll 4
    for (int k4 = 0; k4 < 16; k4++) {
        float4 t0 = *(const float4*)&sT3[(lbase + 0) * 64 + 4 * k4];
        float4 t1 = *(const float4*)&sT3[(lbase + 1) * 64 + 4 * k4];
        float4 t2 = *(const float4*)&sT3[(lbase + 2) * 64 + 4 * k4];
        float4 t3 = *(const float4*)&sT3[(lbase + 3) * 64 + 4 * k4];
        #pragma unroll
        for (int j = 0; j < 4; j++) {
            float4 wv = *(const float4*)&sW3[(4 * k4 + j) * 128 + c4];
            FMA4(acc0, ((const float*)&t0)[j], wv);
            FMA4(acc1, ((const float*)&t1)[j], wv);
            FMA4(acc2, ((const float*)&t2)[j], wv);
            FMA4(acc3, ((const float*)&t3)[j], wv);
        }
    }

    float4 bb = *(const float4*)&sb3[c4];
    float w40x = sW4[2 * c4],     w41x = sW4[2 * c4 + 1];
    float w40y = sW4[2 * c4 + 2], w41y = sW4[2 * c4 + 3];
    float w40z = sW4[2 * c4 + 4], w41z = sW4[2 * c4 + 5];
    float w40w = sW4[2 * c4 + 6], w41w = sW4[2 * c4 + 7];
    float av4s0 = av4s[0], av4s1 = av4s[1];
    float av4d0 = av4d[0], av4d1 = av4d[1];

    #pragma unroll
    for (int n = 0; n < 4; n++) {
        float4 a = (n == 0) ? acc0 : (n == 1) ? acc1 : (n == 2) ? acc2 : acc3;
        a.x = fmaxf(a.x + bb.x, 0.f);
        a.y = fmaxf(a.y + bb.y, 0.f);
        a.z = fmaxf(a.z + bb.z, 0.f);
        a.w = fmaxf(a.w + bb.w, 0.f);
        float p0 = a.x * w40x + a.y * w40y + a.z * w40z + a.w * w40w;
        float p1 = a.x * w41x + a.y * w41y + a.z * w41z + a.w * w41w;
        #pragma unroll
        for (int off = 16; off > 0; off >>= 1) {
            p0 += __shfl_down(p0, off, 32);
            p1 += __shfl_down(p1, off, 32);
        }
        if (lw == 0) {
            int gn = blockIdx.x * 32 + lbase + n;
            float asv = p0 * av4s0 + p1 * av4s1;
            float4 pk = {p0, p1, asv, 0.f};
            h4as[gn] = pk;
            as_[gn] = asv;
            ad_[gn] = p0 * av4d0 + p1 * av4d1;
        }
    }
}

// ---------------- final GAT (2ch) + log_softmax, single-pass, 4 lanes/node ----------------

__global__ void k_final(const float4* __restrict__ h4as, const float* __restrict__ as_,
                        const float* __restrict__ ad_, const int* __restrict__ rowptr,
                        const int* __restrict__ col, const float* __restrict__ b,
                        float* __restrict__ out) {
    int gid = blockIdx.x * 256 + threadIdx.x;  // NN*4
    int n = gid >> 2;
    if (n >= NN) return;
    int lsub = gid & 3;
    int beg = rowptr[n], end = rowptr[n + 1];
    float adn = ad_[n];
    float den = 0.f, a0 = 0.f, a1 = 0.f;
    for (int e = beg + lsub; e < end; e += 4) {
        int s = clampN(col[e]);
        float4 h = h4as[s];
        float p = __expf(lrelu_c(h.z + adn));
        den += p;
        a0 += p * h.x;
        a1 += p * h.y;
    }
    den += __shfl_xor(den, 1, 4); den += __shfl_xor(den, 2, 4);
    a0  += __shfl_xor(a0, 1, 4);  a0  += __shfl_xor(a0, 2, 4);
    a1  += __shfl_xor(a1, 1, 4);  a1  += __shfl_xor(a1, 2, 4);
    if (lsub == 0) {
        float inv = 1.0f / (den + 1e-16f);
        float v0 = a0 * inv + b[0];
        float v1 = a1 * inv + b[1];
        float mx = fmaxf(v0, v1);
        float lse = mx + logf(__expf(v0 - mx) + __expf(v1 - mx));
        float2 o = {v0 - lse, v1 - lse};
        *(float2*)(out + n * 2) = o;
    }
}

__global__ void k_sentinel(float* __restrict__ out, float v) {
    int i = blockIdx.x * 256 + threadIdx.x;
    if (i < NN * 2) out[i] = v;
}

// ---------------- launch ----------------

extern "C" void kernel_launch(void* const* d_in, const int* in_sizes, int n_in,
                              void* d_out, int out_size, void* d_ws, size_t ws_size,
                              hipStream_t stream) {
    const float* x    = (const float*)d_in[0];
    const int* ei     = (const int*)d_in[1];
    const float* W1   = (const float*)d_in[2];
    const float* b1   = (const float*)d_in[3];
    const float* W2   = (const float*)d_in[4];
    const float* a2s  = (const float*)d_in[5];
    const float* a2d  = (const float*)d_in[6];
    const float* b2   = (const float*)d_in[7];
    const float* W3   = (const float*)d_in[8];
    const float* b3   = (const float*)d_in[9];
    const float* W4   = (const float*)d_in[10];
    const float* a4s  = (const float*)d_in[11];
    const float* a4d  = (const float*)d_in[12];
    const float* b4   = (const float*)d_in[13];
    float* out = (float*)d_out;

    char* base = (char*)d_ws;
    size_t off = 0;
    auto alloc = [&](size_t bytes) {
        char* q = base + off;
        off += (bytes + 255) & ~(size_t)255;
        return q;
    };
    float* bufA  = (float*)alloc((size_t)NN * 64 * 4);   // xpb -> O1b -> O2b
    float* bufB  = (float*)alloc((size_t)NN * 64 * 4);   // T3
    u32* staging = (u32*)alloc((size_t)NBKT * BCAP * 4);
    int* col     = (int*)alloc((size_t)NT * 4);
    int* rowptr  = (int*)alloc((size_t)(NN + 1) * 4);
    int* deg     = (int*)alloc((size_t)NN * 4);
    float* dinv  = (float*)alloc((size_t)NN * 4);
    float* as_   = (float*)alloc((size_t)NN * 4);
    float* ad_   = (float*)alloc((size_t)NN * 4);
    float4* h4as = (float4*)alloc((size_t)NN * 16);
    int* part    = (int*)alloc(512 * 4);
    int* flag    = (int*)alloc(256);
    int* gcur    = (int*)alloc(NBKT * 4);
    float* va2   = (float*)alloc(32 * 4);
    float* vd2   = (float*)alloc(32 * 4);

    float code = 0.f;
    if (off > ws_size)            code = 1000.f + (float)(ws_size >> 20);
    else if (n_in != 14)          code = 2000.f + 10.f * (float)n_in;
    else if (out_size != NN * 2)  code = 3400.f;
    if (code != 0.f) {
        k_sentinel<<<(NN * 2 + 255) / 256, 256, 0, stream>>>(out, code);
        return;
    }

    const int NTILE = (NT + 4095) / 4096;

    // CSR build: init -> bin -> hist+localscan -> bucket scan -> finalize+scatter
    k_init<<<NN * 4 / 256, 256, 0, stream>>>(x, W2, a2s, a2d, ei, (u32*)bufA, va2, vd2,
                                             flag, gcur);
    k_binA<<<NTILE, 256, 0, stream>>>(ei, flag, gcur, staging);
    k_histscan<<<NBKT, 256, 0, stream>>>(staging, gcur, rowptr, deg, part);
    k_scan2<<<1, 256, 0, stream>>>(part, rowptr);
    k_scat<<<NBKT, 256, 0, stream>>>(staging, gcur, part, rowptr, deg, dinv, col);

    // layer 1 fused: agg(bf16 xp) + dense 7->32 + alpha2  (xpb in bufA -> O1b in bufA)
    k_l1<<<(NN + 63) / 64, 256, 0, stream>>>((const u32*)bufA, rowptr, col, dinv,
                                             W1, b1, va2, vd2, (u32*)bufA, as_, ad_);
    // layer 2 fused: GAT agg + dense 32->64 (O1b in bufA -> O2b in bufA)
    k_l2<<<NN / 32, 256, 0, stream>>>((const u32*)bufA, as_, ad_, rowptr, col,
                                      W2, b2, dinv, (u32*)bufA);
    // layer 3: gather (T3 into bufB)
    k_agg3<<<NN * 8 / 256, 256, 0, stream>>>((const u32*)bufA, rowptr, col, dinv, bufB);
    // dense 3/4
    k_mm34<<<NN / 32, 256, 0, stream>>>(bufB, W3, b3, W4, a4s, a4d, h4as, as_, ad_);
    // layer 4 agg + log_softmax
    k_final<<<NN * 4 / 256 + 1, 256, 0, stream>>>(h4as, as_, ad_, rowptr, col, b4, out);
}